// Round 10
// baseline (1474.002 us; speedup 1.0000x reference)
//
#include <hip/hip_runtime.h>

typedef unsigned int uint;
typedef unsigned short ushort;
typedef unsigned long long u64;
typedef __attribute__((ext_vector_type(8))) short short8;
typedef __attribute__((ext_vector_type(4))) float f32x4;

__device__ __forceinline__ uint brev8(uint x){ return __brev(x) >> 24; }
__device__ __forceinline__ float geluf(float x){
  return 0.5f*x*(1.f + tanhf(0.7978845608028654f*(x + 0.044715f*x*x*x)));
}
__device__ __forceinline__ ushort f2bf(float f){
  unsigned u = __float_as_uint(f);
  unsigned r = u + 0x7FFFu + ((u >> 16) & 1u);
  return (ushort)(r >> 16);
}
__device__ __forceinline__ float bf2f(ushort u){
  return __uint_as_float((uint)u << 16);
}

// ---------------- pooled mean ----------------
__global__ __launch_bounds__(256) void kern_pool(const float* __restrict__ vis,
                                                 const float* __restrict__ irf,
                                                 float* __restrict__ pooled){
  __shared__ float red[256];
  int bc = blockIdx.x;
  int b = bc >> 7, cc = bc & 127;
  const float* src = (cc < 64) ? (vis + (size_t)(b*64+cc)*65536)
                               : (irf + (size_t)(b*64+(cc-64))*65536);
  float s = 0.f;
  for (int i = threadIdx.x; i < 65536; i += 256) s += src[i];
  red[threadIdx.x] = s;
  __syncthreads();
  for (int off = 128; off > 0; off >>= 1){
    if (threadIdx.x < off) red[threadIdx.x] += red[threadIdx.x + off];
    __syncthreads();
  }
  if (threadIdx.x == 0) pooled[bc] = red[0] * (1.f/65536.f);
}

// ---------------- prompt/intent/affine small ops ----------------
__global__ __launch_bounds__(256) void kern_small(const float* __restrict__ pooled,
    const float* __restrict__ Wr, const float* __restrict__ br,
    const float* __restrict__ bank, const float* __restrict__ Wpri,
    const float* __restrict__ Wint, const float* __restrict__ Wa1,
    const float* __restrict__ ba1, const float* __restrict__ Wa2,
    const float* __restrict__ ba2,
    float* __restrict__ IP, float* __restrict__ IPint,
    float* __restrict__ modg, float* __restrict__ modb){
  __shared__ float logit_s[16];
  __shared__ float pw_s[16];
  __shared__ float intent_s[4][64];
  __shared__ float t1_s[4][128];
  int t = threadIdx.x;
  if (t < 16){
    int b = t >> 2, j = t & 3;
    float s = br[j];
    for (int k = 0; k < 128; ++k) s += pooled[b*128+k]*Wr[k*4+j];
    logit_s[t] = s;
  }
  __syncthreads();
  if (t < 4){
    int b = t;
    float m = logit_s[b*4];
    for (int j = 1; j < 4; ++j) m = fmaxf(m, logit_s[b*4+j]);
    float e[4], sum = 0.f;
    for (int j = 0; j < 4; ++j){ e[j] = expf(logit_s[b*4+j]-m); sum += e[j]; }
    for (int j = 0; j < 4; ++j) pw_s[b*4+j] = e[j]/sum;
  }
  __syncthreads();
  {
    int b = t >> 6, p = t & 63;
    float s = 0.f;
    for (int j = 0; j < 4; ++j) s += pw_s[b*4+j]*bank[j*64+p];
    intent_s[b][p] = s;
  }
  __syncthreads();
  for (int o = t; o < 1024; o += 256){
    int i = o >> 9, rem = o & 511, b = rem >> 7, n = rem & 127;
    float s1 = 0.f, s2 = 0.f;
    for (int p = 0; p < 64; ++p){
      float iv = intent_s[b][p];
      s1 += iv * Wpri[(i*64+p)*128 + n];
      s2 += iv * Wint[(i*64+p)*128 + n];
    }
    IP[o] = s1; IPint[o] = s2;
  }
  for (int o = t; o < 512; o += 256){
    int b = o >> 7, n = o & 127;
    float s = ba1[n];
    for (int p = 0; p < 64; ++p) s += intent_s[b][p]*Wa1[p*128+n];
    t1_s[b][n] = geluf(s);
  }
  __syncthreads();
  for (int o = t; o < 512; o += 256){
    int b = o >> 7, n = o & 127;
    float s = ba2[n];
    for (int p = 0; p < 128; ++p) s += t1_s[b][p]*Wa2[p*128+n];
    if (n < 64) modg[b*64+n] = 1.f + 0.1f*tanhf(s);
    else        modb[b*64+(n-64)] = 0.1f*s;
  }
}

// ---------------- forward row FFT (fp32 in, bf16 spectrum out) ----------------
__global__ __launch_bounds__(256) void kern_fft_rows_fwd(const float* __restrict__ x,
    ushort* __restrict__ sre, ushort* __restrict__ sim){
  __shared__ float re[2][256], im[2][256];
  __shared__ float twr[128], twi[128];
  int t = threadIdx.x;
  if (t < 128){
    float a = -6.2831853071795864f * (float)t * (1.f/256.f);
    sincosf(a, &twi[t], &twr[t]);
  }
  int r = t >> 7, jj = t & 127;
  size_t row = (size_t)blockIdx.x*2 + r;
  {
    const float* xp = x + row*256;
    re[r][jj] = xp[jj]; re[r][jj+128] = xp[jj+128];
    im[r][jj] = 0.f;    im[r][jj+128] = 0.f;
  }
  __syncthreads();
  for (int s = 0; s < 8; ++s){
    int half = 128 >> s;
    int j = jj & (half-1);
    int g = jj >> (7-s);
    int k = (g << (8-s)) + j;
    int m = j << s;
    float wc = twr[m], ws = twi[m];
    float are = re[r][k],      aim = im[r][k];
    float bre = re[r][k+half], bim = im[r][k+half];
    re[r][k] = are + bre; im[r][k] = aim + bim;
    float tr = are - bre, ti = aim - bim;
    re[r][k+half] = tr*wc - ti*ws;
    im[r][k+half] = tr*ws + ti*wc;
    __syncthreads();
  }
  {
    int e0 = 2*jj;
    uint vr = (uint)f2bf(re[r][brev8(e0)]) | ((uint)f2bf(re[r][brev8(e0+1)]) << 16);
    uint vi = (uint)f2bf(im[r][brev8(e0)]) | ((uint)f2bf(im[r][brev8(e0+1)]) << 16);
    *(uint*)(sre + row*256 + e0) = vr;
    *(uint*)(sim + row*256 + e0) = vi;
  }
}

// ---------------- inverse row FFT with spec construction (fp32 FULL in, bf16 out) ----
__global__ __launch_bounds__(256) void kern_ifft_rows_spec(const float* __restrict__ famp,
    const float* __restrict__ fph, ushort* __restrict__ sre, ushort* __restrict__ sim){
  __shared__ float re[4][256], im[4][256];
  __shared__ float twr[128], twi[128];
  int t = threadIdx.x;
  if (t < 128){
    float a = -6.2831853071795864f * (float)t * (1.f/256.f);
    sincosf(a, &twi[t], &twr[t]);
  }
  int R = blockIdx.x * 4;
  {
    int r = t >> 6, q = t & 63;
    int row = R + r;
    int bc = row >> 8, h = row & 255;
    int b = bc >> 6, c = bc & 63;
    size_t addr = ((size_t)(b*4096 + (h>>2)*64 + q))*1024 + c*16 + (h&3)*4;
    float4 a4 = *(const float4*)(famp + addr);
    float4 p4 = *(const float4*)(fph + addr);
    float sn, cs;
    sincosf(p4.x, &sn, &cs); re[r][4*q+0] = a4.x*cs; im[r][4*q+0] = a4.x*sn;
    sincosf(p4.y, &sn, &cs); re[r][4*q+1] = a4.y*cs; im[r][4*q+1] = a4.y*sn;
    sincosf(p4.z, &sn, &cs); re[r][4*q+2] = a4.z*cs; im[r][4*q+2] = a4.z*sn;
    sincosf(p4.w, &sn, &cs); re[r][4*q+3] = a4.w*cs; im[r][4*q+3] = a4.w*sn;
  }
  __syncthreads();
  for (int s = 0; s < 8; ++s){
    int half = 128 >> s;
    #pragma unroll
    for (int bi0 = 0; bi0 < 2; ++bi0){
      int bi = t + bi0*256;
      int r = bi >> 7, tj = bi & 127;
      int j = tj & (half-1);
      int g = tj >> (7-s);
      int k = (g << (8-s)) + j;
      int m = j << s;
      float wc = twr[m], ws = -twi[m];
      float are = re[r][k],      aim = im[r][k];
      float bre = re[r][k+half], bim = im[r][k+half];
      re[r][k] = are + bre; im[r][k] = aim + bim;
      float tr = are - bre, ti = aim - bim;
      re[r][k+half] = tr*wc - ti*ws;
      im[r][k+half] = tr*ws + ti*wc;
    }
    __syncthreads();
  }
  {
    int r = t >> 6, q = t & 63;
    size_t row = (size_t)R + r;
    uint2 vr, vi;
    vr.x = (uint)f2bf(re[r][brev8(4*q+0)]) | ((uint)f2bf(re[r][brev8(4*q+1)]) << 16);
    vr.y = (uint)f2bf(re[r][brev8(4*q+2)]) | ((uint)f2bf(re[r][brev8(4*q+3)]) << 16);
    vi.x = (uint)f2bf(im[r][brev8(4*q+0)]) | ((uint)f2bf(im[r][brev8(4*q+1)]) << 16);
    vi.y = (uint)f2bf(im[r][brev8(4*q+2)]) | ((uint)f2bf(im[r][brev8(4*q+3)]) << 16);
    *(uint2*)(sre + row*256 + 4*q) = vr;
    *(uint2*)(sim + row*256 + 4*q) = vi;
  }
}

// ---------------- column FFT: bf16 spectrum in; DIR=0 bf16 amp/ph out, DIR=1 fp32 out --
template<int DIR>
__global__ __launch_bounds__(256) void kern_fft_cols(const ushort* __restrict__ sre,
    const ushort* __restrict__ sim, void* __restrict__ out0, void* __restrict__ out1){
  __shared__ float reL[256*17];
  __shared__ float imL[256*17];
  __shared__ float twr[128], twi[128];
  int t = threadIdx.x;
  if (t < 128){
    float a = -6.2831853071795864f * (float)t * (1.f/256.f);
    sincosf(a, &twi[t], &twr[t]);
  }
  int img = blockIdx.x >> 4;
  int c0 = (blockIdx.x & 15) * 16;
  {
    const ushort* pr = sre + ((size_t)img*256 + t)*256 + c0;
    const ushort* pi = sim + ((size_t)img*256 + t)*256 + c0;
    short8 r0 = *(const short8*)pr;
    short8 r1 = *(const short8*)(pr + 8);
    short8 i0 = *(const short8*)pi;
    short8 i1 = *(const short8*)(pi + 8);
    int base = t*17;
    #pragma unroll
    for (int j = 0; j < 8; ++j){
      reL[base+j]   = bf2f((ushort)r0[j]);
      reL[base+8+j] = bf2f((ushort)r1[j]);
      imL[base+j]   = bf2f((ushort)i0[j]);
      imL[base+8+j] = bf2f((ushort)i1[j]);
    }
  }
  __syncthreads();
  int col = t & 15, tb = t >> 4;
  for (int s = 0; s < 8; ++s){
    int half = 128 >> s;
    #pragma unroll
    for (int it = 0; it < 8; ++it){
      int tj = tb + it*16;
      int j = tj & (half-1);
      int g = tj >> (7-s);
      int k = (g << (8-s)) + j;
      int m = j << s;
      float wc = twr[m];
      float ws = (DIR == 0) ? twi[m] : -twi[m];
      int i0 = k*17 + col, i1 = (k+half)*17 + col;
      float are = reL[i0], aim = imL[i0];
      float bre = reL[i1], bim = imL[i1];
      reL[i0] = are + bre; imL[i0] = aim + bim;
      float tr = are - bre, ti = aim - bim;
      reL[i1] = tr*wc - ti*ws;
      imL[i1] = tr*ws + ti*wc;
    }
    __syncthreads();
  }
  int b = img >> 6, c = img & 63;
  int h = t; int src = (int)brev8((uint)h);
  if (DIR == 0){
    ushort* oa = (ushort*)out0;
    ushort* op = (ushort*)out1;
    int gy = h >> 2, py = h & 3;
    #pragma unroll
    for (int p = 0; p < 4; ++p){
      int base = src*17 + 4*p;
      float a0, a1, a2, a3, p0, p1, p2, p3;
      float rr, ii;
      rr = reL[base+0]; ii = imL[base+0]; a0 = sqrtf(rr*rr+ii*ii); p0 = atan2f(ii, rr);
      rr = reL[base+1]; ii = imL[base+1]; a1 = sqrtf(rr*rr+ii*ii); p1 = atan2f(ii, rr);
      rr = reL[base+2]; ii = imL[base+2]; a2 = sqrtf(rr*rr+ii*ii); p2 = atan2f(ii, rr);
      rr = reL[base+3]; ii = imL[base+3]; a3 = sqrtf(rr*rr+ii*ii); p3 = atan2f(ii, rr);
      size_t addr = ((size_t)(b*4096 + gy*64 + (c0>>2) + p))*1024 + c*16 + py*4;
      uint2 av, pv;
      av.x = (uint)f2bf(a0) | ((uint)f2bf(a1) << 16);
      av.y = (uint)f2bf(a2) | ((uint)f2bf(a3) << 16);
      pv.x = (uint)f2bf(p0) | ((uint)f2bf(p1) << 16);
      pv.y = (uint)f2bf(p2) | ((uint)f2bf(p3) << 16);
      *(uint2*)(oa + addr) = av;
      *(uint2*)(op + addr) = pv;
    }
  } else {
    float* op = (float*)out0 + ((size_t)img*256 + h)*256 + c0;
    #pragma unroll
    for (int p = 0; p < 4; ++p){
      int base = src*17 + 4*p;
      float4 v;
      v.x = reL[base+0]*(1.f/65536.f);
      v.y = reL[base+1]*(1.f/65536.f);
      v.z = reL[base+2]*(1.f/65536.f);
      v.w = reL[base+3]*(1.f/65536.f);
      *(float4*)(op + 4*p) = v;
    }
  }
}

// ---------------- transpose-convert: fp32 [K][N] -> bf16 [N][K], 10 mats ----------
struct TRS {
  const float* src[10];
  ushort* dst[10];
  int K[10], N[10];
  int start[11];
};
__global__ __launch_bounds__(256) void kern_tr(TRS p){
  __shared__ float lds[32][33];
  int bid = blockIdx.x;
  int e = 0;
  while (bid >= p.start[e+1]) ++e;
  int tloc = bid - p.start[e];
  int tilesN = p.N[e] >> 5;
  int tn = tloc % tilesN, tk = tloc / tilesN;
  int k0 = tk << 5, n0 = tn << 5;
  const float* src = p.src[e];
  ushort* dst = p.dst[e];
  int K = p.K[e], N = p.N[e];
  int r = threadIdx.x >> 5, c = threadIdx.x & 31;
  #pragma unroll
  for (int i = 0; i < 4; ++i)
    lds[r + 8*i][c] = src[(size_t)(k0 + r + 8*i)*N + n0 + c];
  __syncthreads();
  #pragma unroll
  for (int i = 0; i < 4; ++i)
    dst[(size_t)(n0 + r + 8*i)*K + k0 + c] = f2bf(lds[c][r + 8*i]);
}

// ---------------- mgemm2: BM=64 BN=128 BK=64, bf16 A + bf16 B^T, swizzled LDS -----
// AMODE: 1 cat(A0|A1) along K (1024 each), 2 gather rows via idx.
// EPI: 0 plain, 1 h-epi, 2 bypass sigmoid-blend (N=1024).
struct GP2 {
  const ushort* A0[6];
  const ushort* A1[2];
  const ushort* Bt[6];
  float* Cm[6];
  const int* idxp[6];
  const float* ep0[2];
  const float* ep1[2];
  const float* ep2[2];
  const ushort* vt[2];
  const ushort* it[2];
  int N, K;
};

template<int AMODE, int EPI>
__global__ __launch_bounds__(256) void kern_mgemm2(GP2 p){
  __shared__ __align__(16) ushort Asb[64*64];
  __shared__ __align__(16) ushort Bsb[128*64];
  __shared__ int idx_s[64];
  int z = blockIdx.z;
  const ushort* A0 = p.A0[z];
  const ushort* Bt = p.Bt[z];
  float* Cm = p.Cm[z];
  int tid = threadIdx.x;
  int m0 = blockIdx.x * 64;
  int n0 = blockIdx.y * 128;
  int lane = tid & 63, w = tid >> 6;
  int wr = w & 1, wc = w >> 1;
  int lr = lane & 15, ql = lane >> 4;

  if (AMODE == 2){
    if (tid < 64){
      int m = m0 + tid;
      idx_s[tid] = p.idxp[z][(m >> 10)*1024 + (m & 1023)];
    }
    __syncthreads();
  }
  int gb = m0 >> 10;

  f32x4 acc[2][4];
  #pragma unroll
  for (int i = 0; i < 2; ++i)
    #pragma unroll
    for (int j = 0; j < 4; ++j) acc[i][j] = (f32x4){0.f,0.f,0.f,0.f};

  int kh = tid & 7;
  int rA = tid >> 3;
  for (int k0 = 0; k0 < p.K; k0 += 64){
    #pragma unroll
    for (int s = 0; s < 2; ++s){
      int m = rA + 32*s;
      const ushort* ap;
      if (AMODE == 1){
        const ushort* srcp = (k0 < 1024) ? A0 : p.A1[z];
        ap = srcp + (size_t)(m0+m)*1024 + (k0 & 1023) + kh*8;
      } else {
        ap = A0 + ((size_t)(gb << 12) + idx_s[m])*(size_t)p.K + k0 + kh*8;
      }
      short8 v = *(const short8*)ap;
      int byte = m*128 + ((kh*16) ^ ((m & 7)*16));
      *(short8*)((char*)Asb + byte) = v;
    }
    #pragma unroll
    for (int s = 0; s < 4; ++s){
      int n = rA + 32*s;
      short8 v = *(const short8*)(Bt + (size_t)(n0+n)*p.K + k0 + kh*8);
      int byte = n*128 + ((kh*16) ^ ((n & 7)*16));
      *(short8*)((char*)Bsb + byte) = v;
    }
    __syncthreads();
    short8 af[2][2], bf[4][2];
    #pragma unroll
    for (int fm = 0; fm < 2; ++fm){
      int row = wr*32 + fm*16 + lr;
      #pragma unroll
      for (int kq = 0; kq < 2; ++kq){
        int byte = row*128 + ((kq*64 + ql*16) ^ ((row & 7)*16));
        af[fm][kq] = *(const short8*)((const char*)Asb + byte);
      }
    }
    #pragma unroll
    for (int fn = 0; fn < 4; ++fn){
      int row = wc*64 + fn*16 + lr;
      #pragma unroll
      for (int kq = 0; kq < 2; ++kq){
        int byte = row*128 + ((kq*64 + ql*16) ^ ((row & 7)*16));
        bf[fn][kq] = *(const short8*)((const char*)Bsb + byte);
      }
    }
    #pragma unroll
    for (int kq = 0; kq < 2; ++kq)
      #pragma unroll
      for (int fm = 0; fm < 2; ++fm)
        #pragma unroll
        for (int fn = 0; fn < 4; ++fn)
          acc[fm][fn] = __builtin_amdgcn_mfma_f32_16x16x32_bf16(af[fm][kq], bf[fn][kq],
                                                                acc[fm][fn], 0, 0, 0);
    __syncthreads();
  }

  #pragma unroll
  for (int fm = 0; fm < 2; ++fm){
    #pragma unroll
    for (int fn = 0; fn < 4; ++fn){
      int n = n0 + wc*64 + fn*16 + lr;
      #pragma unroll
      for (int reg = 0; reg < 4; ++reg){
        int m = m0 + wr*32 + fm*16 + ql*4 + reg;
        float v = acc[fm][fn][reg];
        if (EPI == 0){
          Cm[(size_t)m*p.N + n] = v;
        } else if (EPI == 1){
          int bl = m >> 12, g = m & 4095;
          int gy = g >> 6, gx = g & 63;
          float cy = ((float)gy + 0.5f)*(1.f/64.f);
          float cx = ((float)gx + 0.5f)*(1.f/64.f);
          float o = v + p.ep0[z][bl*128 + n] + cy*p.ep1[z][n]
                  + cx*p.ep1[z][128 + n] + p.ep2[z][n];
          Cm[(size_t)m*128 + n] = o;
        } else {
          size_t off = (size_t)m*1024 + n;
          float vt = bf2f(p.vt[z][off]);
          float it = bf2f(p.it[z][off]);
          float gg = 1.f/(1.f + expf(-(v + p.ep0[z][n])));
          Cm[off] = gg*vt + (1.f-gg)*it;
        }
      }
    }
  }
}

// ---------------- scatter GEMM: fused_sel = vs(bf16) + o@Wo, K=128 ----------------
struct SCP {
  const float* A0[2];
  const float* Bm[2];
  float* Cm[2];
  const int* idxp[2];
  const ushort* vtb[2];
};

__global__ __launch_bounds__(256) void kern_scat(SCP p){
  __shared__ __align__(16) ushort Asb[64*40];
  __shared__ __align__(16) ushort Bsb[128*40];
  __shared__ int idx_s[64];
  int z = blockIdx.z;
  const float* A0 = p.A0[z];
  const float* Bm = p.Bm[z];
  float* Cm = p.Cm[z];
  int tid = threadIdx.x;
  int m0 = blockIdx.y * 64;
  int n0 = blockIdx.x * 128;
  int lane = tid & 63, w = tid >> 6;
  int wr = w & 1, wc = w >> 1;
  int lr = lane & 15, ql = lane >> 4;
  if (tid < 64){
    int m = m0 + tid;
    idx_s[tid] = p.idxp[z][(m >> 10)*1024 + (m & 1023)];
  }
  __syncthreads();
  int gb = m0 >> 10;

  f32x4 acc[2][4];
  #pragma unroll
  for (int i = 0; i < 2; ++i)
    #pragma unroll
    for (int j = 0; j < 4; ++j) acc[i][j] = (f32x4){0.f,0.f,0.f,0.f};

  for (int k0 = 0; k0 < 128; k0 += 32){
    {
      int m = tid & 63;
      int khh = (tid >> 6) * 8;
      const float* ap = A0 + (size_t)(m0+m)*128 + k0 + khh;
      float4 f0 = *(const float4*)ap;
      float4 f1 = *(const float4*)(ap + 4);
      short8 v;
      v[0]=(short)f2bf(f0.x); v[1]=(short)f2bf(f0.y);
      v[2]=(short)f2bf(f0.z); v[3]=(short)f2bf(f0.w);
      v[4]=(short)f2bf(f1.x); v[5]=(short)f2bf(f1.y);
      v[6]=(short)f2bf(f1.z); v[7]=(short)f2bf(f1.w);
      *(short8*)&Asb[m*40 + khh] = v;
    }
    #pragma unroll
    for (int e0 = 0; e0 < 512; e0 += 256){
      int e = e0 + tid;
      int n = e & 127;
      int khh = (e >> 7) * 8;
      const float* bp = Bm + (size_t)(k0+khh)*1024 + n0 + n;
      short8 v;
      #pragma unroll
      for (int j = 0; j < 8; ++j) v[j] = (short)f2bf(bp[(size_t)j*1024]);
      *(short8*)&Bsb[n*40 + khh] = v;
    }
    __syncthreads();
    short8 af[2], bf[4];
    #pragma unroll
    for (int fr = 0; fr < 2; ++fr)
      af[fr] = *(const short8*)&Asb[(wr*32 + fr*16 + lr)*40 + ql*8];
    #pragma unroll
    for (int fc = 0; fc < 4; ++fc)
      bf[fc] = *(const short8*)&Bsb[(wc*64 + fc*16 + lr)*40 + ql*8];
    #pragma unroll
    for (int fr = 0; fr < 2; ++fr)
      #pragma unroll
      for (int fc = 0; fc < 4; ++fc)
        acc[fr][fc] = __builtin_amdgcn_mfma_f32_16x16x32_bf16(af[fr], bf[fc],
                                                              acc[fr][fc], 0, 0, 0);
    __syncthreads();
  }

  #pragma unroll
  for (int fr = 0; fr < 2; ++fr){
    #pragma unroll
    for (int fc = 0; fc < 4; ++fc){
      int n = n0 + wc*64 + fc*16 + lr;
      #pragma unroll
      for (int reg = 0; reg < 4; ++reg){
        int mloc = wr*32 + fr*16 + ql*4 + reg;
        int gt = idx_s[mloc];
        size_t off = ((size_t)(gb << 12) + gt)*1024 + n;
        Cm[off] = acc[fr][fc][reg] + bf2f(p.vtb[z][off]);
      }
    }
  }
}

// ---------------- score ----------------
__global__ __launch_bounds__(64) void kern_score(const float* __restrict__ h,
    const float* __restrict__ wout, const float* __restrict__ bout,
    float* __restrict__ score, int Mper){
  int m = blockIdx.x, br = blockIdx.y, t = threadIdx.x;
  const float* hp = h + ((size_t)br*Mper + m)*128;
  const float* wp = wout + br*128;
  float s = geluf(hp[t])*wp[t] + geluf(hp[t+64])*wp[t+64];
  #pragma unroll
  for (int off = 32; off > 0; off >>= 1) s += __shfl_down(s, off);
  if (t == 0) score[(size_t)br*Mper + m] = s + bout[br];
}

// ---------------- top-1024 of 4096 (bitonic, jax tie-break) ----------------
__global__ __launch_bounds__(1024) void kern_topk(const float* __restrict__ score,
    int* __restrict__ idx_out){
  __shared__ u64 keys[4096];
  int b = blockIdx.x, t = threadIdx.x;
  for (int i = t; i < 4096; i += 1024){
    float s = score[b*4096 + i];
    uint u = __float_as_uint(s);
    uint msk = (u & 0x80000000u) ? ~u : (u | 0x80000000u);
    keys[i] = ((u64)msk << 32) | (uint)(4095 - i);
  }
  __syncthreads();
  for (int k = 2; k <= 4096; k <<= 1){
    for (int j = k >> 1; j > 0; j >>= 1){
      for (int i = t; i < 4096; i += 1024){
        int l = i ^ j;
        if (l > i){
          u64 a = keys[i], c = keys[l];
          bool descB = ((i & k) == 0);
          bool sw = descB ? (a < c) : (a > c);
          if (sw){ keys[i] = c; keys[l] = a; }
        }
      }
      __syncthreads();
    }
  }
  idx_out[b*1024 + t] = 4095 - (int)(keys[t] & 0xFFFFFFFFu);
}

// ---------------- attention partials (k-split flash, 128-thr q-split) ----------
__global__ __launch_bounds__(128) void kern_attn_part(const float* __restrict__ qb,
    const float* __restrict__ kb, const float* __restrict__ vb,
    float* __restrict__ paoa, float* __restrict__ pml){
  __shared__ float Ks[64][32];
  __shared__ float Vs[64][32];
  int t = threadIdx.x;
  int hh = blockIdx.y;
  int zc = blockIdx.z;
  int zf = zc >> 2, c = zc & 3;
  size_t boff = (size_t)zf*131072;
  int jq = blockIdx.x*128 + t;
  float qv[32];
  {
    const float4* qp = (const float4*)(qb + boff + (size_t)jq*128 + hh*32);
    #pragma unroll
    for (int d = 0; d < 8; ++d) ((float4*)qv)[d] = qp[d];
  }
  float mrun = -3.0e38f, lrun = 0.f;
  float oa[32];
  #pragma unroll
  for (int d = 0; d < 32; ++d) oa[d] = 0.f;
  for (int kt = 0; kt < 4; ++kt){
    int k0 = c*256 + kt*64;
    #pragma unroll
    for (int rep = 0; rep < 4; ++rep){
      int f = t + rep*128;
      int r = f >> 3, q4 = f & 7;
      size_t base = boff + (size_t)(k0 + r)*128 + hh*32 + 4*q4;
      *(float4*)&Ks[r][4*q4] = *(const float4*)(kb + base);
      *(float4*)&Vs[r][4*q4] = *(const float4*)(vb + base);
    }
    __syncthreads();
    #pragma unroll
    for (int st = 0; st < 4; ++st){
      float s[16];
      #pragma unroll
      for (int j = 0; j < 16; ++j){
        float v = 0.f;
        #pragma unroll
        for (int d = 0; d < 32; ++d) v += qv[d]*Ks[st*16+j][d];
        s[j] = v * 0.17677669529663687f;
      }
      float mt = s[0];
      #pragma unroll
      for (int j = 1; j < 16; ++j) mt = fmaxf(mt, s[j]);
      float mnew = fmaxf(mrun, mt);
      float alpha = expf(mrun - mnew);
      lrun *= alpha;
      #pragma unroll
      for (int d = 0; d < 32; ++d) oa[d] *= alpha;
      #pragma unroll
      for (int j = 0; j < 16; ++j){
        float pe = expf(s[j] - mnew);
        lrun += pe;
        #pragma unroll
        for (int d = 0; d < 32; ++d) oa[d] += pe*Vs[st*16+j][d];
      }
      mrun = mnew;
    }
    __syncthreads();
  }
  size_t rec = (((size_t)zf*4 + hh)*4 + c)*1024 + jq;
  float* pp = paoa + rec*32;
  #pragma unroll
  for (int d = 0; d < 8; ++d) ((float4*)pp)[d] = ((float4*)oa)[d];
  pml[rec*2]   = mrun;
  pml[rec*2+1] = lrun;
}

// ---------------- attention combine ----------------
__global__ __launch_bounds__(256) void kern_attn_comb(const float* __restrict__ paoa,
    const float* __restrict__ pml, float* __restrict__ ob,
    const float* __restrict__ ipint, int PB, int b0){
  int t = threadIdx.x;
  int hh = blockIdx.y, zf = blockIdx.z;
  int jq = blockIdx.x*256 + t;
  size_t rbase = (((size_t)zf*4 + hh)*4)*1024 + jq;
  float mc[4], lc[4];
  #pragma unroll
  for (int c = 0; c < 4; ++c){
    mc[c] = pml[(rbase + c*1024)*2];
    lc[c] = pml[(rbase + c*1024)*2 + 1];
  }
  float M = fmaxf(fmaxf(mc[0], mc[1]), fmaxf(mc[2], mc[3]));
  float wgt[4], L = 0.f;
  #pragma unroll
  for (int c = 0; c < 4; ++c){ wgt[c] = expf(mc[c] - M); L += lc[c]*wgt[c]; }
  float inv = 1.f/L;
  int br = (zf >= PB) ? 1 : 0;
  int bb = zf - br*PB;
  const float* ip = ipint + br*512 + (b0+bb)*128 + hh*32;
  float* op = ob + (size_t)zf*131072 + (size_t)jq*128 + hh*32;
  #pragma unroll
  for (int d = 0; d < 32; ++d){
    float o = 0.f;
    #pragma unroll
    for (int c = 0; c < 4; ++c) o += paoa[(rbase + c*1024)*32 + d]*wgt[c];
    op[d] = o*inv + ip[d];
  }
}

// ---------------- conv weight transform ----------------
__global__ __launch_bounds__(256) void kern_wt(const float* __restrict__ w1,
    const float* __restrict__ w2, ushort* __restrict__ wt){
  int blk = blockIdx.x;
  const float* src = (blk < 9) ? w1 : w2;
  int tap = blk - (blk < 9 ? 0 : 9);
  ushort* dst = wt + (blk < 9 ? 0 : 36864) + tap*4096;
  for (int e = threadIdx.x; e < 4096; e += 256){
    dst[e] = f2bf(src[(size_t)e*9 + tap]);
  }
}

// ---------------- implicit-GEMM 3x3 conv via MFMA ----------------
template<int MODE>
__global__ __launch_bounds__(256) void kern_cmfma(const float* __restrict__ in,
    const ushort* __restrict__ wt, const float* __restrict__ bias,
    float* __restrict__ out,
    const float* __restrict__ modg, const float* __restrict__ modb,
    const float* __restrict__ vis, const float* __restrict__ irf){
  __shared__ __align__(16) ushort ins[64][268];
  int t = threadIdx.x;
  int y = blockIdx.x, b = blockIdx.y;
  int lane = t & 63, w = t >> 6;
  int wc = w & 1, wx = w >> 1;
  int lr = lane & 15, ql = lane >> 4;

  f32x4 acc[2][8];
  #pragma unroll
  for (int f = 0; f < 2; ++f)
    #pragma unroll
    for (int xf = 0; xf < 8; ++xf) acc[f][xf] = (f32x4){0.f,0.f,0.f,0.f};

  for (int dy = 0; dy < 3; ++dy){
    int yy = y + dy - 1;
    if (yy < 0 || yy > 255) continue;
    const float* src = in + ((size_t)(b*64)*256 + yy)*256;
    #pragma unroll
    for (int s = 0; s < 16; ++s){
      int e = t + s*256;
      int ci = e >> 6, q = e & 63;
      float4 f4 = *(const float4*)(src + (size_t)ci*65536 + 4*q);
      uint lo = (uint)f2bf(f4.x) | ((uint)f2bf(f4.y) << 16);
      uint hi = (uint)f2bf(f4.z) | ((uint)f2bf(f4.w) << 16);
      *(uint2*)&ins[ci][4*q + 4] = make_uint2(lo, hi);
    }
    if (t < 128){
      int r = t & 63;
      ins[r][(t >> 6) ? 260 : 3] = 0;
    }
    __syncthreads();
    short8 wf[2][3][2];
    #pragma unroll
    for (int kk = 0; kk < 2; ++kk)
      #pragma unroll
      for (int dx = 0; dx < 3; ++dx)
        #pragma unroll
        for (int f = 0; f < 2; ++f)
          wf[kk][dx][f] = *(const short8*)(wt +
            (size_t)((dy*3 + dx)*64 + 32*wc + 16*f + lr)*64 + kk*32 + ql*8);
    #pragma unroll
    for (int kk = 0; kk < 2; ++kk){
      const ushort* bp = &ins[kk*32 + ql*8][0];
      #pragma unroll
      for (int dx = 0; dx < 3; ++dx){
        int xb = 128*wx + lr + dx + 3;
        #pragma unroll
        for (int xf = 0; xf < 8; ++xf){
          int xi = xb + 16*xf;
          short8 bf;
          #pragma unroll
          for (int e = 0; e < 8; ++e) bf[e] = (short)bp[e*268 + xi];
          acc[0][xf] = __builtin_amdgcn_mfma_f32_16x16x32_bf16(wf[kk][dx][0], bf,
                                                               acc[0][xf], 0, 0, 0);
          acc[1][xf] = __builtin_amdgcn_mfma_f32_16x16x32_bf16(wf[kk][dx][1], bf,
                                                               acc[1][xf], 0, 0, 0);
        }
      }
    }
    __syncthreads();
  }

  #pragma unroll
  for (int f = 0; f < 2; ++f){
    #pragma unroll
    for (int xf = 0; xf < 8; ++xf){
      int x = 128*wx + 16*xf + lr;
      #pragma unroll
      for (int reg = 0; reg < 4; ++reg){
        int co = 32*wc + 16*f + ql*4 + reg;
        float v = acc[f][xf][reg] + bias[co];
        size_t oi = ((size_t)(b*64 + co)*256 + y)*256 + x;
        if (MODE == 1){
          out[oi] = fmaxf(v, 0.f);
        } else {
          out[oi] = v*modg[b*64+co] + modb[b*64+co] + 0.5f*(vis[oi] + irf[oi]);
        }
      }
    }
  }
}

// ---------------- launch ----------------
extern "C" void kernel_launch(void* const* d_in, const int* in_sizes, int n_in,
                              void* d_out, int out_size, void* d_ws, size_t ws_size,
                              hipStream_t stream){
  (void)in_sizes; (void)n_in; (void)out_size;
  const float* vis  = (const float*)d_in[0];
  const float* irf  = (const float*)d_in[1];
  const float* bank = (const float*)d_in[2];
  const float* Wr   = (const float*)d_in[3];
  const float* br   = (const float*)d_in[4];
  const float* Wtok = (const float*)d_in[5];
  const float* Wpri = (const float*)d_in[6];
  const float* Wco  = (const float*)d_in[7];
  const float* bs   = (const float*)d_in[8];
  const float* Wout = (const float*)d_in[9];
  const float* bout = (const float*)d_in[10];
  const float* Wq   = (const float*)d_in[11];
  const float* Wk   = (const float*)d_in[12];
  const float* Wv   = (const float*)d_in[13];
  const float* Wo   = (const float*)d_in[14];
  const float* Wint = (const float*)d_in[15];
  const float* Wbyp = (const float*)d_in[16];
  const float* bbyp = (const float*)d_in[17];
  const float* c1w  = (const float*)d_in[18];
  const float* c1b  = (const float*)d_in[19];
  const float* c2w  = (const float*)d_in[20];
  const float* c2b  = (const float*)d_in[21];
  const float* Wa1  = (const float*)d_in[22];
  const float* ba1  = (const float*)d_in[23];
  const float* Wa2  = (const float*)d_in[24];
  const float* ba2  = (const float*)d_in[25];

  // layout identical in size to round 9: 3 plane-equivalents + smalls + BT + persist
  auto needB = [](int PB)->size_t{
    return ((size_t)PB*14755840 + 2792448) * 4;
  };
  const int PB = (ws_size >= needB(4)) ? 4 : (ws_size >= needB(2)) ? 2 : 1;

  float* ws = (float*)d_ws;
  const size_t PLF = (size_t)PB*4194304;           // one fp32 plane (floats)
  // plane-equivalent 0: fwd bf16 row-spectrum transient, then FULL_ph (fp32)
  ushort* FRre = (ushort*)ws;                      // [PLF] bf16
  ushort* FRim = FRre + PLF;                       // [PLF] bf16 (totals PLF floats)
  float*  PH4  = ws;                               // FULL_ph fp32 (after fwd FFT done)
  // plane-equivalents 1-2: bf16 amp/ph planes; later iFFT bf16 transient aliases
  ushort* ABV = (ushort*)(ws + PLF);
  ushort* PBV = ABV + PLF;
  ushort* ABI = PBV + PLF;
  ushort* PBI = ABI + PLF;
  ushort* IRre = ABV;                              // iFFT transient (planes dead)
  ushort* IRim = ABV + PLF;
  float* sm = ws + 3*PLF;
  float* hbuf  = sm; sm += (size_t)2*PB*524288;    // h; later aliased by paoa
  float* qbuf  = sm; sm += (size_t)2*PB*131072;
  float* kbuf  = sm; sm += (size_t)2*PB*131072;
  float* vbuf  = sm; sm += (size_t)2*PB*131072;
  float* obuf  = sm; sm += (size_t)2*PB*131072;
  float* score = sm; sm += (size_t)2*PB*4096;
  int*   idxb  = (int*)sm; sm += (size_t)2*PB*1024;
  float* pml   = sm; sm += (size_t)PB*65536;
  ushort* BTtok = (ushort*)sm;                     // [2][128][2048]
  ushort* BTbyp = BTtok + 524288;                  // [2][1024][2048]
  ushort* BTq   = BTbyp + 4194304;                 // [2][128][1024]
  ushort* BTk   = BTq + 262144;
  ushort* BTv   = BTk + 262144;
  sm += 2752512;
  float* pooled= sm; sm += 512;
  float* IP    = sm; sm += 1024;
  float* IPint = sm; sm += 1024;
  float* modg  = sm; sm += 256;
  float* modb  = sm; sm += 256;
  ushort* wtb = (ushort*)sm; sm += 36864;          // [2][9][64][64] bf16
  float* paoa = hbuf;

  kern_pool <<<512, 256, 0, stream>>>(vis, irf, pooled);
  kern_small<<<1, 256, 0, stream>>>(pooled, Wr, br, bank, Wpri, Wint,
                                    Wa1, ba1, Wa2, ba2, IP, IPint, modg, modb);
  kern_wt   <<<18, 256, 0, stream>>>(c1w, c2w, wtb);
  {
    TRS tr{};
    const float* srcs[10] = {Wtok, Wtok+262144, Wbyp, Wbyp+2097152,
                             Wq, Wq+131072, Wk, Wk+131072, Wv, Wv+131072};
    ushort* dsts[10] = {BTtok, BTtok+262144, BTbyp, BTbyp+2097152,
                        BTq, BTq+131072, BTk, BTk+131072, BTv, BTv+131072};
    int Ks[10] = {2048,2048,2048,2048,1024,1024,1024,1024,1024,1024};
    int Ns[10] = {128,128,1024,1024,128,128,128,128,128,128};
    int tiles[10] = {256,256,2048,2048,128,128,128,128,128,128};
    int acc0 = 0;
    for (int i = 0; i < 10; ++i){
      tr.src[i] = srcs[i]; tr.dst[i] = dsts[i];
      tr.K[i] = Ks[i]; tr.N[i] = Ns[i];
      tr.start[i] = acc0; acc0 += tiles[i];
    }
    tr.start[10] = acc0;
    kern_tr<<<acc0, 256, 0, stream>>>(tr);
  }

  for (int b0 = 0; b0 < 4; b0 += PB){
    const float* vis_b = vis + (size_t)b0*4194304;
    const float* ir_b  = irf + (size_t)b0*4194304;
    float* OUT = (float*)d_out + (size_t)b0*4194304;  // FULL_amp fp32 / spatial

    // forward FFT2 -> bf16 amp/ph (patchified); bf16 row-spectrum transient in FR
    kern_fft_rows_fwd<<<PB*8192, 256, 0, stream>>>(vis_b, FRre, FRim);
    kern_fft_cols<0> <<<PB*1024, 256, 0, stream>>>(FRre, FRim, ABV, PBV);
    kern_fft_rows_fwd<<<PB*8192, 256, 0, stream>>>(ir_b, FRre, FRim);
    kern_fft_cols<0> <<<PB*1024, 256, 0, stream>>>(FRre, FRim, ABI, PBI);

    {  // h = cat(vt,it)@Wtok + IP + coords@Wco + bs
      GP2 p{};
      p.A0[0]=ABV; p.A1[0]=ABI; p.A0[1]=PBV; p.A1[1]=PBI;
      for (int z = 0; z < 2; ++z){
        p.Bt[z] = BTtok + (size_t)z*262144;
        p.Cm[z] = hbuf + (size_t)z*PB*524288;
        p.ep0[z] = IP + z*512 + b0*128;
        p.ep1[z] = Wco + z*256;
        p.ep2[z] = bs + z*128;
      }
      p.N = 128; p.K = 2048;
      kern_mgemm2<1,1><<<dim3(PB*64, 1, 2), 256, 0, stream>>>(p);
    }
    kern_score<<<dim3(PB*4096, 2), 64, 0, stream>>>(hbuf, Wout, bout, score, PB*4096);
    kern_topk <<<2*PB, 1024, 0, stream>>>(score, idxb);
    {  // bypass blend -> FULL (amp: OUT fp32, ph: PH4 fp32 overwrites dead FR)
      GP2 p{};
      p.A0[0]=ABV; p.A1[0]=ABI; p.A0[1]=PBV; p.A1[1]=PBI;
      p.vt[0]=ABV; p.it[0]=ABI; p.vt[1]=PBV; p.it[1]=PBI;
      p.Cm[0]=OUT; p.Cm[1]=PH4;
      for (int z = 0; z < 2; ++z){
        p.Bt[z] = BTbyp + (size_t)z*2097152;
        p.ep0[z] = bbyp + z*1024;
      }
      p.N = 1024; p.K = 2048;
      kern_mgemm2<1,2><<<dim3(PB*64, 8, 2), 256, 0, stream>>>(p);
    }
    {  // q,k,v gathered rows
      GP2 p{};
      const ushort* Aplanes[6] = {ABV, ABI, ABI, PBV, PBI, PBI};
      const ushort* Bmats[6] = {BTq, BTk, BTv, BTq+131072, BTk+131072, BTv+131072};
      float* Cms[6] = {qbuf, kbuf, vbuf,
                       qbuf+(size_t)PB*131072, kbuf+(size_t)PB*131072,
                       vbuf+(size_t)PB*131072};
      for (int z = 0; z < 6; ++z){
        p.A0[z] = Aplanes[z]; p.Bt[z] = Bmats[z]; p.Cm[z] = Cms[z];
        p.idxp[z] = idxb + (z < 3 ? 0 : PB*1024);
      }
      p.N = 128; p.K = 1024;
      kern_mgemm2<2,0><<<dim3(PB*16, 1, 6), 256, 0, stream>>>(p);
    }
    // k-split flash attention (h dead -> paoa aliases hbuf)
    kern_attn_part<<<dim3(8, 4, 2*PB*4), 128, 0, stream>>>(qbuf, kbuf, vbuf,
                                                           paoa, pml);
    kern_attn_comb<<<dim3(4, 4, 2*PB), 256, 0, stream>>>(paoa, pml, obuf,
                                                         IPint, PB, b0);
    {  // fused_sel = vs(bf16) + o@Wo, scatter into FULL
      SCP p{};
      p.A0[0]=obuf; p.A0[1]=obuf+(size_t)PB*131072;
      p.Bm[0]=Wo; p.Bm[1]=Wo+131072;
      p.Cm[0]=OUT; p.Cm[1]=PH4;
      p.vtb[0]=ABV; p.vtb[1]=PBV;
      p.idxp[0]=idxb; p.idxp[1]=idxb+PB*1024;
      kern_scat<<<dim3(8, PB*16, 2), 256, 0, stream>>>(p);
    }

    // spec = famp*e^{i fph}; inverse FFT2 -> spatial into OUT
    // (bf16 amp/ph planes dead after scat -> IRre/IRim alias them)
    kern_ifft_rows_spec<<<PB*4096, 256, 0, stream>>>(OUT, PH4, IRre, IRim);
    kern_fft_cols<1>   <<<PB*1024, 256, 0, stream>>>(IRre, IRim, OUT, nullptr);
  }

  // convs (MFMA): d_out(spatial) -> ws[0..16.78M floats) (conv1+relu) -> d_out
  kern_cmfma<1><<<dim3(256, 4), 256, 0, stream>>>((float*)d_out, wtb, c1b, ws,
                                                  nullptr, nullptr, nullptr, nullptr);
  kern_cmfma<2><<<dim3(256, 4), 256, 0, stream>>>(ws, wtb + 36864, c2b, (float*)d_out,
                                                  modg, modb, vis, irf);
}

// Round 11
// 1410.507 us; speedup vs baseline: 1.0450x; 1.0450x over previous
//
#include <hip/hip_runtime.h>

typedef unsigned int uint;
typedef unsigned short ushort;
typedef unsigned long long u64;
typedef __attribute__((ext_vector_type(8))) short short8;
typedef __attribute__((ext_vector_type(4))) float f32x4;

__device__ __forceinline__ uint brev8(uint x){ return __brev(x) >> 24; }
__device__ __forceinline__ float geluf(float x){
  return 0.5f*x*(1.f + tanhf(0.7978845608028654f*(x + 0.044715f*x*x*x)));
}
__device__ __forceinline__ ushort f2bf(float f){
  unsigned u = __float_as_uint(f);
  unsigned r = u + 0x7FFFu + ((u >> 16) & 1u);
  return (ushort)(r >> 16);
}
__device__ __forceinline__ float bf2f(ushort u){
  return __uint_as_float((uint)u << 16);
}

// ---------------- pooled mean ----------------
__global__ __launch_bounds__(256) void kern_pool(const float* __restrict__ vis,
                                                 const float* __restrict__ irf,
                                                 float* __restrict__ pooled){
  __shared__ float red[256];
  int bc = blockIdx.x;
  int b = bc >> 7, cc = bc & 127;
  const float* src = (cc < 64) ? (vis + (size_t)(b*64+cc)*65536)
                               : (irf + (size_t)(b*64+(cc-64))*65536);
  float s = 0.f;
  for (int i = threadIdx.x; i < 65536; i += 256) s += src[i];
  red[threadIdx.x] = s;
  __syncthreads();
  for (int off = 128; off > 0; off >>= 1){
    if (threadIdx.x < off) red[threadIdx.x] += red[threadIdx.x + off];
    __syncthreads();
  }
  if (threadIdx.x == 0) pooled[bc] = red[0] * (1.f/65536.f);
}

// ---------------- prompt/intent/affine small ops ----------------
__global__ __launch_bounds__(256) void kern_small(const float* __restrict__ pooled,
    const float* __restrict__ Wr, const float* __restrict__ br,
    const float* __restrict__ bank, const float* __restrict__ Wpri,
    const float* __restrict__ Wint, const float* __restrict__ Wa1,
    const float* __restrict__ ba1, const float* __restrict__ Wa2,
    const float* __restrict__ ba2,
    float* __restrict__ IP, float* __restrict__ IPint,
    float* __restrict__ modg, float* __restrict__ modb){
  __shared__ float logit_s[16];
  __shared__ float pw_s[16];
  __shared__ float intent_s[4][64];
  __shared__ float t1_s[4][128];
  int t = threadIdx.x;
  if (t < 16){
    int b = t >> 2, j = t & 3;
    float s = br[j];
    for (int k = 0; k < 128; ++k) s += pooled[b*128+k]*Wr[k*4+j];
    logit_s[t] = s;
  }
  __syncthreads();
  if (t < 4){
    int b = t;
    float m = logit_s[b*4];
    for (int j = 1; j < 4; ++j) m = fmaxf(m, logit_s[b*4+j]);
    float e[4], sum = 0.f;
    for (int j = 0; j < 4; ++j){ e[j] = expf(logit_s[b*4+j]-m); sum += e[j]; }
    for (int j = 0; j < 4; ++j) pw_s[b*4+j] = e[j]/sum;
  }
  __syncthreads();
  {
    int b = t >> 6, p = t & 63;
    float s = 0.f;
    for (int j = 0; j < 4; ++j) s += pw_s[b*4+j]*bank[j*64+p];
    intent_s[b][p] = s;
  }
  __syncthreads();
  for (int o = t; o < 1024; o += 256){
    int i = o >> 9, rem = o & 511, b = rem >> 7, n = rem & 127;
    float s1 = 0.f, s2 = 0.f;
    for (int p = 0; p < 64; ++p){
      float iv = intent_s[b][p];
      s1 += iv * Wpri[(i*64+p)*128 + n];
      s2 += iv * Wint[(i*64+p)*128 + n];
    }
    IP[o] = s1; IPint[o] = s2;
  }
  for (int o = t; o < 512; o += 256){
    int b = o >> 7, n = o & 127;
    float s = ba1[n];
    for (int p = 0; p < 64; ++p) s += intent_s[b][p]*Wa1[p*128+n];
    t1_s[b][n] = geluf(s);
  }
  __syncthreads();
  for (int o = t; o < 512; o += 256){
    int b = o >> 7, n = o & 127;
    float s = ba2[n];
    for (int p = 0; p < 128; ++p) s += t1_s[b][p]*Wa2[p*128+n];
    if (n < 64) modg[b*64+n] = 1.f + 0.1f*tanhf(s);
    else        modb[b*64+(n-64)] = 0.1f*s;
  }
}

// ---------------- forward row FFT (fp32 transients) ----------------
__global__ __launch_bounds__(256) void kern_fft_rows_fwd(const float* __restrict__ x,
    float* __restrict__ sre, float* __restrict__ sim){
  __shared__ float re[2][256], im[2][256];
  __shared__ float twr[128], twi[128];
  int t = threadIdx.x;
  if (t < 128){
    float a = -6.2831853071795864f * (float)t * (1.f/256.f);
    sincosf(a, &twi[t], &twr[t]);
  }
  int r = t >> 7, jj = t & 127;
  size_t row = (size_t)blockIdx.x*2 + r;
  {
    const float* xp = x + row*256;
    re[r][jj] = xp[jj]; re[r][jj+128] = xp[jj+128];
    im[r][jj] = 0.f;    im[r][jj+128] = 0.f;
  }
  __syncthreads();
  for (int s = 0; s < 8; ++s){
    int half = 128 >> s;
    int j = jj & (half-1);
    int g = jj >> (7-s);
    int k = (g << (8-s)) + j;
    int m = j << s;
    float wc = twr[m], ws = twi[m];
    float are = re[r][k],      aim = im[r][k];
    float bre = re[r][k+half], bim = im[r][k+half];
    re[r][k] = are + bre; im[r][k] = aim + bim;
    float tr = are - bre, ti = aim - bim;
    re[r][k+half] = tr*wc - ti*ws;
    im[r][k+half] = tr*ws + ti*wc;
    __syncthreads();
  }
  {
    float* orp = sre + row*256; float* oip = sim + row*256;
    int w1 = jj, w2 = jj + 128;
    orp[w1] = re[r][brev8(w1)]; oip[w1] = im[r][brev8(w1)];
    orp[w2] = re[r][brev8(w2)]; oip[w2] = im[r][brev8(w2)];
  }
}

// ---------------- inverse row FFT with spec construction (fp32) ----------------
__global__ __launch_bounds__(256) void kern_ifft_rows_spec(const float* __restrict__ famp,
    const float* __restrict__ fph, float* __restrict__ sre, float* __restrict__ sim){
  __shared__ float re[4][256], im[4][256];
  __shared__ float twr[128], twi[128];
  int t = threadIdx.x;
  if (t < 128){
    float a = -6.2831853071795864f * (float)t * (1.f/256.f);
    sincosf(a, &twi[t], &twr[t]);
  }
  int R = blockIdx.x * 4;
  {
    int r = t >> 6, q = t & 63;
    int row = R + r;
    int bc = row >> 8, h = row & 255;
    int b = bc >> 6, c = bc & 63;
    size_t addr = ((size_t)(b*4096 + (h>>2)*64 + q))*1024 + c*16 + (h&3)*4;
    float4 a4 = *(const float4*)(famp + addr);
    float4 p4 = *(const float4*)(fph + addr);
    float sn, cs;
    sincosf(p4.x, &sn, &cs); re[r][4*q+0] = a4.x*cs; im[r][4*q+0] = a4.x*sn;
    sincosf(p4.y, &sn, &cs); re[r][4*q+1] = a4.y*cs; im[r][4*q+1] = a4.y*sn;
    sincosf(p4.z, &sn, &cs); re[r][4*q+2] = a4.z*cs; im[r][4*q+2] = a4.z*sn;
    sincosf(p4.w, &sn, &cs); re[r][4*q+3] = a4.w*cs; im[r][4*q+3] = a4.w*sn;
  }
  __syncthreads();
  for (int s = 0; s < 8; ++s){
    int half = 128 >> s;
    #pragma unroll
    for (int bi0 = 0; bi0 < 2; ++bi0){
      int bi = t + bi0*256;
      int r = bi >> 7, tj = bi & 127;
      int j = tj & (half-1);
      int g = tj >> (7-s);
      int k = (g << (8-s)) + j;
      int m = j << s;
      float wc = twr[m], ws = -twi[m];
      float are = re[r][k],      aim = im[r][k];
      float bre = re[r][k+half], bim = im[r][k+half];
      re[r][k] = are + bre; im[r][k] = aim + bim;
      float tr = are - bre, ti = aim - bim;
      re[r][k+half] = tr*wc - ti*ws;
      im[r][k+half] = tr*ws + ti*wc;
    }
    __syncthreads();
  }
  {
    int r = t >> 6, q = t & 63;
    size_t row = (size_t)R + r;
    float4 vr, vi;
    vr.x = re[r][brev8(4*q+0)]; vi.x = im[r][brev8(4*q+0)];
    vr.y = re[r][brev8(4*q+1)]; vi.y = im[r][brev8(4*q+1)];
    vr.z = re[r][brev8(4*q+2)]; vi.z = im[r][brev8(4*q+2)];
    vr.w = re[r][brev8(4*q+3)]; vi.w = im[r][brev8(4*q+3)];
    *(float4*)(sre + row*256 + 4*q) = vr;
    *(float4*)(sim + row*256 + 4*q) = vi;
  }
}

// ---------------- column FFT: fp32 in; DIR=0 bf16 amp/ph out, DIR=1 fp32 out ------
template<int DIR>
__global__ __launch_bounds__(256) void kern_fft_cols(const float* __restrict__ sre,
    const float* __restrict__ sim, void* __restrict__ out0, void* __restrict__ out1){
  __shared__ float reL[256*17];
  __shared__ float imL[256*17];
  __shared__ float twr[128], twi[128];
  int t = threadIdx.x;
  if (t < 128){
    float a = -6.2831853071795864f * (float)t * (1.f/256.f);
    sincosf(a, &twi[t], &twr[t]);
  }
  int img = blockIdx.x >> 4;
  int c0 = (blockIdx.x & 15) * 16;
  {
    const float* pr = sre + ((size_t)img*256 + t)*256 + c0;
    const float* pi = sim + ((size_t)img*256 + t)*256 + c0;
    #pragma unroll
    for (int p = 0; p < 4; ++p){
      float4 vr = *(const float4*)(pr + 4*p);
      float4 vi = *(const float4*)(pi + 4*p);
      int base = t*17 + 4*p;
      reL[base+0]=vr.x; reL[base+1]=vr.y; reL[base+2]=vr.z; reL[base+3]=vr.w;
      imL[base+0]=vi.x; imL[base+1]=vi.y; imL[base+2]=vi.z; imL[base+3]=vi.w;
    }
  }
  __syncthreads();
  int col = t & 15, tb = t >> 4;
  for (int s = 0; s < 8; ++s){
    int half = 128 >> s;
    #pragma unroll
    for (int it = 0; it < 8; ++it){
      int tj = tb + it*16;
      int j = tj & (half-1);
      int g = tj >> (7-s);
      int k = (g << (8-s)) + j;
      int m = j << s;
      float wc = twr[m];
      float ws = (DIR == 0) ? twi[m] : -twi[m];
      int i0 = k*17 + col, i1 = (k+half)*17 + col;
      float are = reL[i0], aim = imL[i0];
      float bre = reL[i1], bim = imL[i1];
      reL[i0] = are + bre; imL[i0] = aim + bim;
      float tr = are - bre, ti = aim - bim;
      reL[i1] = tr*wc - ti*ws;
      imL[i1] = tr*ws + ti*wc;
    }
    __syncthreads();
  }
  int b = img >> 6, c = img & 63;
  int h = t; int src = (int)brev8((uint)h);
  if (DIR == 0){
    ushort* oa = (ushort*)out0;
    ushort* op = (ushort*)out1;
    int gy = h >> 2, py = h & 3;
    #pragma unroll
    for (int p = 0; p < 4; ++p){
      int base = src*17 + 4*p;
      float a0, a1, a2, a3, p0, p1, p2, p3;
      float rr, ii;
      rr = reL[base+0]; ii = imL[base+0]; a0 = sqrtf(rr*rr+ii*ii); p0 = atan2f(ii, rr);
      rr = reL[base+1]; ii = imL[base+1]; a1 = sqrtf(rr*rr+ii*ii); p1 = atan2f(ii, rr);
      rr = reL[base+2]; ii = imL[base+2]; a2 = sqrtf(rr*rr+ii*ii); p2 = atan2f(ii, rr);
      rr = reL[base+3]; ii = imL[base+3]; a3 = sqrtf(rr*rr+ii*ii); p3 = atan2f(ii, rr);
      size_t addr = ((size_t)(b*4096 + gy*64 + (c0>>2) + p))*1024 + c*16 + py*4;
      uint2 av, pv;
      av.x = (uint)f2bf(a0) | ((uint)f2bf(a1) << 16);
      av.y = (uint)f2bf(a2) | ((uint)f2bf(a3) << 16);
      pv.x = (uint)f2bf(p0) | ((uint)f2bf(p1) << 16);
      pv.y = (uint)f2bf(p2) | ((uint)f2bf(p3) << 16);
      *(uint2*)(oa + addr) = av;
      *(uint2*)(op + addr) = pv;
    }
  } else {
    float* op = (float*)out0 + ((size_t)img*256 + h)*256 + c0;
    #pragma unroll
    for (int p = 0; p < 4; ++p){
      int base = src*17 + 4*p;
      float4 v;
      v.x = reL[base+0]*(1.f/65536.f);
      v.y = reL[base+1]*(1.f/65536.f);
      v.z = reL[base+2]*(1.f/65536.f);
      v.w = reL[base+3]*(1.f/65536.f);
      *(float4*)(op + 4*p) = v;
    }
  }
}

// ---------------- transpose-convert: fp32 [K][N] -> bf16 [N][K], 10 mats ----------
struct TRS {
  const float* src[10];
  ushort* dst[10];
  int K[10], N[10];
  int start[11];
};
__global__ __launch_bounds__(256) void kern_tr(TRS p){
  __shared__ float lds[32][33];
  int bid = blockIdx.x;
  int e = 0;
  while (bid >= p.start[e+1]) ++e;
  int tloc = bid - p.start[e];
  int tilesN = p.N[e] >> 5;
  int tn = tloc % tilesN, tk = tloc / tilesN;
  int k0 = tk << 5, n0 = tn << 5;
  const float* src = p.src[e];
  ushort* dst = p.dst[e];
  int K = p.K[e], N = p.N[e];
  int r = threadIdx.x >> 5, c = threadIdx.x & 31;
  #pragma unroll
  for (int i = 0; i < 4; ++i)
    lds[r + 8*i][c] = src[(size_t)(k0 + r + 8*i)*N + n0 + c];
  __syncthreads();
  #pragma unroll
  for (int i = 0; i < 4; ++i)
    dst[(size_t)(n0 + r + 8*i)*K + k0 + c] = f2bf(lds[c][r + 8*i]);
}

// ---------------- mgemm2: BM=64 BN=128 BK=64, bf16 A + bf16 B^T, swizzled LDS -----
// AMODE: 2 gather rows via idx.  EPI: 0 plain store.
struct GP2 {
  const ushort* A0[6];
  const ushort* Bt[6];
  float* Cm[6];
  const int* idxp[6];
  int N, K;
};

__global__ __launch_bounds__(256) void kern_mgemm2(GP2 p){
  __shared__ __align__(16) ushort Asb[64*64];
  __shared__ __align__(16) ushort Bsb[128*64];
  __shared__ int idx_s[64];
  int z = blockIdx.z;
  const ushort* A0 = p.A0[z];
  const ushort* Bt = p.Bt[z];
  float* Cm = p.Cm[z];
  int tid = threadIdx.x;
  int m0 = blockIdx.x * 64;
  int n0 = blockIdx.y * 128;
  int lane = tid & 63, w = tid >> 6;
  int wr = w & 1, wc = w >> 1;
  int lr = lane & 15, ql = lane >> 4;

  if (tid < 64){
    int m = m0 + tid;
    idx_s[tid] = p.idxp[z][(m >> 10)*1024 + (m & 1023)];
  }
  __syncthreads();
  int gb = m0 >> 10;

  f32x4 acc[2][4];
  #pragma unroll
  for (int i = 0; i < 2; ++i)
    #pragma unroll
    for (int j = 0; j < 4; ++j) acc[i][j] = (f32x4){0.f,0.f,0.f,0.f};

  int kh = tid & 7;
  int rA = tid >> 3;
  for (int k0 = 0; k0 < p.K; k0 += 64){
    #pragma unroll
    for (int s = 0; s < 2; ++s){
      int m = rA + 32*s;
      const ushort* ap = A0 + ((size_t)(gb << 12) + idx_s[m])*(size_t)p.K + k0 + kh*8;
      short8 v = *(const short8*)ap;
      int byte = m*128 + ((kh*16) ^ ((m & 7)*16));
      *(short8*)((char*)Asb + byte) = v;
    }
    #pragma unroll
    for (int s = 0; s < 4; ++s){
      int n = rA + 32*s;
      short8 v = *(const short8*)(Bt + (size_t)(n0+n)*p.K + k0 + kh*8);
      int byte = n*128 + ((kh*16) ^ ((n & 7)*16));
      *(short8*)((char*)Bsb + byte) = v;
    }
    __syncthreads();
    short8 af[2][2], bf[4][2];
    #pragma unroll
    for (int fm = 0; fm < 2; ++fm){
      int row = wr*32 + fm*16 + lr;
      #pragma unroll
      for (int kq = 0; kq < 2; ++kq){
        int byte = row*128 + ((kq*64 + ql*16) ^ ((row & 7)*16));
        af[fm][kq] = *(const short8*)((const char*)Asb + byte);
      }
    }
    #pragma unroll
    for (int fn = 0; fn < 4; ++fn){
      int row = wc*64 + fn*16 + lr;
      #pragma unroll
      for (int kq = 0; kq < 2; ++kq){
        int byte = row*128 + ((kq*64 + ql*16) ^ ((row & 7)*16));
        bf[fn][kq] = *(const short8*)((const char*)Bsb + byte);
      }
    }
    #pragma unroll
    for (int kq = 0; kq < 2; ++kq)
      #pragma unroll
      for (int fm = 0; fm < 2; ++fm)
        #pragma unroll
        for (int fn = 0; fn < 4; ++fn)
          acc[fm][fn] = __builtin_amdgcn_mfma_f32_16x16x32_bf16(af[fm][kq], bf[fn][kq],
                                                                acc[fm][fn], 0, 0, 0);
    __syncthreads();
  }

  #pragma unroll
  for (int fm = 0; fm < 2; ++fm){
    #pragma unroll
    for (int fn = 0; fn < 4; ++fn){
      int n = n0 + wc*64 + fn*16 + lr;
      #pragma unroll
      for (int reg = 0; reg < 4; ++reg){
        int m = m0 + wr*32 + fm*16 + ql*4 + reg;
        Cm[(size_t)m*p.N + n] = acc[fm][fn][reg];
      }
    }
  }
}

// ---------------- mgemm3: FUSED h + bypass, BM=128 BN=128 BK=64, N=1152 -----------
// blockIdx.y == 0 -> h-epilogue (cols 0..127); else bypass sigmoid-blend (cols-128).
struct GP3 {
  const ushort* A0[2];
  const ushort* A1[2];
  const ushort* Bt[2];
  float* Ch[2];
  float* Cm[2];
  const float* ep0[2];
  const float* ep1[2];
  const float* ep2[2];
  const float* bias[2];
  const ushort* vt[2];
  const ushort* it[2];
  int K;
};

__global__ __launch_bounds__(256) void kern_mgemm3(GP3 p){
  __shared__ __align__(16) ushort Asb[128*64];
  __shared__ __align__(16) ushort Bsb[128*64];
  int z = blockIdx.z;
  const ushort* Bt = p.Bt[z];
  int tid = threadIdx.x;
  int m0 = blockIdx.x * 128;
  int n0 = blockIdx.y * 128;
  int lane = tid & 63, w = tid >> 6;
  int wr = w & 1, wc = w >> 1;
  int lr = lane & 15, ql = lane >> 4;

  f32x4 acc[4][4];
  #pragma unroll
  for (int i = 0; i < 4; ++i)
    #pragma unroll
    for (int j = 0; j < 4; ++j) acc[i][j] = (f32x4){0.f,0.f,0.f,0.f};

  int kh = tid & 7;
  int rA = tid >> 3;
  for (int k0 = 0; k0 < p.K; k0 += 64){
    const ushort* Asrc = (k0 < 1024) ? p.A0[z] : p.A1[z];
    int kk = (k0 & 1023) + kh*8;
    #pragma unroll
    for (int s = 0; s < 4; ++s){
      int m = rA + 32*s;
      short8 v = *(const short8*)(Asrc + (size_t)(m0+m)*1024 + kk);
      int byte = m*128 + ((kh*16) ^ ((m & 7)*16));
      *(short8*)((char*)Asb + byte) = v;
    }
    #pragma unroll
    for (int s = 0; s < 4; ++s){
      int n = rA + 32*s;
      short8 v = *(const short8*)(Bt + (size_t)(n0+n)*p.K + k0 + kh*8);
      int byte = n*128 + ((kh*16) ^ ((n & 7)*16));
      *(short8*)((char*)Bsb + byte) = v;
    }
    __syncthreads();
    short8 af[4][2], bf[4][2];
    #pragma unroll
    for (int fm = 0; fm < 4; ++fm){
      int row = wr*64 + fm*16 + lr;
      #pragma unroll
      for (int kq = 0; kq < 2; ++kq){
        int byte = row*128 + ((kq*64 + ql*16) ^ ((row & 7)*16));
        af[fm][kq] = *(const short8*)((const char*)Asb + byte);
      }
    }
    #pragma unroll
    for (int fn = 0; fn < 4; ++fn){
      int row = wc*64 + fn*16 + lr;
      #pragma unroll
      for (int kq = 0; kq < 2; ++kq){
        int byte = row*128 + ((kq*64 + ql*16) ^ ((row & 7)*16));
        bf[fn][kq] = *(const short8*)((const char*)Bsb + byte);
      }
    }
    #pragma unroll
    for (int kq = 0; kq < 2; ++kq)
      #pragma unroll
      for (int fm = 0; fm < 4; ++fm)
        #pragma unroll
        for (int fn = 0; fn < 4; ++fn)
          acc[fm][fn] = __builtin_amdgcn_mfma_f32_16x16x32_bf16(af[fm][kq], bf[fn][kq],
                                                                acc[fm][fn], 0, 0, 0);
    __syncthreads();
  }

  if (blockIdx.y == 0){
    float* Ch = p.Ch[z];
    #pragma unroll
    for (int fm = 0; fm < 4; ++fm){
      #pragma unroll
      for (int fn = 0; fn < 4; ++fn){
        int n = wc*64 + fn*16 + lr;
        #pragma unroll
        for (int reg = 0; reg < 4; ++reg){
          int m = m0 + wr*64 + fm*16 + ql*4 + reg;
          int bl = m >> 12, g = m & 4095;
          int gy = g >> 6, gx = g & 63;
          float cy = ((float)gy + 0.5f)*(1.f/64.f);
          float cx = ((float)gx + 0.5f)*(1.f/64.f);
          float o = acc[fm][fn][reg] + p.ep0[z][bl*128 + n] + cy*p.ep1[z][n]
                  + cx*p.ep1[z][128 + n] + p.ep2[z][n];
          Ch[(size_t)m*128 + n] = o;
        }
      }
    }
  } else {
    float* Cm = p.Cm[z];
    const ushort* vtp = p.vt[z];
    const ushort* itp = p.it[z];
    int nb = n0 - 128;
    #pragma unroll
    for (int fm = 0; fm < 4; ++fm){
      #pragma unroll
      for (int fn = 0; fn < 4; ++fn){
        int n = nb + wc*64 + fn*16 + lr;
        float bia = p.bias[z][n];
        #pragma unroll
        for (int reg = 0; reg < 4; ++reg){
          int m = m0 + wr*64 + fm*16 + ql*4 + reg;
          size_t off = (size_t)m*1024 + n;
          float vt = bf2f(vtp[off]);
          float it = bf2f(itp[off]);
          float gg = 1.f/(1.f + expf(-(acc[fm][fn][reg] + bia)));
          Cm[off] = gg*vt + (1.f-gg)*it;
        }
      }
    }
  }
}

// ---------------- scatter GEMM: fused_sel = vs(bf16) + o@Wo, K=128 ----------------
struct SCP {
  const float* A0[2];
  const float* Bm[2];
  float* Cm[2];
  const int* idxp[2];
  const ushort* vtb[2];
};

__global__ __launch_bounds__(256) void kern_scat(SCP p){
  __shared__ __align__(16) ushort Asb[64*40];
  __shared__ __align__(16) ushort Bsb[128*40];
  __shared__ int idx_s[64];
  int z = blockIdx.z;
  const float* A0 = p.A0[z];
  const float* Bm = p.Bm[z];
  float* Cm = p.Cm[z];
  int tid = threadIdx.x;
  int m0 = blockIdx.y * 64;
  int n0 = blockIdx.x * 128;
  int lane = tid & 63, w = tid >> 6;
  int wr = w & 1, wc = w >> 1;
  int lr = lane & 15, ql = lane >> 4;
  if (tid < 64){
    int m = m0 + tid;
    idx_s[tid] = p.idxp[z][(m >> 10)*1024 + (m & 1023)];
  }
  __syncthreads();
  int gb = m0 >> 10;

  f32x4 acc[2][4];
  #pragma unroll
  for (int i = 0; i < 2; ++i)
    #pragma unroll
    for (int j = 0; j < 4; ++j) acc[i][j] = (f32x4){0.f,0.f,0.f,0.f};

  for (int k0 = 0; k0 < 128; k0 += 32){
    {
      int m = tid & 63;
      int khh = (tid >> 6) * 8;
      const float* ap = A0 + (size_t)(m0+m)*128 + k0 + khh;
      float4 f0 = *(const float4*)ap;
      float4 f1 = *(const float4*)(ap + 4);
      short8 v;
      v[0]=(short)f2bf(f0.x); v[1]=(short)f2bf(f0.y);
      v[2]=(short)f2bf(f0.z); v[3]=(short)f2bf(f0.w);
      v[4]=(short)f2bf(f1.x); v[5]=(short)f2bf(f1.y);
      v[6]=(short)f2bf(f1.z); v[7]=(short)f2bf(f1.w);
      *(short8*)&Asb[m*40 + khh] = v;
    }
    #pragma unroll
    for (int e0 = 0; e0 < 512; e0 += 256){
      int e = e0 + tid;
      int n = e & 127;
      int khh = (e >> 7) * 8;
      const float* bp = Bm + (size_t)(k0+khh)*1024 + n0 + n;
      short8 v;
      #pragma unroll
      for (int j = 0; j < 8; ++j) v[j] = (short)f2bf(bp[(size_t)j*1024]);
      *(short8*)&Bsb[n*40 + khh] = v;
    }
    __syncthreads();
    short8 af[2], bf[4];
    #pragma unroll
    for (int fr = 0; fr < 2; ++fr)
      af[fr] = *(const short8*)&Asb[(wr*32 + fr*16 + lr)*40 + ql*8];
    #pragma unroll
    for (int fc = 0; fc < 4; ++fc)
      bf[fc] = *(const short8*)&Bsb[(wc*64 + fc*16 + lr)*40 + ql*8];
    #pragma unroll
    for (int fr = 0; fr < 2; ++fr)
      #pragma unroll
      for (int fc = 0; fc < 4; ++fc)
        acc[fr][fc] = __builtin_amdgcn_mfma_f32_16x16x32_bf16(af[fr], bf[fc],
                                                              acc[fr][fc], 0, 0, 0);
    __syncthreads();
  }

  #pragma unroll
  for (int fr = 0; fr < 2; ++fr){
    #pragma unroll
    for (int fc = 0; fc < 4; ++fc){
      int n = n0 + wc*64 + fc*16 + lr;
      #pragma unroll
      for (int reg = 0; reg < 4; ++reg){
        int mloc = wr*32 + fr*16 + ql*4 + reg;
        int gt = idx_s[mloc];
        size_t off = ((size_t)(gb << 12) + gt)*1024 + n;
        Cm[off] = acc[fr][fc][reg] + bf2f(p.vtb[z][off]);
      }
    }
  }
}

// ---------------- score ----------------
__global__ __launch_bounds__(64) void kern_score(const float* __restrict__ h,
    const float* __restrict__ wout, const float* __restrict__ bout,
    float* __restrict__ score, int Mper){
  int m = blockIdx.x, br = blockIdx.y, t = threadIdx.x;
  const float* hp = h + ((size_t)br*Mper + m)*128;
  const float* wp = wout + br*128;
  float s = geluf(hp[t])*wp[t] + geluf(hp[t+64])*wp[t+64];
  #pragma unroll
  for (int off = 32; off > 0; off >>= 1) s += __shfl_down(s, off);
  if (t == 0) score[(size_t)br*Mper + m] = s + bout[br];
}

// ---------------- top-1024 of 4096 (bitonic, jax tie-break) ----------------
__global__ __launch_bounds__(1024) void kern_topk(const float* __restrict__ score,
    int* __restrict__ idx_out){
  __shared__ u64 keys[4096];
  int b = blockIdx.x, t = threadIdx.x;
  for (int i = t; i < 4096; i += 1024){
    float s = score[b*4096 + i];
    uint u = __float_as_uint(s);
    uint msk = (u & 0x80000000u) ? ~u : (u | 0x80000000u);
    keys[i] = ((u64)msk << 32) | (uint)(4095 - i);
  }
  __syncthreads();
  for (int k = 2; k <= 4096; k <<= 1){
    for (int j = k >> 1; j > 0; j >>= 1){
      for (int i = t; i < 4096; i += 1024){
        int l = i ^ j;
        if (l > i){
          u64 a = keys[i], c = keys[l];
          bool descB = ((i & k) == 0);
          bool sw = descB ? (a < c) : (a > c);
          if (sw){ keys[i] = c; keys[l] = a; }
        }
      }
      __syncthreads();
    }
  }
  idx_out[b*1024 + t] = 4095 - (int)(keys[t] & 0xFFFFFFFFu);
}

// ---------------- attention partials (k-split flash, 128-thr q-split) ----------
__global__ __launch_bounds__(128) void kern_attn_part(const float* __restrict__ qb,
    const float* __restrict__ kb, const float* __restrict__ vb,
    float* __restrict__ paoa, float* __restrict__ pml){
  __shared__ float Ks[64][32];
  __shared__ float Vs[64][32];
  int t = threadIdx.x;
  int hh = blockIdx.y;
  int zc = blockIdx.z;
  int zf = zc >> 2, c = zc & 3;
  size_t boff = (size_t)zf*131072;
  int jq = blockIdx.x*128 + t;
  float qv[32];
  {
    const float4* qp = (const float4*)(qb + boff + (size_t)jq*128 + hh*32);
    #pragma unroll
    for (int d = 0; d < 8; ++d) ((float4*)qv)[d] = qp[d];
  }
  float mrun = -3.0e38f, lrun = 0.f;
  float oa[32];
  #pragma unroll
  for (int d = 0; d < 32; ++d) oa[d] = 0.f;
  for (int kt = 0; kt < 4; ++kt){
    int k0 = c*256 + kt*64;
    #pragma unroll
    for (int rep = 0; rep < 4; ++rep){
      int f = t + rep*128;
      int r = f >> 3, q4 = f & 7;
      size_t base = boff + (size_t)(k0 + r)*128 + hh*32 + 4*q4;
      *(float4*)&Ks[r][4*q4] = *(const float4*)(kb + base);
      *(float4*)&Vs[r][4*q4] = *(const float4*)(vb + base);
    }
    __syncthreads();
    #pragma unroll
    for (int st = 0; st < 4; ++st){
      float s[16];
      #pragma unroll
      for (int j = 0; j < 16; ++j){
        float v = 0.f;
        #pragma unroll
        for (int d = 0; d < 32; ++d) v += qv[d]*Ks[st*16+j][d];
        s[j] = v * 0.17677669529663687f;
      }
      float mt = s[0];
      #pragma unroll
      for (int j = 1; j < 16; ++j) mt = fmaxf(mt, s[j]);
      float mnew = fmaxf(mrun, mt);
      float alpha = expf(mrun - mnew);
      lrun *= alpha;
      #pragma unroll
      for (int d = 0; d < 32; ++d) oa[d] *= alpha;
      #pragma unroll
      for (int j = 0; j < 16; ++j){
        float pe = expf(s[j] - mnew);
        lrun += pe;
        #pragma unroll
        for (int d = 0; d < 32; ++d) oa[d] += pe*Vs[st*16+j][d];
      }
      mrun = mnew;
    }
    __syncthreads();
  }
  size_t rec = (((size_t)zf*4 + hh)*4 + c)*1024 + jq;
  float* pp = paoa + rec*32;
  #pragma unroll
  for (int d = 0; d < 8; ++d) ((float4*)pp)[d] = ((float4*)oa)[d];
  pml[rec*2]   = mrun;
  pml[rec*2+1] = lrun;
}

// ---------------- attention combine ----------------
__global__ __launch_bounds__(256) void kern_attn_comb(const float* __restrict__ paoa,
    const float* __restrict__ pml, float* __restrict__ ob,
    const float* __restrict__ ipint, int PB, int b0){
  int t = threadIdx.x;
  int hh = blockIdx.y, zf = blockIdx.z;
  int jq = blockIdx.x*256 + t;
  size_t rbase = (((size_t)zf*4 + hh)*4)*1024 + jq;
  float mc[4], lc[4];
  #pragma unroll
  for (int c = 0; c < 4; ++c){
    mc[c] = pml[(rbase + c*1024)*2];
    lc[c] = pml[(rbase + c*1024)*2 + 1];
  }
  float M = fmaxf(fmaxf(mc[0], mc[1]), fmaxf(mc[2], mc[3]));
  float wgt[4], L = 0.f;
  #pragma unroll
  for (int c = 0; c < 4; ++c){ wgt[c] = expf(mc[c] - M); L += lc[c]*wgt[c]; }
  float inv = 1.f/L;
  int br = (zf >= PB) ? 1 : 0;
  int bb = zf - br*PB;
  const float* ip = ipint + br*512 + (b0+bb)*128 + hh*32;
  float* op = ob + (size_t)zf*131072 + (size_t)jq*128 + hh*32;
  #pragma unroll
  for (int d = 0; d < 32; ++d){
    float o = 0.f;
    #pragma unroll
    for (int c = 0; c < 4; ++c) o += paoa[(rbase + c*1024)*32 + d]*wgt[c];
    op[d] = o*inv + ip[d];
  }
}

// ---------------- conv weight transform ----------------
__global__ __launch_bounds__(256) void kern_wt(const float* __restrict__ w1,
    const float* __restrict__ w2, ushort* __restrict__ wt){
  int blk = blockIdx.x;
  const float* src = (blk < 9) ? w1 : w2;
  int tap = blk - (blk < 9 ? 0 : 9);
  ushort* dst = wt + (blk < 9 ? 0 : 36864) + tap*4096;
  for (int e = threadIdx.x; e < 4096; e += 256){
    dst[e] = f2bf(src[(size_t)e*9 + tap]);
  }
}

// ---------------- implicit-GEMM 3x3 conv via MFMA ----------------
template<int MODE>
__global__ __launch_bounds__(256) void kern_cmfma(const float* __restrict__ in,
    const ushort* __restrict__ wt, const float* __restrict__ bias,
    float* __restrict__ out,
    const float* __restrict__ modg, const float* __restrict__ modb,
    const float* __restrict__ vis, const float* __restrict__ irf){
  __shared__ __align__(16) ushort ins[64][268];
  int t = threadIdx.x;
  int y = blockIdx.x, b = blockIdx.y;
  int lane = t & 63, w = t >> 6;
  int wc = w & 1, wx = w >> 1;
  int lr = lane & 15, ql = lane >> 4;

  f32x4 acc[2][8];
  #pragma unroll
  for (int f = 0; f < 2; ++f)
    #pragma unroll
    for (int xf = 0; xf < 8; ++xf) acc[f][xf] = (f32x4){0.f,0.f,0.f,0.f};

  for (int dy = 0; dy < 3; ++dy){
    int yy = y + dy - 1;
    if (yy < 0 || yy > 255) continue;
    const float* src = in + ((size_t)(b*64)*256 + yy)*256;
    #pragma unroll
    for (int s = 0; s < 16; ++s){
      int e = t + s*256;
      int ci = e >> 6, q = e & 63;
      float4 f4 = *(const float4*)(src + (size_t)ci*65536 + 4*q);
      uint lo = (uint)f2bf(f4.x) | ((uint)f2bf(f4.y) << 16);
      uint hi = (uint)f2bf(f4.z) | ((uint)f2bf(f4.w) << 16);
      *(uint2*)&ins[ci][4*q + 4] = make_uint2(lo, hi);
    }
    if (t < 128){
      int r = t & 63;
      ins[r][(t >> 6) ? 260 : 3] = 0;
    }
    __syncthreads();
    short8 wf[2][3][2];
    #pragma unroll
    for (int kk = 0; kk < 2; ++kk)
      #pragma unroll
      for (int dx = 0; dx < 3; ++dx)
        #pragma unroll
        for (int f = 0; f < 2; ++f)
          wf[kk][dx][f] = *(const short8*)(wt +
            (size_t)((dy*3 + dx)*64 + 32*wc + 16*f + lr)*64 + kk*32 + ql*8);
    #pragma unroll
    for (int kk = 0; kk < 2; ++kk){
      const ushort* bp = &ins[kk*32 + ql*8][0];
      #pragma unroll
      for (int dx = 0; dx < 3; ++dx){
        int xb = 128*wx + lr + dx + 3;
        #pragma unroll
        for (int xf = 0; xf < 8; ++xf){
          int xi = xb + 16*xf;
          short8 bf;
          #pragma unroll
          for (int e = 0; e < 8; ++e) bf[e] = (short)bp[e*268 + xi];
          acc[0][xf] = __builtin_amdgcn_mfma_f32_16x16x32_bf16(wf[kk][dx][0], bf,
                                                               acc[0][xf], 0, 0, 0);
          acc[1][xf] = __builtin_amdgcn_mfma_f32_16x16x32_bf16(wf[kk][dx][1], bf,
                                                               acc[1][xf], 0, 0, 0);
        }
      }
    }
    __syncthreads();
  }

  #pragma unroll
  for (int f = 0; f < 2; ++f){
    #pragma unroll
    for (int xf = 0; xf < 8; ++xf){
      int x = 128*wx + 16*xf + lr;
      #pragma unroll
      for (int reg = 0; reg < 4; ++reg){
        int co = 32*wc + 16*f + ql*4 + reg;
        float v = acc[f][xf][reg] + bias[co];
        size_t oi = ((size_t)(b*64 + co)*256 + y)*256 + x;
        if (MODE == 1){
          out[oi] = fmaxf(v, 0.f);
        } else {
          out[oi] = v*modg[b*64+co] + modb[b*64+co] + 0.5f*(vis[oi] + irf[oi]);
        }
      }
    }
  }
}

// ---------------- launch ----------------
extern "C" void kernel_launch(void* const* d_in, const int* in_sizes, int n_in,
                              void* d_out, int out_size, void* d_ws, size_t ws_size,
                              hipStream_t stream){
  (void)in_sizes; (void)n_in; (void)out_size;
  const float* vis  = (const float*)d_in[0];
  const float* irf  = (const float*)d_in[1];
  const float* bank = (const float*)d_in[2];
  const float* Wr   = (const float*)d_in[3];
  const float* br   = (const float*)d_in[4];
  const float* Wtok = (const float*)d_in[5];
  const float* Wpri = (const float*)d_in[6];
  const float* Wco  = (const float*)d_in[7];
  const float* bs   = (const float*)d_in[8];
  const float* Wout = (const float*)d_in[9];
  const float* bout = (const float*)d_in[10];
  const float* Wq   = (const float*)d_in[11];
  const float* Wk   = (const float*)d_in[12];
  const float* Wv   = (const float*)d_in[13];
  const float* Wo   = (const float*)d_in[14];
  const float* Wint = (const float*)d_in[15];
  const float* Wbyp = (const float*)d_in[16];
  const float* bbyp = (const float*)d_in[17];
  const float* c1w  = (const float*)d_in[18];
  const float* c1b  = (const float*)d_in[19];
  const float* c2w  = (const float*)d_in[20];
  const float* c2b  = (const float*)d_in[21];
  const float* Wa1  = (const float*)d_in[22];
  const float* ba1  = (const float*)d_in[23];
  const float* Wa2  = (const float*)d_in[24];
  const float* ba2  = (const float*)d_in[25];

  // layout identical in size to round 9
  auto needB = [](int PB)->size_t{
    return ((size_t)PB*14755840 + 2792448) * 4;
  };
  const int PB = (ws_size >= needB(4)) ? 4 : (ws_size >= needB(2)) ? 2 : 1;

  float* ws = (float*)d_ws;
  const size_t PLF = (size_t)PB*4194304;           // one fp32 plane (floats)
  float* PH4 = ws;                                 // fwd im transient + FULL_ph (fp32)
  ushort* ABV = (ushort*)(ws + PLF);               // 4 bf16 planes = 2*PLF floats
  ushort* PBV = ABV + PLF;
  ushort* ABI = PBV + PLF;
  ushort* PBI = ABI + PLF;
  float* S0 = ws + PLF;                            // iFFT fp32 transients ALIAS bf16 region
  float* S1 = S0 + PLF;
  float* sm = ws + 3*PLF;
  float* hbuf  = sm; sm += (size_t)2*PB*524288;    // h; later aliased by paoa
  float* qbuf  = sm; sm += (size_t)2*PB*131072;
  float* kbuf  = sm; sm += (size_t)2*PB*131072;
  float* vbuf  = sm; sm += (size_t)2*PB*131072;
  float* obuf  = sm; sm += (size_t)2*PB*131072;
  float* score = sm; sm += (size_t)2*PB*4096;
  int*   idxb  = (int*)sm; sm += (size_t)2*PB*1024;
  float* pml   = sm; sm += (size_t)PB*65536;
  ushort* BTcomb = (ushort*)sm;                    // [2][1152][2048] (Wtok|Wbyp cols)
  ushort* BTq    = BTcomb + 4718592;               // [2][128][1024]
  ushort* BTk    = BTq + 262144;
  ushort* BTv    = BTk + 262144;
  sm += 2752512;
  float* pooled= sm; sm += 512;
  float* IP    = sm; sm += 1024;
  float* IPint = sm; sm += 1024;
  float* modg  = sm; sm += 256;
  float* modb  = sm; sm += 256;
  ushort* wtb = (ushort*)sm; sm += 36864;          // [2][9][64][64] bf16
  float* paoa = hbuf;

  kern_pool <<<512, 256, 0, stream>>>(vis, irf, pooled);
  kern_small<<<1, 256, 0, stream>>>(pooled, Wr, br, bank, Wpri, Wint,
                                    Wa1, ba1, Wa2, ba2, IP, IPint, modg, modb);
  kern_wt   <<<18, 256, 0, stream>>>(c1w, c2w, wtb);
  {
    TRS tr{};
    const float* srcs[10] = {Wtok, Wtok+262144, Wbyp, Wbyp+2097152,
                             Wq, Wq+131072, Wk, Wk+131072, Wv, Wv+131072};
    ushort* dsts[10] = {BTcomb, BTcomb+2359296, BTcomb+262144, BTcomb+2359296+262144,
                        BTq, BTq+131072, BTk, BTk+131072, BTv, BTv+131072};
    int Ks[10] = {2048,2048,2048,2048,1024,1024,1024,1024,1024,1024};
    int Ns[10] = {128,128,1024,1024,128,128,128,128,128,128};
    int tiles[10] = {256,256,2048,2048,128,128,128,128,128,128};
    int acc0 = 0;
    for (int i = 0; i < 10; ++i){
      tr.src[i] = srcs[i]; tr.dst[i] = dsts[i];
      tr.K[i] = Ks[i]; tr.N[i] = Ns[i];
      tr.start[i] = acc0; acc0 += tiles[i];
    }
    tr.start[10] = acc0;
    kern_tr<<<acc0, 256, 0, stream>>>(tr);
  }

  for (int b0 = 0; b0 < 4; b0 += PB){
    const float* vis_b = vis + (size_t)b0*4194304;
    const float* ir_b  = irf + (size_t)b0*4194304;
    float* OUT = (float*)d_out + (size_t)b0*4194304;  // re transient / FULL_amp / spatial

    // forward FFT2 -> bf16 amp/ph (patchified), fp32 transients
    kern_fft_rows_fwd<<<PB*8192, 256, 0, stream>>>(vis_b, OUT, PH4);
    kern_fft_cols<0> <<<PB*1024, 256, 0, stream>>>(OUT, PH4, ABV, PBV);
    kern_fft_rows_fwd<<<PB*8192, 256, 0, stream>>>(ir_b, OUT, PH4);
    kern_fft_cols<0> <<<PB*1024, 256, 0, stream>>>(OUT, PH4, ABI, PBI);

    {  // FUSED h-GEMM + bypass blend (N=1152: y=0 -> h, y>=1 -> blend)
      GP3 p{};
      p.A0[0]=ABV; p.A1[0]=ABI; p.A0[1]=PBV; p.A1[1]=PBI;
      p.vt[0]=ABV; p.it[0]=ABI; p.vt[1]=PBV; p.it[1]=PBI;
      p.Cm[0]=OUT; p.Cm[1]=PH4;
      for (int z = 0; z < 2; ++z){
        p.Bt[z] = BTcomb + (size_t)z*2359296;
        p.Ch[z] = hbuf + (size_t)z*PB*524288;
        p.ep0[z] = IP + z*512 + b0*128;
        p.ep1[z] = Wco + z*256;
        p.ep2[z] = bs + z*128;
        p.bias[z] = bbyp + z*1024;
      }
      p.K = 2048;
      kern_mgemm3<<<dim3(PB*32, 9, 2), 256, 0, stream>>>(p);
    }
    kern_score<<<dim3(PB*4096, 2), 64, 0, stream>>>(hbuf, Wout, bout, score, PB*4096);
    kern_topk <<<2*PB, 1024, 0, stream>>>(score, idxb);
    {  // q,k,v gathered rows
      GP2 p{};
      const ushort* Aplanes[6] = {ABV, ABI, ABI, PBV, PBI, PBI};
      const ushort* Bmats[6] = {BTq, BTk, BTv, BTq+131072, BTk+131072, BTv+131072};
      float* Cms[6] = {qbuf, kbuf, vbuf,
                       qbuf+(size_t)PB*131072, kbuf+(size_t)PB*131072,
                       vbuf+(size_t)PB*131072};
      for (int z = 0; z < 6; ++z){
        p.A0[z] = Aplanes[z]; p.Bt[z] = Bmats[z]; p.Cm[z] = Cms[z];
        p.idxp[z] = idxb + (z < 3 ? 0 : PB*1024);
      }
      p.N = 128; p.K = 1024;
      kern_mgemm2<<<dim3(PB*16, 1, 6), 256, 0, stream>>>(p);
    }
    // k-split flash attention (h dead -> paoa aliases hbuf)
    kern_attn_part<<<dim3(8, 4, 2*PB*4), 128, 0, stream>>>(qbuf, kbuf, vbuf,
                                                           paoa, pml);
    kern_attn_comb<<<dim3(4, 4, 2*PB), 256, 0, stream>>>(paoa, pml, obuf,
                                                         IPint, PB, b0);
    {  // fused_sel = vs(bf16) + o@Wo, scatter into FULL
      SCP p{};
      p.A0[0]=obuf; p.A0[1]=obuf+(size_t)PB*131072;
      p.Bm[0]=Wo; p.Bm[1]=Wo+131072;
      p.Cm[0]=OUT; p.Cm[1]=PH4;
      p.vtb[0]=ABV; p.vtb[1]=PBV;
      p.idxp[0]=idxb; p.idxp[1]=idxb+PB*1024;
      kern_scat<<<dim3(8, PB*16, 2), 256, 0, stream>>>(p);
    }

    // spec = famp*e^{i fph}; inverse FFT2 -> spatial into OUT
    // (bf16 amp/ph planes dead after scat -> S0/S1 alias them)
    kern_ifft_rows_spec<<<PB*4096, 256, 0, stream>>>(OUT, PH4, S0, S1);
    kern_fft_cols<1>   <<<PB*1024, 256, 0, stream>>>(S0, S1, OUT, nullptr);
  }

  // convs (MFMA): d_out(spatial) -> ws[0..16.78M floats) (conv1+relu) -> d_out
  kern_cmfma<1><<<dim3(256, 4), 256, 0, stream>>>((float*)d_out, wtb, c1b, ws,
                                                  nullptr, nullptr, nullptr, nullptr);
  kern_cmfma<2><<<dim3(256, 4), 256, 0, stream>>>(ws, wtb + 36864, c2b, (float*)d_out,
                                                  modg, modb, vis, irf);
}

// Round 12
// 1365.410 us; speedup vs baseline: 1.0795x; 1.0330x over previous
//
#include <hip/hip_runtime.h>

typedef unsigned int uint;
typedef unsigned short ushort;
typedef unsigned long long u64;
typedef __attribute__((ext_vector_type(8))) short short8;
typedef __attribute__((ext_vector_type(4))) float f32x4;

__device__ __forceinline__ uint brev8(uint x){ return __brev(x) >> 24; }
__device__ __forceinline__ float geluf(float x){
  return 0.5f*x*(1.f + tanhf(0.7978845608028654f*(x + 0.044715f*x*x*x)));
}
__device__ __forceinline__ ushort f2bf(float f){
  unsigned u = __float_as_uint(f);
  unsigned r = u + 0x7FFFu + ((u >> 16) & 1u);
  return (ushort)(r >> 16);
}
__device__ __forceinline__ float bf2f(ushort u){
  return __uint_as_float((uint)u << 16);
}

// ---------------- pooled mean ----------------
__global__ __launch_bounds__(256) void kern_pool(const float* __restrict__ vis,
                                                 const float* __restrict__ irf,
                                                 float* __restrict__ pooled){
  __shared__ float red[256];
  int bc = blockIdx.x;
  int b = bc >> 7, cc = bc & 127;
  const float* src = (cc < 64) ? (vis + (size_t)(b*64+cc)*65536)
                               : (irf + (size_t)(b*64+(cc-64))*65536);
  float s = 0.f;
  for (int i = threadIdx.x; i < 65536; i += 256) s += src[i];
  red[threadIdx.x] = s;
  __syncthreads();
  for (int off = 128; off > 0; off >>= 1){
    if (threadIdx.x < off) red[threadIdx.x] += red[threadIdx.x + off];
    __syncthreads();
  }
  if (threadIdx.x == 0) pooled[bc] = red[0] * (1.f/65536.f);
}

// ---------------- prompt/intent/affine small ops ----------------
__global__ __launch_bounds__(256) void kern_small(const float* __restrict__ pooled,
    const float* __restrict__ Wr, const float* __restrict__ br,
    const float* __restrict__ bank, const float* __restrict__ Wpri,
    const float* __restrict__ Wint, const float* __restrict__ Wa1,
    const float* __restrict__ ba1, const float* __restrict__ Wa2,
    const float* __restrict__ ba2,
    float* __restrict__ IP, float* __restrict__ IPint,
    float* __restrict__ modg, float* __restrict__ modb){
  __shared__ float logit_s[16];
  __shared__ float pw_s[16];
  __shared__ float intent_s[4][64];
  __shared__ float t1_s[4][128];
  int t = threadIdx.x;
  if (t < 16){
    int b = t >> 2, j = t & 3;
    float s = br[j];
    for (int k = 0; k < 128; ++k) s += pooled[b*128+k]*Wr[k*4+j];
    logit_s[t] = s;
  }
  __syncthreads();
  if (t < 4){
    int b = t;
    float m = logit_s[b*4];
    for (int j = 1; j < 4; ++j) m = fmaxf(m, logit_s[b*4+j]);
    float e[4], sum = 0.f;
    for (int j = 0; j < 4; ++j){ e[j] = expf(logit_s[b*4+j]-m); sum += e[j]; }
    for (int j = 0; j < 4; ++j) pw_s[b*4+j] = e[j]/sum;
  }
  __syncthreads();
  {
    int b = t >> 6, p = t & 63;
    float s = 0.f;
    for (int j = 0; j < 4; ++j) s += pw_s[b*4+j]*bank[j*64+p];
    intent_s[b][p] = s;
  }
  __syncthreads();
  for (int o = t; o < 1024; o += 256){
    int i = o >> 9, rem = o & 511, b = rem >> 7, n = rem & 127;
    float s1 = 0.f, s2 = 0.f;
    for (int p = 0; p < 64; ++p){
      float iv = intent_s[b][p];
      s1 += iv * Wpri[(i*64+p)*128 + n];
      s2 += iv * Wint[(i*64+p)*128 + n];
    }
    IP[o] = s1; IPint[o] = s2;
  }
  for (int o = t; o < 512; o += 256){
    int b = o >> 7, n = o & 127;
    float s = ba1[n];
    for (int p = 0; p < 64; ++p) s += intent_s[b][p]*Wa1[p*128+n];
    t1_s[b][n] = geluf(s);
  }
  __syncthreads();
  for (int o = t; o < 512; o += 256){
    int b = o >> 7, n = o & 127;
    float s = ba2[n];
    for (int p = 0; p < 128; ++p) s += t1_s[b][p]*Wa2[p*128+n];
    if (n < 64) modg[b*64+n] = 1.f + 0.1f*tanhf(s);
    else        modb[b*64+(n-64)] = 0.1f*s;
  }
}

// ---------------- forward row FFT (fp32 transients) ----------------
__global__ __launch_bounds__(256) void kern_fft_rows_fwd(const float* __restrict__ x,
    float* __restrict__ sre, float* __restrict__ sim){
  __shared__ float re[2][256], im[2][256];
  __shared__ float twr[128], twi[128];
  int t = threadIdx.x;
  if (t < 128){
    float a = -6.2831853071795864f * (float)t * (1.f/256.f);
    sincosf(a, &twi[t], &twr[t]);
  }
  int r = t >> 7, jj = t & 127;
  size_t row = (size_t)blockIdx.x*2 + r;
  {
    const float* xp = x + row*256;
    re[r][jj] = xp[jj]; re[r][jj+128] = xp[jj+128];
    im[r][jj] = 0.f;    im[r][jj+128] = 0.f;
  }
  __syncthreads();
  for (int s = 0; s < 8; ++s){
    int half = 128 >> s;
    int j = jj & (half-1);
    int g = jj >> (7-s);
    int k = (g << (8-s)) + j;
    int m = j << s;
    float wc = twr[m], ws = twi[m];
    float are = re[r][k],      aim = im[r][k];
    float bre = re[r][k+half], bim = im[r][k+half];
    re[r][k] = are + bre; im[r][k] = aim + bim;
    float tr = are - bre, ti = aim - bim;
    re[r][k+half] = tr*wc - ti*ws;
    im[r][k+half] = tr*ws + ti*wc;
    __syncthreads();
  }
  {
    float* orp = sre + row*256; float* oip = sim + row*256;
    int w1 = jj, w2 = jj + 128;
    orp[w1] = re[r][brev8(w1)]; oip[w1] = im[r][brev8(w1)];
    orp[w2] = re[r][brev8(w2)]; oip[w2] = im[r][brev8(w2)];
  }
}

// ---------------- inverse row FFT with spec construction (fp32) ----------------
__global__ __launch_bounds__(256) void kern_ifft_rows_spec(const float* __restrict__ famp,
    const float* __restrict__ fph, float* __restrict__ sre, float* __restrict__ sim){
  __shared__ float re[4][256], im[4][256];
  __shared__ float twr[128], twi[128];
  int t = threadIdx.x;
  if (t < 128){
    float a = -6.2831853071795864f * (float)t * (1.f/256.f);
    sincosf(a, &twi[t], &twr[t]);
  }
  int R = blockIdx.x * 4;
  {
    int r = t >> 6, q = t & 63;
    int row = R + r;
    int bc = row >> 8, h = row & 255;
    int b = bc >> 6, c = bc & 63;
    size_t addr = ((size_t)(b*4096 + (h>>2)*64 + q))*1024 + c*16 + (h&3)*4;
    float4 a4 = *(const float4*)(famp + addr);
    float4 p4 = *(const float4*)(fph + addr);
    float sn, cs;
    sincosf(p4.x, &sn, &cs); re[r][4*q+0] = a4.x*cs; im[r][4*q+0] = a4.x*sn;
    sincosf(p4.y, &sn, &cs); re[r][4*q+1] = a4.y*cs; im[r][4*q+1] = a4.y*sn;
    sincosf(p4.z, &sn, &cs); re[r][4*q+2] = a4.z*cs; im[r][4*q+2] = a4.z*sn;
    sincosf(p4.w, &sn, &cs); re[r][4*q+3] = a4.w*cs; im[r][4*q+3] = a4.w*sn;
  }
  __syncthreads();
  for (int s = 0; s < 8; ++s){
    int half = 128 >> s;
    #pragma unroll
    for (int bi0 = 0; bi0 < 2; ++bi0){
      int bi = t + bi0*256;
      int r = bi >> 7, tj = bi & 127;
      int j = tj & (half-1);
      int g = tj >> (7-s);
      int k = (g << (8-s)) + j;
      int m = j << s;
      float wc = twr[m], ws = -twi[m];
      float are = re[r][k],      aim = im[r][k];
      float bre = re[r][k+half], bim = im[r][k+half];
      re[r][k] = are + bre; im[r][k] = aim + bim;
      float tr = are - bre, ti = aim - bim;
      re[r][k+half] = tr*wc - ti*ws;
      im[r][k+half] = tr*ws + ti*wc;
    }
    __syncthreads();
  }
  {
    int r = t >> 6, q = t & 63;
    size_t row = (size_t)R + r;
    float4 vr, vi;
    vr.x = re[r][brev8(4*q+0)]; vi.x = im[r][brev8(4*q+0)];
    vr.y = re[r][brev8(4*q+1)]; vi.y = im[r][brev8(4*q+1)];
    vr.z = re[r][brev8(4*q+2)]; vi.z = im[r][brev8(4*q+2)];
    vr.w = re[r][brev8(4*q+3)]; vi.w = im[r][brev8(4*q+3)];
    *(float4*)(sre + row*256 + 4*q) = vr;
    *(float4*)(sim + row*256 + 4*q) = vi;
  }
}

// ---------------- column FFT: fp32 in; DIR=0 bf16 amp/ph out, DIR=1 fp32 out ------
template<int DIR>
__global__ __launch_bounds__(256) void kern_fft_cols(const float* __restrict__ sre,
    const float* __restrict__ sim, void* __restrict__ out0, void* __restrict__ out1){
  __shared__ float reL[256*17];
  __shared__ float imL[256*17];
  __shared__ float twr[128], twi[128];
  int t = threadIdx.x;
  if (t < 128){
    float a = -6.2831853071795864f * (float)t * (1.f/256.f);
    sincosf(a, &twi[t], &twr[t]);
  }
  int img = blockIdx.x >> 4;
  int c0 = (blockIdx.x & 15) * 16;
  {
    const float* pr = sre + ((size_t)img*256 + t)*256 + c0;
    const float* pi = sim + ((size_t)img*256 + t)*256 + c0;
    #pragma unroll
    for (int p = 0; p < 4; ++p){
      float4 vr = *(const float4*)(pr + 4*p);
      float4 vi = *(const float4*)(pi + 4*p);
      int base = t*17 + 4*p;
      reL[base+0]=vr.x; reL[base+1]=vr.y; reL[base+2]=vr.z; reL[base+3]=vr.w;
      imL[base+0]=vi.x; imL[base+1]=vi.y; imL[base+2]=vi.z; imL[base+3]=vi.w;
    }
  }
  __syncthreads();
  int col = t & 15, tb = t >> 4;
  for (int s = 0; s < 8; ++s){
    int half = 128 >> s;
    #pragma unroll
    for (int it = 0; it < 8; ++it){
      int tj = tb + it*16;
      int j = tj & (half-1);
      int g = tj >> (7-s);
      int k = (g << (8-s)) + j;
      int m = j << s;
      float wc = twr[m];
      float ws = (DIR == 0) ? twi[m] : -twi[m];
      int i0 = k*17 + col, i1 = (k+half)*17 + col;
      float are = reL[i0], aim = imL[i0];
      float bre = reL[i1], bim = imL[i1];
      reL[i0] = are + bre; imL[i0] = aim + bim;
      float tr = are - bre, ti = aim - bim;
      reL[i1] = tr*wc - ti*ws;
      imL[i1] = tr*ws + ti*wc;
    }
    __syncthreads();
  }
  int b = img >> 6, c = img & 63;
  int h = t; int src = (int)brev8((uint)h);
  if (DIR == 0){
    ushort* oa = (ushort*)out0;
    ushort* op = (ushort*)out1;
    int gy = h >> 2, py = h & 3;
    #pragma unroll
    for (int p = 0; p < 4; ++p){
      int base = src*17 + 4*p;
      float a0, a1, a2, a3, p0, p1, p2, p3;
      float rr, ii;
      rr = reL[base+0]; ii = imL[base+0]; a0 = sqrtf(rr*rr+ii*ii); p0 = atan2f(ii, rr);
      rr = reL[base+1]; ii = imL[base+1]; a1 = sqrtf(rr*rr+ii*ii); p1 = atan2f(ii, rr);
      rr = reL[base+2]; ii = imL[base+2]; a2 = sqrtf(rr*rr+ii*ii); p2 = atan2f(ii, rr);
      rr = reL[base+3]; ii = imL[base+3]; a3 = sqrtf(rr*rr+ii*ii); p3 = atan2f(ii, rr);
      size_t addr = ((size_t)(b*4096 + gy*64 + (c0>>2) + p))*1024 + c*16 + py*4;
      uint2 av, pv;
      av.x = (uint)f2bf(a0) | ((uint)f2bf(a1) << 16);
      av.y = (uint)f2bf(a2) | ((uint)f2bf(a3) << 16);
      pv.x = (uint)f2bf(p0) | ((uint)f2bf(p1) << 16);
      pv.y = (uint)f2bf(p2) | ((uint)f2bf(p3) << 16);
      *(uint2*)(oa + addr) = av;
      *(uint2*)(op + addr) = pv;
    }
  } else {
    float* op = (float*)out0 + ((size_t)img*256 + h)*256 + c0;
    #pragma unroll
    for (int p = 0; p < 4; ++p){
      int base = src*17 + 4*p;
      float4 v;
      v.x = reL[base+0]*(1.f/65536.f);
      v.y = reL[base+1]*(1.f/65536.f);
      v.z = reL[base+2]*(1.f/65536.f);
      v.w = reL[base+3]*(1.f/65536.f);
      *(float4*)(op + 4*p) = v;
    }
  }
}

// ---------------- transpose-convert: fp32 [K][N] -> bf16 [N][K], 10 mats ----------
struct TRS {
  const float* src[10];
  ushort* dst[10];
  int K[10], N[10];
  int start[11];
};
__global__ __launch_bounds__(256) void kern_tr(TRS p){
  __shared__ float lds[32][33];
  int bid = blockIdx.x;
  int e = 0;
  while (bid >= p.start[e+1]) ++e;
  int tloc = bid - p.start[e];
  int tilesN = p.N[e] >> 5;
  int tn = tloc % tilesN, tk = tloc / tilesN;
  int k0 = tk << 5, n0 = tn << 5;
  const float* src = p.src[e];
  ushort* dst = p.dst[e];
  int K = p.K[e], N = p.N[e];
  int r = threadIdx.x >> 5, c = threadIdx.x & 31;
  #pragma unroll
  for (int i = 0; i < 4; ++i)
    lds[r + 8*i][c] = src[(size_t)(k0 + r + 8*i)*N + n0 + c];
  __syncthreads();
  #pragma unroll
  for (int i = 0; i < 4; ++i)
    dst[(size_t)(n0 + r + 8*i)*K + k0 + c] = f2bf(lds[c][r + 8*i]);
}

// ---------------- mgemm2: BM=64 BN=128 BK=64, bf16 A + bf16 B^T (qkv gather) -----
struct GP2 {
  const ushort* A0[6];
  const ushort* Bt[6];
  float* Cm[6];
  const int* idxp[6];
  int N, K;
};

__global__ __launch_bounds__(256) void kern_mgemm2(GP2 p){
  __shared__ __align__(16) ushort Asb[64*64];
  __shared__ __align__(16) ushort Bsb[128*64];
  __shared__ int idx_s[64];
  int z = blockIdx.z;
  const ushort* A0 = p.A0[z];
  const ushort* Bt = p.Bt[z];
  float* Cm = p.Cm[z];
  int tid = threadIdx.x;
  int m0 = blockIdx.x * 64;
  int n0 = blockIdx.y * 128;
  int lane = tid & 63, w = tid >> 6;
  int wr = w & 1, wc = w >> 1;
  int lr = lane & 15, ql = lane >> 4;

  if (tid < 64){
    int m = m0 + tid;
    idx_s[tid] = p.idxp[z][(m >> 10)*1024 + (m & 1023)];
  }
  __syncthreads();
  int gb = m0 >> 10;

  f32x4 acc[2][4];
  #pragma unroll
  for (int i = 0; i < 2; ++i)
    #pragma unroll
    for (int j = 0; j < 4; ++j) acc[i][j] = (f32x4){0.f,0.f,0.f,0.f};

  int kh = tid & 7;
  int rA = tid >> 3;
  for (int k0 = 0; k0 < p.K; k0 += 64){
    #pragma unroll
    for (int s = 0; s < 2; ++s){
      int m = rA + 32*s;
      const ushort* ap = A0 + ((size_t)(gb << 12) + idx_s[m])*(size_t)p.K + k0 + kh*8;
      short8 v = *(const short8*)ap;
      int byte = m*128 + ((kh*16) ^ ((m & 7)*16));
      *(short8*)((char*)Asb + byte) = v;
    }
    #pragma unroll
    for (int s = 0; s < 4; ++s){
      int n = rA + 32*s;
      short8 v = *(const short8*)(Bt + (size_t)(n0+n)*p.K + k0 + kh*8);
      int byte = n*128 + ((kh*16) ^ ((n & 7)*16));
      *(short8*)((char*)Bsb + byte) = v;
    }
    __syncthreads();
    short8 af[2][2], bf[4][2];
    #pragma unroll
    for (int fm = 0; fm < 2; ++fm){
      int row = wr*32 + fm*16 + lr;
      #pragma unroll
      for (int kq = 0; kq < 2; ++kq){
        int byte = row*128 + ((kq*64 + ql*16) ^ ((row & 7)*16));
        af[fm][kq] = *(const short8*)((const char*)Asb + byte);
      }
    }
    #pragma unroll
    for (int fn = 0; fn < 4; ++fn){
      int row = wc*64 + fn*16 + lr;
      #pragma unroll
      for (int kq = 0; kq < 2; ++kq){
        int byte = row*128 + ((kq*64 + ql*16) ^ ((row & 7)*16));
        bf[fn][kq] = *(const short8*)((const char*)Bsb + byte);
      }
    }
    #pragma unroll
    for (int kq = 0; kq < 2; ++kq)
      #pragma unroll
      for (int fm = 0; fm < 2; ++fm)
        #pragma unroll
        for (int fn = 0; fn < 4; ++fn)
          acc[fm][fn] = __builtin_amdgcn_mfma_f32_16x16x32_bf16(af[fm][kq], bf[fn][kq],
                                                                acc[fm][fn], 0, 0, 0);
    __syncthreads();
  }

  #pragma unroll
  for (int fm = 0; fm < 2; ++fm){
    #pragma unroll
    for (int fn = 0; fn < 4; ++fn){
      int n = n0 + wc*64 + fn*16 + lr;
      #pragma unroll
      for (int reg = 0; reg < 4; ++reg){
        int m = m0 + wr*32 + fm*16 + ql*4 + reg;
        Cm[(size_t)m*p.N + n] = acc[fm][fn][reg];
      }
    }
  }
}

// ---------------- hscore: h-GEMM (N=128) + fused gelu@Wout score reduction --------
struct HSP {
  const ushort* A0[2];
  const ushort* A1[2];
  const ushort* Bt[2];
  float* score;                 // [2][Mper]
  const float* ep0[2];
  const float* ep1[2];
  const float* ep2[2];
  const float* wout;            // [2][128]
  const float* bout;            // [2]
  int Mper;
};

__global__ __launch_bounds__(256) void kern_hscore(HSP p){
  __shared__ __align__(16) ushort Asb[128*64];
  __shared__ __align__(16) ushort Bsb[128*64];
  __shared__ float part[2][128];
  int z = blockIdx.z;
  const ushort* Bt = p.Bt[z];
  int tid = threadIdx.x;
  int m0 = blockIdx.x * 128;
  int lane = tid & 63, w = tid >> 6;
  int wr = w & 1, wc = w >> 1;
  int lr = lane & 15, ql = lane >> 4;

  f32x4 acc[4][4];
  #pragma unroll
  for (int i = 0; i < 4; ++i)
    #pragma unroll
    for (int j = 0; j < 4; ++j) acc[i][j] = (f32x4){0.f,0.f,0.f,0.f};

  int kh = tid & 7;
  int rA = tid >> 3;
  for (int k0 = 0; k0 < 2048; k0 += 64){
    const ushort* Asrc = (k0 < 1024) ? p.A0[z] : p.A1[z];
    int kk = (k0 & 1023) + kh*8;
    #pragma unroll
    for (int s = 0; s < 4; ++s){
      int m = rA + 32*s;
      short8 v = *(const short8*)(Asrc + (size_t)(m0+m)*1024 + kk);
      int byte = m*128 + ((kh*16) ^ ((m & 7)*16));
      *(short8*)((char*)Asb + byte) = v;
    }
    #pragma unroll
    for (int s = 0; s < 4; ++s){
      int n = rA + 32*s;
      short8 v = *(const short8*)(Bt + (size_t)n*2048 + k0 + kh*8);
      int byte = n*128 + ((kh*16) ^ ((n & 7)*16));
      *(short8*)((char*)Bsb + byte) = v;
    }
    __syncthreads();
    short8 af[4][2], bf[4][2];
    #pragma unroll
    for (int fm = 0; fm < 4; ++fm){
      int row = wr*64 + fm*16 + lr;
      #pragma unroll
      for (int kq = 0; kq < 2; ++kq){
        int byte = row*128 + ((kq*64 + ql*16) ^ ((row & 7)*16));
        af[fm][kq] = *(const short8*)((const char*)Asb + byte);
      }
    }
    #pragma unroll
    for (int fn = 0; fn < 4; ++fn){
      int row = wc*64 + fn*16 + lr;
      #pragma unroll
      for (int kq = 0; kq < 2; ++kq){
        int byte = row*128 + ((kq*64 + ql*16) ^ ((row & 7)*16));
        bf[fn][kq] = *(const short8*)((const char*)Bsb + byte);
      }
    }
    #pragma unroll
    for (int kq = 0; kq < 2; ++kq)
      #pragma unroll
      for (int fm = 0; fm < 4; ++fm)
        #pragma unroll
        for (int fn = 0; fn < 4; ++fn)
          acc[fm][fn] = __builtin_amdgcn_mfma_f32_16x16x32_bf16(af[fm][kq], bf[fn][kq],
                                                                acc[fm][fn], 0, 0, 0);
    __syncthreads();
  }

  // epilogue: h = acc + IP + coords@Wco + bs; partial = sum_fn gelu(h)*wout[col]
  float wv[4];
  #pragma unroll
  for (int fn = 0; fn < 4; ++fn) wv[fn] = p.wout[z*128 + wc*64 + fn*16 + lr];
  #pragma unroll
  for (int fm = 0; fm < 4; ++fm){
    #pragma unroll
    for (int reg = 0; reg < 4; ++reg){
      int m = m0 + wr*64 + fm*16 + ql*4 + reg;
      int bl = m >> 12, g = m & 4095;
      int gy = g >> 6, gx = g & 63;
      float cy = ((float)gy + 0.5f)*(1.f/64.f);
      float cx = ((float)gx + 0.5f)*(1.f/64.f);
      float ps = 0.f;
      #pragma unroll
      for (int fn = 0; fn < 4; ++fn){
        int n = wc*64 + fn*16 + lr;
        float o = acc[fm][fn][reg] + p.ep0[z][bl*128 + n] + cy*p.ep1[z][n]
                + cx*p.ep1[z][128 + n] + p.ep2[z][n];
        ps += geluf(o)*wv[fn];
      }
      #pragma unroll
      for (int off = 8; off > 0; off >>= 1) ps += __shfl_xor(ps, off);
      if (lr == 0) part[wc][wr*64 + fm*16 + ql*4 + reg] = ps;
    }
  }
  __syncthreads();
  if (tid < 128)
    p.score[(size_t)z*p.Mper + m0 + tid] = part[0][tid] + part[1][tid] + p.bout[z];
}

// ---------------- nsel: complement of top-1024 -> 3072 gather list ----------------
__global__ __launch_bounds__(1024) void kern_nsel(const int* __restrict__ idxb,
    int* __restrict__ nsel){
  __shared__ unsigned char mask[4096];
  __shared__ int cnt;
  int b = blockIdx.x, t = threadIdx.x;
  *(uint*)&mask[4*t] = 0;
  if (t == 0) cnt = 0;
  __syncthreads();
  mask[idxb[b*1024 + t]] = 1;
  __syncthreads();
  for (int i = t; i < 4096; i += 1024){
    if (!mask[i]){
      int pos = atomicAdd(&cnt, 1);
      nsel[(size_t)b*3072 + pos] = i;
    }
  }
}

// ---------------- byp: gather bypass blend over 3072 non-selected rows -----------
// BM=128 BN=128 BK=64, cat(A0|A1) via gathered rows.
struct BYP {
  const ushort* A0[2];
  const ushort* A1[2];
  const ushort* Bt[2];
  float* Cm[2];
  const int* nsel[2];          // [PB][3072]
  const float* bias[2];
  const ushort* vt[2];
  const ushort* it[2];
};

__global__ __launch_bounds__(256) void kern_byp(BYP p){
  __shared__ __align__(16) ushort Asb[128*64];
  __shared__ __align__(16) ushort Bsb[128*64];
  __shared__ int idx_s[128];
  int z = blockIdx.z;
  const ushort* Bt = p.Bt[z];
  int tid = threadIdx.x;
  int gb  = blockIdx.x / 24;          // batch within group
  int m0l = (blockIdx.x % 24) * 128;  // row offset within batch's 3072 list
  int n0 = blockIdx.y * 128;
  int lane = tid & 63, w = tid >> 6;
  int wr = w & 1, wc = w >> 1;
  int lr = lane & 15, ql = lane >> 4;

  if (tid < 128)
    idx_s[tid] = p.nsel[z][(size_t)gb*3072 + m0l + tid];
  __syncthreads();

  f32x4 acc[4][4];
  #pragma unroll
  for (int i = 0; i < 4; ++i)
    #pragma unroll
    for (int j = 0; j < 4; ++j) acc[i][j] = (f32x4){0.f,0.f,0.f,0.f};

  int kh = tid & 7;
  int rA = tid >> 3;
  for (int k0 = 0; k0 < 2048; k0 += 64){
    const ushort* Asrc = (k0 < 1024) ? p.A0[z] : p.A1[z];
    int kk = (k0 & 1023) + kh*8;
    #pragma unroll
    for (int s = 0; s < 4; ++s){
      int m = rA + 32*s;
      size_t grow = (size_t)(gb << 12) + idx_s[m];
      short8 v = *(const short8*)(Asrc + grow*1024 + kk);
      int byte = m*128 + ((kh*16) ^ ((m & 7)*16));
      *(short8*)((char*)Asb + byte) = v;
    }
    #pragma unroll
    for (int s = 0; s < 4; ++s){
      int n = rA + 32*s;
      short8 v = *(const short8*)(Bt + (size_t)(n0+n)*2048 + k0 + kh*8);
      int byte = n*128 + ((kh*16) ^ ((n & 7)*16));
      *(short8*)((char*)Bsb + byte) = v;
    }
    __syncthreads();
    short8 af[4][2], bf[4][2];
    #pragma unroll
    for (int fm = 0; fm < 4; ++fm){
      int row = wr*64 + fm*16 + lr;
      #pragma unroll
      for (int kq = 0; kq < 2; ++kq){
        int byte = row*128 + ((kq*64 + ql*16) ^ ((row & 7)*16));
        af[fm][kq] = *(const short8*)((const char*)Asb + byte);
      }
    }
    #pragma unroll
    for (int fn = 0; fn < 4; ++fn){
      int row = wc*64 + fn*16 + lr;
      #pragma unroll
      for (int kq = 0; kq < 2; ++kq){
        int byte = row*128 + ((kq*64 + ql*16) ^ ((row & 7)*16));
        bf[fn][kq] = *(const short8*)((const char*)Bsb + byte);
      }
    }
    #pragma unroll
    for (int kq = 0; kq < 2; ++kq)
      #pragma unroll
      for (int fm = 0; fm < 4; ++fm)
        #pragma unroll
        for (int fn = 0; fn < 4; ++fn)
          acc[fm][fn] = __builtin_amdgcn_mfma_f32_16x16x32_bf16(af[fm][kq], bf[fn][kq],
                                                                acc[fm][fn], 0, 0, 0);
    __syncthreads();
  }

  float* Cm = p.Cm[z];
  const ushort* vtp = p.vt[z];
  const ushort* itp = p.it[z];
  #pragma unroll
  for (int fm = 0; fm < 4; ++fm){
    #pragma unroll
    for (int fn = 0; fn < 4; ++fn){
      int n = n0 + wc*64 + fn*16 + lr;
      float bia = p.bias[z][n];
      #pragma unroll
      for (int reg = 0; reg < 4; ++reg){
        int mloc = wr*64 + fm*16 + ql*4 + reg;
        size_t off = ((size_t)(gb << 12) + idx_s[mloc])*1024 + n;
        float vt = bf2f(vtp[off]);
        float it = bf2f(itp[off]);
        float gg = 1.f/(1.f + expf(-(acc[fm][fn][reg] + bia)));
        Cm[off] = gg*vt + (1.f-gg)*it;
      }
    }
  }
}

// ---------------- scatter GEMM: fused_sel = vs(bf16) + o@Wo, K=128 ----------------
struct SCP {
  const float* A0[2];
  const float* Bm[2];
  float* Cm[2];
  const int* idxp[2];
  const ushort* vtb[2];
};

__global__ __launch_bounds__(256) void kern_scat(SCP p){
  __shared__ __align__(16) ushort Asb[64*40];
  __shared__ __align__(16) ushort Bsb[128*40];
  __shared__ int idx_s[64];
  int z = blockIdx.z;
  const float* A0 = p.A0[z];
  const float* Bm = p.Bm[z];
  float* Cm = p.Cm[z];
  int tid = threadIdx.x;
  int m0 = blockIdx.y * 64;
  int n0 = blockIdx.x * 128;
  int lane = tid & 63, w = tid >> 6;
  int wr = w & 1, wc = w >> 1;
  int lr = lane & 15, ql = lane >> 4;
  if (tid < 64){
    int m = m0 + tid;
    idx_s[tid] = p.idxp[z][(m >> 10)*1024 + (m & 1023)];
  }
  __syncthreads();
  int gb = m0 >> 10;

  f32x4 acc[2][4];
  #pragma unroll
  for (int i = 0; i < 2; ++i)
    #pragma unroll
    for (int j = 0; j < 4; ++j) acc[i][j] = (f32x4){0.f,0.f,0.f,0.f};

  for (int k0 = 0; k0 < 128; k0 += 32){
    {
      int m = tid & 63;
      int khh = (tid >> 6) * 8;
      const float* ap = A0 + (size_t)(m0+m)*128 + k0 + khh;
      float4 f0 = *(const float4*)ap;
      float4 f1 = *(const float4*)(ap + 4);
      short8 v;
      v[0]=(short)f2bf(f0.x); v[1]=(short)f2bf(f0.y);
      v[2]=(short)f2bf(f0.z); v[3]=(short)f2bf(f0.w);
      v[4]=(short)f2bf(f1.x); v[5]=(short)f2bf(f1.y);
      v[6]=(short)f2bf(f1.z); v[7]=(short)f2bf(f1.w);
      *(short8*)&Asb[m*40 + khh] = v;
    }
    #pragma unroll
    for (int e0 = 0; e0 < 512; e0 += 256){
      int e = e0 + tid;
      int n = e & 127;
      int khh = (e >> 7) * 8;
      const float* bp = Bm + (size_t)(k0+khh)*1024 + n0 + n;
      short8 v;
      #pragma unroll
      for (int j = 0; j < 8; ++j) v[j] = (short)f2bf(bp[(size_t)j*1024]);
      *(short8*)&Bsb[n*40 + khh] = v;
    }
    __syncthreads();
    short8 af[2], bf[4];
    #pragma unroll
    for (int fr = 0; fr < 2; ++fr)
      af[fr] = *(const short8*)&Asb[(wr*32 + fr*16 + lr)*40 + ql*8];
    #pragma unroll
    for (int fc = 0; fc < 4; ++fc)
      bf[fc] = *(const short8*)&Bsb[(wc*64 + fc*16 + lr)*40 + ql*8];
    #pragma unroll
    for (int fr = 0; fr < 2; ++fr)
      #pragma unroll
      for (int fc = 0; fc < 4; ++fc)
        acc[fr][fc] = __builtin_amdgcn_mfma_f32_16x16x32_bf16(af[fr], bf[fc],
                                                              acc[fr][fc], 0, 0, 0);
    __syncthreads();
  }

  #pragma unroll
  for (int fr = 0; fr < 2; ++fr){
    #pragma unroll
    for (int fc = 0; fc < 4; ++fc){
      int n = n0 + wc*64 + fc*16 + lr;
      #pragma unroll
      for (int reg = 0; reg < 4; ++reg){
        int mloc = wr*32 + fr*16 + ql*4 + reg;
        int gt = idx_s[mloc];
        size_t off = ((size_t)(gb << 12) + gt)*1024 + n;
        Cm[off] = acc[fr][fc][reg] + bf2f(p.vtb[z][off]);
      }
    }
  }
}

// ---------------- top-1024 of 4096 (bitonic, jax tie-break) ----------------
__global__ __launch_bounds__(1024) void kern_topk(const float* __restrict__ score,
    int* __restrict__ idx_out){
  __shared__ u64 keys[4096];
  int b = blockIdx.x, t = threadIdx.x;
  for (int i = t; i < 4096; i += 1024){
    float s = score[b*4096 + i];
    uint u = __float_as_uint(s);
    uint msk = (u & 0x80000000u) ? ~u : (u | 0x80000000u);
    keys[i] = ((u64)msk << 32) | (uint)(4095 - i);
  }
  __syncthreads();
  for (int k = 2; k <= 4096; k <<= 1){
    for (int j = k >> 1; j > 0; j >>= 1){
      for (int i = t; i < 4096; i += 1024){
        int l = i ^ j;
        if (l > i){
          u64 a = keys[i], c = keys[l];
          bool descB = ((i & k) == 0);
          bool sw = descB ? (a < c) : (a > c);
          if (sw){ keys[i] = c; keys[l] = a; }
        }
      }
      __syncthreads();
    }
  }
  idx_out[b*1024 + t] = 4095 - (int)(keys[t] & 0xFFFFFFFFu);
}

// ---------------- attention partials (k-split flash, 128-thr q-split) ----------
__global__ __launch_bounds__(128) void kern_attn_part(const float* __restrict__ qb,
    const float* __restrict__ kb, const float* __restrict__ vb,
    float* __restrict__ paoa, float* __restrict__ pml){
  __shared__ float Ks[64][32];
  __shared__ float Vs[64][32];
  int t = threadIdx.x;
  int hh = blockIdx.y;
  int zc = blockIdx.z;
  int zf = zc >> 2, c = zc & 3;
  size_t boff = (size_t)zf*131072;
  int jq = blockIdx.x*128 + t;
  float qv[32];
  {
    const float4* qp = (const float4*)(qb + boff + (size_t)jq*128 + hh*32);
    #pragma unroll
    for (int d = 0; d < 8; ++d) ((float4*)qv)[d] = qp[d];
  }
  float mrun = -3.0e38f, lrun = 0.f;
  float oa[32];
  #pragma unroll
  for (int d = 0; d < 32; ++d) oa[d] = 0.f;
  for (int kt = 0; kt < 4; ++kt){
    int k0 = c*256 + kt*64;
    #pragma unroll
    for (int rep = 0; rep < 4; ++rep){
      int f = t + rep*128;
      int r = f >> 3, q4 = f & 7;
      size_t base = boff + (size_t)(k0 + r)*128 + hh*32 + 4*q4;
      *(float4*)&Ks[r][4*q4] = *(const float4*)(kb + base);
      *(float4*)&Vs[r][4*q4] = *(const float4*)(vb + base);
    }
    __syncthreads();
    #pragma unroll
    for (int st = 0; st < 4; ++st){
      float s[16];
      #pragma unroll
      for (int j = 0; j < 16; ++j){
        float v = 0.f;
        #pragma unroll
        for (int d = 0; d < 32; ++d) v += qv[d]*Ks[st*16+j][d];
        s[j] = v * 0.17677669529663687f;
      }
      float mt = s[0];
      #pragma unroll
      for (int j = 1; j < 16; ++j) mt = fmaxf(mt, s[j]);
      float mnew = fmaxf(mrun, mt);
      float alpha = expf(mrun - mnew);
      lrun *= alpha;
      #pragma unroll
      for (int d = 0; d < 32; ++d) oa[d] *= alpha;
      #pragma unroll
      for (int j = 0; j < 16; ++j){
        float pe = expf(s[j] - mnew);
        lrun += pe;
        #pragma unroll
        for (int d = 0; d < 32; ++d) oa[d] += pe*Vs[st*16+j][d];
      }
      mrun = mnew;
    }
    __syncthreads();
  }
  size_t rec = (((size_t)zf*4 + hh)*4 + c)*1024 + jq;
  float* pp = paoa + rec*32;
  #pragma unroll
  for (int d = 0; d < 8; ++d) ((float4*)pp)[d] = ((float4*)oa)[d];
  pml[rec*2]   = mrun;
  pml[rec*2+1] = lrun;
}

// ---------------- attention combine ----------------
__global__ __launch_bounds__(256) void kern_attn_comb(const float* __restrict__ paoa,
    const float* __restrict__ pml, float* __restrict__ ob,
    const float* __restrict__ ipint, int PB, int b0){
  int t = threadIdx.x;
  int hh = blockIdx.y, zf = blockIdx.z;
  int jq = blockIdx.x*256 + t;
  size_t rbase = (((size_t)zf*4 + hh)*4)*1024 + jq;
  float mc[4], lc[4];
  #pragma unroll
  for (int c = 0; c < 4; ++c){
    mc[c] = pml[(rbase + c*1024)*2];
    lc[c] = pml[(rbase + c*1024)*2 + 1];
  }
  float M = fmaxf(fmaxf(mc[0], mc[1]), fmaxf(mc[2], mc[3]));
  float wgt[4], L = 0.f;
  #pragma unroll
  for (int c = 0; c < 4; ++c){ wgt[c] = expf(mc[c] - M); L += lc[c]*wgt[c]; }
  float inv = 1.f/L;
  int br = (zf >= PB) ? 1 : 0;
  int bb = zf - br*PB;
  const float* ip = ipint + br*512 + (b0+bb)*128 + hh*32;
  float* op = ob + (size_t)zf*131072 + (size_t)jq*128 + hh*32;
  #pragma unroll
  for (int d = 0; d < 32; ++d){
    float o = 0.f;
    #pragma unroll
    for (int c = 0; c < 4; ++c) o += paoa[(rbase + c*1024)*32 + d]*wgt[c];
    op[d] = o*inv + ip[d];
  }
}

// ---------------- conv weight transform ----------------
__global__ __launch_bounds__(256) void kern_wt(const float* __restrict__ w1,
    const float* __restrict__ w2, ushort* __restrict__ wt){
  int blk = blockIdx.x;
  const float* src = (blk < 9) ? w1 : w2;
  int tap = blk - (blk < 9 ? 0 : 9);
  ushort* dst = wt + (blk < 9 ? 0 : 36864) + tap*4096;
  for (int e = threadIdx.x; e < 4096; e += 256){
    dst[e] = f2bf(src[(size_t)e*9 + tap]);
  }
}

// ---------------- implicit-GEMM 3x3 conv via MFMA ----------------
template<int MODE>
__global__ __launch_bounds__(256) void kern_cmfma(const float* __restrict__ in,
    const ushort* __restrict__ wt, const float* __restrict__ bias,
    float* __restrict__ out,
    const float* __restrict__ modg, const float* __restrict__ modb,
    const float* __restrict__ vis, const float* __restrict__ irf){
  __shared__ __align__(16) ushort ins[64][268];
  int t = threadIdx.x;
  int y = blockIdx.x, b = blockIdx.y;
  int lane = t & 63, w = t >> 6;
  int wc = w & 1, wx = w >> 1;
  int lr = lane & 15, ql = lane >> 4;

  f32x4 acc[2][8];
  #pragma unroll
  for (int f = 0; f < 2; ++f)
    #pragma unroll
    for (int xf = 0; xf < 8; ++xf) acc[f][xf] = (f32x4){0.f,0.f,0.f,0.f};

  for (int dy = 0; dy < 3; ++dy){
    int yy = y + dy - 1;
    if (yy < 0 || yy > 255) continue;
    const float* src = in + ((size_t)(b*64)*256 + yy)*256;
    #pragma unroll
    for (int s = 0; s < 16; ++s){
      int e = t + s*256;
      int ci = e >> 6, q = e & 63;
      float4 f4 = *(const float4*)(src + (size_t)ci*65536 + 4*q);
      uint lo = (uint)f2bf(f4.x) | ((uint)f2bf(f4.y) << 16);
      uint hi = (uint)f2bf(f4.z) | ((uint)f2bf(f4.w) << 16);
      *(uint2*)&ins[ci][4*q + 4] = make_uint2(lo, hi);
    }
    if (t < 128){
      int r = t & 63;
      ins[r][(t >> 6) ? 260 : 3] = 0;
    }
    __syncthreads();
    short8 wf[2][3][2];
    #pragma unroll
    for (int kk = 0; kk < 2; ++kk)
      #pragma unroll
      for (int dx = 0; dx < 3; ++dx)
        #pragma unroll
        for (int f = 0; f < 2; ++f)
          wf[kk][dx][f] = *(const short8*)(wt +
            (size_t)((dy*3 + dx)*64 + 32*wc + 16*f + lr)*64 + kk*32 + ql*8);
    #pragma unroll
    for (int kk = 0; kk < 2; ++kk){
      const ushort* bp = &ins[kk*32 + ql*8][0];
      #pragma unroll
      for (int dx = 0; dx < 3; ++dx){
        int xb = 128*wx + lr + dx + 3;
        #pragma unroll
        for (int xf = 0; xf < 8; ++xf){
          int xi = xb + 16*xf;
          short8 bf;
          #pragma unroll
          for (int e = 0; e < 8; ++e) bf[e] = (short)bp[e*268 + xi];
          acc[0][xf] = __builtin_amdgcn_mfma_f32_16x16x32_bf16(wf[kk][dx][0], bf,
                                                               acc[0][xf], 0, 0, 0);
          acc[1][xf] = __builtin_amdgcn_mfma_f32_16x16x32_bf16(wf[kk][dx][1], bf,
                                                               acc[1][xf], 0, 0, 0);
        }
      }
    }
    __syncthreads();
  }

  #pragma unroll
  for (int f = 0; f < 2; ++f){
    #pragma unroll
    for (int xf = 0; xf < 8; ++xf){
      int x = 128*wx + 16*xf + lr;
      #pragma unroll
      for (int reg = 0; reg < 4; ++reg){
        int co = 32*wc + 16*f + ql*4 + reg;
        float v = acc[f][xf][reg] + bias[co];
        size_t oi = ((size_t)(b*64 + co)*256 + y)*256 + x;
        if (MODE == 1){
          out[oi] = fmaxf(v, 0.f);
        } else {
          out[oi] = v*modg[b*64+co] + modb[b*64+co] + 0.5f*(vis[oi] + irf[oi]);
        }
      }
    }
  }
}

// ---------------- launch ----------------
extern "C" void kernel_launch(void* const* d_in, const int* in_sizes, int n_in,
                              void* d_out, int out_size, void* d_ws, size_t ws_size,
                              hipStream_t stream){
  (void)in_sizes; (void)n_in; (void)out_size;
  const float* vis  = (const float*)d_in[0];
  const float* irf  = (const float*)d_in[1];
  const float* bank = (const float*)d_in[2];
  const float* Wr   = (const float*)d_in[3];
  const float* br   = (const float*)d_in[4];
  const float* Wtok = (const float*)d_in[5];
  const float* Wpri = (const float*)d_in[6];
  const float* Wco  = (const float*)d_in[7];
  const float* bs   = (const float*)d_in[8];
  const float* Wout = (const float*)d_in[9];
  const float* bout = (const float*)d_in[10];
  const float* Wq   = (const float*)d_in[11];
  const float* Wk   = (const float*)d_in[12];
  const float* Wv   = (const float*)d_in[13];
  const float* Wo   = (const float*)d_in[14];
  const float* Wint = (const float*)d_in[15];
  const float* Wbyp = (const float*)d_in[16];
  const float* bbyp = (const float*)d_in[17];
  const float* c1w  = (const float*)d_in[18];
  const float* c1b  = (const float*)d_in[19];
  const float* c2w  = (const float*)d_in[20];
  const float* c2b  = (const float*)d_in[21];
  const float* Wa1  = (const float*)d_in[22];
  const float* ba1  = (const float*)d_in[23];
  const float* Wa2  = (const float*)d_in[24];
  const float* ba2  = (const float*)d_in[25];

  // layout identical in size to round 9/11
  auto needB = [](int PB)->size_t{
    return ((size_t)PB*14755840 + 2792448) * 4;
  };
  const int PB = (ws_size >= needB(4)) ? 4 : (ws_size >= needB(2)) ? 2 : 1;

  float* ws = (float*)d_ws;
  const size_t PLF = (size_t)PB*4194304;
  float* PH4 = ws;                                 // fwd im transient + FULL_ph (fp32)
  ushort* ABV = (ushort*)(ws + PLF);               // 4 bf16 planes = 2*PLF floats
  ushort* PBV = ABV + PLF;
  ushort* ABI = PBV + PLF;
  ushort* PBI = ABI + PLF;
  float* S0 = ws + PLF;                            // iFFT fp32 transients alias bf16 region
  float* S1 = S0 + PLF;
  float* sm = ws + 3*PLF;
  float* hbuf  = sm; sm += (size_t)2*PB*524288;    // nsel + paoa alias here
  float* qbuf  = sm; sm += (size_t)2*PB*131072;
  float* kbuf  = sm; sm += (size_t)2*PB*131072;
  float* vbuf  = sm; sm += (size_t)2*PB*131072;
  float* obuf  = sm; sm += (size_t)2*PB*131072;
  float* score = sm; sm += (size_t)2*PB*4096;
  int*   idxb  = (int*)sm; sm += (size_t)2*PB*1024;
  float* pml   = sm; sm += (size_t)PB*65536;
  ushort* BTtok = (ushort*)sm;                     // [2][128][2048]
  ushort* BTbyp = BTtok + 524288;                  // [2][1024][2048]
  ushort* BTq   = BTbyp + 4194304;                 // [2][128][1024]
  ushort* BTk   = BTq + 262144;
  ushort* BTv   = BTk + 262144;
  sm += 2752512;
  float* pooled= sm; sm += 512;
  float* IP    = sm; sm += 1024;
  float* IPint = sm; sm += 1024;
  float* modg  = sm; sm += 256;
  float* modb  = sm; sm += 256;
  ushort* wtb = (ushort*)sm; sm += 36864;
  int*   nselb = (int*)hbuf;                       // [2PB][3072] (dead before paoa)
  float* paoa  = hbuf;

  kern_pool <<<512, 256, 0, stream>>>(vis, irf, pooled);
  kern_small<<<1, 256, 0, stream>>>(pooled, Wr, br, bank, Wpri, Wint,
                                    Wa1, ba1, Wa2, ba2, IP, IPint, modg, modb);
  kern_wt   <<<18, 256, 0, stream>>>(c1w, c2w, wtb);
  {
    TRS tr{};
    const float* srcs[10] = {Wtok, Wtok+262144, Wbyp, Wbyp+2097152,
                             Wq, Wq+131072, Wk, Wk+131072, Wv, Wv+131072};
    ushort* dsts[10] = {BTtok, BTtok+262144, BTbyp, BTbyp+2097152,
                        BTq, BTq+131072, BTk, BTk+131072, BTv, BTv+131072};
    int Ks[10] = {2048,2048,2048,2048,1024,1024,1024,1024,1024,1024};
    int Ns[10] = {128,128,1024,1024,128,128,128,128,128,128};
    int tiles[10] = {256,256,2048,2048,128,128,128,128,128,128};
    int acc0 = 0;
    for (int i = 0; i < 10; ++i){
      tr.src[i] = srcs[i]; tr.dst[i] = dsts[i];
      tr.K[i] = Ks[i]; tr.N[i] = Ns[i];
      tr.start[i] = acc0; acc0 += tiles[i];
    }
    tr.start[10] = acc0;
    kern_tr<<<acc0, 256, 0, stream>>>(tr);
  }

  for (int b0 = 0; b0 < 4; b0 += PB){
    const float* vis_b = vis + (size_t)b0*4194304;
    const float* ir_b  = irf + (size_t)b0*4194304;
    float* OUT = (float*)d_out + (size_t)b0*4194304;

    // forward FFT2 -> bf16 amp/ph (patchified), fp32 transients
    kern_fft_rows_fwd<<<PB*8192, 256, 0, stream>>>(vis_b, OUT, PH4);
    kern_fft_cols<0> <<<PB*1024, 256, 0, stream>>>(OUT, PH4, ABV, PBV);
    kern_fft_rows_fwd<<<PB*8192, 256, 0, stream>>>(ir_b, OUT, PH4);
    kern_fft_cols<0> <<<PB*1024, 256, 0, stream>>>(OUT, PH4, ABI, PBI);

    {  // h-GEMM with fused score (h never stored)
      HSP p{};
      p.A0[0]=ABV; p.A1[0]=ABI; p.A0[1]=PBV; p.A1[1]=PBI;
      for (int z = 0; z < 2; ++z){
        p.Bt[z] = BTtok + (size_t)z*262144;
        p.ep0[z] = IP + z*512 + b0*128;
        p.ep1[z] = Wco + z*256;
        p.ep2[z] = bs + z*128;
      }
      p.score = score; p.wout = Wout; p.bout = bout;
      p.Mper = PB*4096;
      kern_hscore<<<dim3(PB*32, 1, 2), 256, 0, stream>>>(p);
    }
    kern_topk<<<2*PB, 1024, 0, stream>>>(score, idxb);
    kern_nsel<<<2*PB, 1024, 0, stream>>>(idxb, nselb);
    {  // bypass blend over 3072 non-selected rows per (branch,batch)
      BYP p{};
      p.A0[0]=ABV; p.A1[0]=ABI; p.A0[1]=PBV; p.A1[1]=PBI;
      p.vt[0]=ABV; p.it[0]=ABI; p.vt[1]=PBV; p.it[1]=PBI;
      p.Cm[0]=OUT; p.Cm[1]=PH4;
      for (int z = 0; z < 2; ++z){
        p.Bt[z] = BTbyp + (size_t)z*2097152;
        p.bias[z] = bbyp + z*1024;
        p.nsel[z] = nselb + (size_t)z*PB*3072;
      }
      kern_byp<<<dim3(PB*24, 8, 2), 256, 0, stream>>>(p);
    }
    {  // q,k,v gathered rows
      GP2 p{};
      const ushort* Aplanes[6] = {ABV, ABI, ABI, PBV, PBI, PBI};
      const ushort* Bmats[6] = {BTq, BTk, BTv, BTq+131072, BTk+131072, BTv+131072};
      float* Cms[6] = {qbuf, kbuf, vbuf,
                       qbuf+(size_t)PB*131072, kbuf+(size_t)PB*131072,
                       vbuf+(size_t)PB*131072};
      for (int z = 0; z < 6; ++z){
        p.A0[z] = Aplanes[z]; p.Bt[z] = Bmats[z]; p.Cm[z] = Cms[z];
        p.idxp[z] = idxb + (z < 3 ? 0 : PB*1024);
      }
      p.N = 128; p.K = 1024;
      kern_mgemm2<<<dim3(PB*16, 1, 6), 256, 0, stream>>>(p);
    }
    // k-split flash attention (nsel dead -> paoa aliases hbuf)
    kern_attn_part<<<dim3(8, 4, 2*PB*4), 128, 0, stream>>>(qbuf, kbuf, vbuf,
                                                           paoa, pml);
    kern_attn_comb<<<dim3(4, 4, 2*PB), 256, 0, stream>>>(paoa, pml, obuf,
                                                         IPint, PB, b0);
    {  // fused_sel = vs(bf16) + o@Wo, scatter into FULL (selected rows)
      SCP p{};
      p.A0[0]=obuf; p.A0[1]=obuf+(size_t)PB*131072;
      p.Bm[0]=Wo; p.Bm[1]=Wo+131072;
      p.Cm[0]=OUT; p.Cm[1]=PH4;
      p.vtb[0]=ABV; p.vtb[1]=PBV;
      p.idxp[0]=idxb; p.idxp[1]=idxb+PB*1024;
      kern_scat<<<dim3(8, PB*16, 2), 256, 0, stream>>>(p);
    }

    // spec = famp*e^{i fph}; inverse FFT2 -> spatial into OUT
    kern_ifft_rows_spec<<<PB*4096, 256, 0, stream>>>(OUT, PH4, S0, S1);
    kern_fft_cols<1>   <<<PB*1024, 256, 0, stream>>>(S0, S1, OUT, nullptr);
  }

  // convs (MFMA): d_out(spatial) -> ws[0..16.78M floats) (conv1+relu) -> d_out
  kern_cmfma<1><<<dim3(256, 4), 256, 0, stream>>>((float*)d_out, wtb, c1b, ws,
                                                  nullptr, nullptr, nullptr, nullptr);
  kern_cmfma<2><<<dim3(256, 4), 256, 0, stream>>>(ws, wtb + 36864, c2b, (float*)d_out,
                                                  modg, modb, vis, irf);
}

// Round 13
// 1291.493 us; speedup vs baseline: 1.1413x; 1.0572x over previous
//
#include <hip/hip_runtime.h>

typedef unsigned int uint;
typedef unsigned short ushort;
typedef unsigned long long u64;
typedef __attribute__((ext_vector_type(8))) short short8;
typedef __attribute__((ext_vector_type(4))) float f32x4;

__device__ __forceinline__ uint brev8(uint x){ return __brev(x) >> 24; }
__device__ __forceinline__ float geluf(float x){
  return 0.5f*x*(1.f + tanhf(0.7978845608028654f*(x + 0.044715f*x*x*x)));
}
__device__ __forceinline__ ushort f2bf(float f){
  unsigned u = __float_as_uint(f);
  unsigned r = u + 0x7FFFu + ((u >> 16) & 1u);
  return (ushort)(r >> 16);
}
__device__ __forceinline__ float bf2f(ushort u){
  return __uint_as_float((uint)u << 16);
}

// ---------------- pooled mean ----------------
__global__ __launch_bounds__(256) void kern_pool(const float* __restrict__ vis,
                                                 const float* __restrict__ irf,
                                                 float* __restrict__ pooled){
  __shared__ float red[256];
  int bc = blockIdx.x;
  int b = bc >> 7, cc = bc & 127;
  const float* src = (cc < 64) ? (vis + (size_t)(b*64+cc)*65536)
                               : (irf + (size_t)(b*64+(cc-64))*65536);
  float s = 0.f;
  for (int i = threadIdx.x; i < 65536; i += 256) s += src[i];
  red[threadIdx.x] = s;
  __syncthreads();
  for (int off = 128; off > 0; off >>= 1){
    if (threadIdx.x < off) red[threadIdx.x] += red[threadIdx.x + off];
    __syncthreads();
  }
  if (threadIdx.x == 0) pooled[bc] = red[0] * (1.f/65536.f);
}

// ---------------- prompt/intent/affine small ops ----------------
__global__ __launch_bounds__(256) void kern_small(const float* __restrict__ pooled,
    const float* __restrict__ Wr, const float* __restrict__ br,
    const float* __restrict__ bank, const float* __restrict__ Wpri,
    const float* __restrict__ Wint, const float* __restrict__ Wa1,
    const float* __restrict__ ba1, const float* __restrict__ Wa2,
    const float* __restrict__ ba2,
    float* __restrict__ IP, float* __restrict__ IPint,
    float* __restrict__ modg, float* __restrict__ modb){
  __shared__ float logit_s[16];
  __shared__ float pw_s[16];
  __shared__ float intent_s[4][64];
  __shared__ float t1_s[4][128];
  int t = threadIdx.x;
  if (t < 16){
    int b = t >> 2, j = t & 3;
    float s = br[j];
    for (int k = 0; k < 128; ++k) s += pooled[b*128+k]*Wr[k*4+j];
    logit_s[t] = s;
  }
  __syncthreads();
  if (t < 4){
    int b = t;
    float m = logit_s[b*4];
    for (int j = 1; j < 4; ++j) m = fmaxf(m, logit_s[b*4+j]);
    float e[4], sum = 0.f;
    for (int j = 0; j < 4; ++j){ e[j] = expf(logit_s[b*4+j]-m); sum += e[j]; }
    for (int j = 0; j < 4; ++j) pw_s[b*4+j] = e[j]/sum;
  }
  __syncthreads();
  {
    int b = t >> 6, p = t & 63;
    float s = 0.f;
    for (int j = 0; j < 4; ++j) s += pw_s[b*4+j]*bank[j*64+p];
    intent_s[b][p] = s;
  }
  __syncthreads();
  for (int o = t; o < 1024; o += 256){
    int i = o >> 9, rem = o & 511, b = rem >> 7, n = rem & 127;
    float s1 = 0.f, s2 = 0.f;
    for (int p = 0; p < 64; ++p){
      float iv = intent_s[b][p];
      s1 += iv * Wpri[(i*64+p)*128 + n];
      s2 += iv * Wint[(i*64+p)*128 + n];
    }
    IP[o] = s1; IPint[o] = s2;
  }
  for (int o = t; o < 512; o += 256){
    int b = o >> 7, n = o & 127;
    float s = ba1[n];
    for (int p = 0; p < 64; ++p) s += intent_s[b][p]*Wa1[p*128+n];
    t1_s[b][n] = geluf(s);
  }
  __syncthreads();
  for (int o = t; o < 512; o += 256){
    int b = o >> 7, n = o & 127;
    float s = ba2[n];
    for (int p = 0; p < 128; ++p) s += t1_s[b][p]*Wa2[p*128+n];
    if (n < 64) modg[b*64+n] = 1.f + 0.1f*tanhf(s);
    else        modb[b*64+(n-64)] = 0.1f*s;
  }
}

// ---------------- packed forward row FFT: Z = FFT(vis + i*ir) per row ----------
__global__ __launch_bounds__(256) void kern_fft_rows_pack(const float* __restrict__ xv,
    const float* __restrict__ xi, float* __restrict__ sre, float* __restrict__ sim){
  __shared__ float re[2][256], im[2][256];
  __shared__ float twr[128], twi[128];
  int t = threadIdx.x;
  if (t < 128){
    float a = -6.2831853071795864f * (float)t * (1.f/256.f);
    sincosf(a, &twi[t], &twr[t]);
  }
  int r = t >> 7, jj = t & 127;
  size_t row = (size_t)blockIdx.x*2 + r;
  {
    const float* vp = xv + row*256;
    const float* ip = xi + row*256;
    re[r][jj] = vp[jj]; re[r][jj+128] = vp[jj+128];
    im[r][jj] = ip[jj]; im[r][jj+128] = ip[jj+128];
  }
  __syncthreads();
  for (int s = 0; s < 8; ++s){
    int half = 128 >> s;
    int j = jj & (half-1);
    int g = jj >> (7-s);
    int k = (g << (8-s)) + j;
    int m = j << s;
    float wc = twr[m], ws = twi[m];
    float are = re[r][k],      aim = im[r][k];
    float bre = re[r][k+half], bim = im[r][k+half];
    re[r][k] = are + bre; im[r][k] = aim + bim;
    float tr = are - bre, ti = aim - bim;
    re[r][k+half] = tr*wc - ti*ws;
    im[r][k+half] = tr*ws + ti*wc;
    __syncthreads();
  }
  {
    float* orp = sre + row*256; float* oip = sim + row*256;
    int w1 = jj, w2 = jj + 128;
    orp[w1] = re[r][brev8(w1)]; oip[w1] = im[r][brev8(w1)];
    orp[w2] = re[r][brev8(w2)]; oip[w2] = im[r][brev8(w2)];
  }
}

// ---------------- packed column FFT + unpack: mirror-closed 16-col sets ----------
// j=0: cols {0..7,128,249..255}; j>=1: {8j..8j+7} U {249-8j..256-8j}.
// Unpack: Fvis=(Z[u,v]+conj(Z[-u,-v]))/2, Fir=(Z[u,v]-conj(Z[-u,-v]))/(2i).
__global__ __launch_bounds__(256) void kern_fft_cols_pack(const float* __restrict__ sre,
    const float* __restrict__ sim, ushort* __restrict__ AV, ushort* __restrict__ PV,
    ushort* __restrict__ AI, ushort* __restrict__ PI){
  __shared__ float reL[256*17];
  __shared__ float imL[256*17];
  __shared__ float twr[128], twi[128];
  int t = threadIdx.x;
  if (t < 128){
    float a = -6.2831853071795864f * (float)t * (1.f/256.f);
    sincosf(a, &twi[t], &twr[t]);
  }
  int img = blockIdx.x >> 4;
  int j = blockIdx.x & 15;
  {
    const float* pr = sre + ((size_t)img*256 + t)*256;
    const float* pi = sim + ((size_t)img*256 + t)*256;
    int base = t*17;
    // group A: cols 8j..8j+7 (aligned)
    float4 a0 = *(const float4*)(pr + 8*j);
    float4 a1 = *(const float4*)(pr + 8*j + 4);
    float4 c0 = *(const float4*)(pi + 8*j);
    float4 c1 = *(const float4*)(pi + 8*j + 4);
    reL[base+0]=a0.x; reL[base+1]=a0.y; reL[base+2]=a0.z; reL[base+3]=a0.w;
    reL[base+4]=a1.x; reL[base+5]=a1.y; reL[base+6]=a1.z; reL[base+7]=a1.w;
    imL[base+0]=c0.x; imL[base+1]=c0.y; imL[base+2]=c0.z; imL[base+3]=c0.w;
    imL[base+4]=c1.x; imL[base+5]=c1.y; imL[base+6]=c1.z; imL[base+7]=c1.w;
    if (j == 0){
      // local 8 = col 128; local 9..15 = cols 249..255
      reL[base+8] = pr[128]; imL[base+8] = pi[128];
      float4 b0 = *(const float4*)(pr + 248);
      float4 b1 = *(const float4*)(pr + 252);
      float4 d0 = *(const float4*)(pi + 248);
      float4 d1 = *(const float4*)(pi + 252);
      reL[base+9]=b0.y;  reL[base+10]=b0.z; reL[base+11]=b0.w;
      reL[base+12]=b1.x; reL[base+13]=b1.y; reL[base+14]=b1.z; reL[base+15]=b1.w;
      imL[base+9]=d0.y;  imL[base+10]=d0.z; imL[base+11]=d0.w;
      imL[base+12]=d1.x; imL[base+13]=d1.y; imL[base+14]=d1.z; imL[base+15]=d1.w;
    } else {
      // local 8..15 = cols 249-8j..256-8j
      float4 b0 = *(const float4*)(pr + 248 - 8*j);
      float4 b1 = *(const float4*)(pr + 252 - 8*j);
      float4 d0 = *(const float4*)(pi + 248 - 8*j);
      float4 d1 = *(const float4*)(pi + 252 - 8*j);
      reL[base+8]=b0.y;  reL[base+9]=b0.z;  reL[base+10]=b0.w;
      reL[base+11]=b1.x; reL[base+12]=b1.y; reL[base+13]=b1.z; reL[base+14]=b1.w;
      reL[base+15]=pr[256 - 8*j];
      imL[base+8]=d0.y;  imL[base+9]=d0.z;  imL[base+10]=d0.w;
      imL[base+11]=d1.x; imL[base+12]=d1.y; imL[base+13]=d1.z; imL[base+14]=d1.w;
      imL[base+15]=pi[256 - 8*j];
    }
  }
  __syncthreads();
  int col = t & 15, tb = t >> 4;
  for (int s = 0; s < 8; ++s){
    int half = 128 >> s;
    #pragma unroll
    for (int it = 0; it < 8; ++it){
      int tj = tb + it*16;
      int jl = tj & (half-1);
      int g = tj >> (7-s);
      int k = (g << (8-s)) + jl;
      int m = jl << s;
      float wc = twr[m], ws = twi[m];
      int i0 = k*17 + col, i1 = (k+half)*17 + col;
      float are = reL[i0], aim = imL[i0];
      float bre = reL[i1], bim = imL[i1];
      reL[i0] = are + bre; imL[i0] = aim + bim;
      float tr = are - bre, ti = aim - bim;
      reL[i1] = tr*wc - ti*ws;
      imL[i1] = tr*ws + ti*wc;
    }
    __syncthreads();
  }
  int b = img >> 6, cimg = img & 63;
  int u = t;
  int su  = (int)brev8((uint)u) * 17;
  int smu = (int)brev8((uint)((256 - u) & 255)) * 17;
  #pragma unroll
  for (int c = 0; c < 16; ++c){
    int v, mc;
    if (j == 0){
      v  = (c < 8) ? c : ((c == 8) ? 128 : 240 + c);
      mc = (c == 0) ? 0 : ((c == 8) ? 8 : 16 - c);
    } else {
      v  = (c < 8) ? (8*j + c) : (241 - 8*j + c);
      mc = 15 - c;
    }
    float re1 = reL[su + c],  im1 = imL[su + c];
    float re2 = reL[smu + mc], im2 = imL[smu + mc];
    float vr = 0.5f*(re1 + re2), vi = 0.5f*(im1 - im2);
    float jr = 0.5f*(im1 + im2), ji = 0.5f*(re2 - re1);
    float aV = sqrtf(vr*vr + vi*vi), pVh = atan2f(vi, vr);
    float aI = sqrtf(jr*jr + ji*ji), pIh = atan2f(ji, jr);
    size_t addr = ((size_t)(b*4096 + (u>>2)*64 + (v>>2)))*1024
                + cimg*16 + (u&3)*4 + (v&3);
    AV[addr] = f2bf(aV); PV[addr] = f2bf(pVh);
    AI[addr] = f2bf(aI); PI[addr] = f2bf(pIh);
  }
}

// ---------------- inverse row FFT with spec construction (fp32) ----------------
__global__ __launch_bounds__(256) void kern_ifft_rows_spec(const float* __restrict__ famp,
    const float* __restrict__ fph, float* __restrict__ sre, float* __restrict__ sim){
  __shared__ float re[4][256], im[4][256];
  __shared__ float twr[128], twi[128];
  int t = threadIdx.x;
  if (t < 128){
    float a = -6.2831853071795864f * (float)t * (1.f/256.f);
    sincosf(a, &twi[t], &twr[t]);
  }
  int R = blockIdx.x * 4;
  {
    int r = t >> 6, q = t & 63;
    int row = R + r;
    int bc = row >> 8, h = row & 255;
    int b = bc >> 6, c = bc & 63;
    size_t addr = ((size_t)(b*4096 + (h>>2)*64 + q))*1024 + c*16 + (h&3)*4;
    float4 a4 = *(const float4*)(famp + addr);
    float4 p4 = *(const float4*)(fph + addr);
    float sn, cs;
    sincosf(p4.x, &sn, &cs); re[r][4*q+0] = a4.x*cs; im[r][4*q+0] = a4.x*sn;
    sincosf(p4.y, &sn, &cs); re[r][4*q+1] = a4.y*cs; im[r][4*q+1] = a4.y*sn;
    sincosf(p4.z, &sn, &cs); re[r][4*q+2] = a4.z*cs; im[r][4*q+2] = a4.z*sn;
    sincosf(p4.w, &sn, &cs); re[r][4*q+3] = a4.w*cs; im[r][4*q+3] = a4.w*sn;
  }
  __syncthreads();
  for (int s = 0; s < 8; ++s){
    int half = 128 >> s;
    #pragma unroll
    for (int bi0 = 0; bi0 < 2; ++bi0){
      int bi = t + bi0*256;
      int r = bi >> 7, tj = bi & 127;
      int j = tj & (half-1);
      int g = tj >> (7-s);
      int k = (g << (8-s)) + j;
      int m = j << s;
      float wc = twr[m], ws = -twi[m];
      float are = re[r][k],      aim = im[r][k];
      float bre = re[r][k+half], bim = im[r][k+half];
      re[r][k] = are + bre; im[r][k] = aim + bim;
      float tr = are - bre, ti = aim - bim;
      re[r][k+half] = tr*wc - ti*ws;
      im[r][k+half] = tr*ws + ti*wc;
    }
    __syncthreads();
  }
  {
    int r = t >> 6, q = t & 63;
    size_t row = (size_t)R + r;
    float4 vr, vi;
    vr.x = re[r][brev8(4*q+0)]; vi.x = im[r][brev8(4*q+0)];
    vr.y = re[r][brev8(4*q+1)]; vi.y = im[r][brev8(4*q+1)];
    vr.z = re[r][brev8(4*q+2)]; vi.z = im[r][brev8(4*q+2)];
    vr.w = re[r][brev8(4*q+3)]; vi.w = im[r][brev8(4*q+3)];
    *(float4*)(sre + row*256 + 4*q) = vr;
    *(float4*)(sim + row*256 + 4*q) = vi;
  }
}

// ---------------- inverse column FFT (fp32 in -> fp32 spatial out) --------------
__global__ __launch_bounds__(256) void kern_fft_cols_inv(const float* __restrict__ sre,
    const float* __restrict__ sim, float* __restrict__ out0){
  __shared__ float reL[256*17];
  __shared__ float imL[256*17];
  __shared__ float twr[128], twi[128];
  int t = threadIdx.x;
  if (t < 128){
    float a = -6.2831853071795864f * (float)t * (1.f/256.f);
    sincosf(a, &twi[t], &twr[t]);
  }
  int img = blockIdx.x >> 4;
  int c0 = (blockIdx.x & 15) * 16;
  {
    const float* pr = sre + ((size_t)img*256 + t)*256 + c0;
    const float* pi = sim + ((size_t)img*256 + t)*256 + c0;
    #pragma unroll
    for (int p = 0; p < 4; ++p){
      float4 vr = *(const float4*)(pr + 4*p);
      float4 vi = *(const float4*)(pi + 4*p);
      int base = t*17 + 4*p;
      reL[base+0]=vr.x; reL[base+1]=vr.y; reL[base+2]=vr.z; reL[base+3]=vr.w;
      imL[base+0]=vi.x; imL[base+1]=vi.y; imL[base+2]=vi.z; imL[base+3]=vi.w;
    }
  }
  __syncthreads();
  int col = t & 15, tb = t >> 4;
  for (int s = 0; s < 8; ++s){
    int half = 128 >> s;
    #pragma unroll
    for (int it = 0; it < 8; ++it){
      int tj = tb + it*16;
      int j = tj & (half-1);
      int g = tj >> (7-s);
      int k = (g << (8-s)) + j;
      int m = j << s;
      float wc = twr[m];
      float ws = -twi[m];
      int i0 = k*17 + col, i1 = (k+half)*17 + col;
      float are = reL[i0], aim = imL[i0];
      float bre = reL[i1], bim = imL[i1];
      reL[i0] = are + bre; imL[i0] = aim + bim;
      float tr = are - bre, ti = aim - bim;
      reL[i1] = tr*wc - ti*ws;
      imL[i1] = tr*ws + ti*wc;
    }
    __syncthreads();
  }
  int h = t; int src = (int)brev8((uint)h);
  float* op = out0 + ((size_t)img*256 + h)*256 + c0;
  #pragma unroll
  for (int p = 0; p < 4; ++p){
    int base = src*17 + 4*p;
    float4 v;
    v.x = reL[base+0]*(1.f/65536.f);
    v.y = reL[base+1]*(1.f/65536.f);
    v.z = reL[base+2]*(1.f/65536.f);
    v.w = reL[base+3]*(1.f/65536.f);
    *(float4*)(op + 4*p) = v;
  }
}

// ---------------- transpose-convert: fp32 [K][N] -> bf16 [N][K], 10 mats ----------
struct TRS {
  const float* src[10];
  ushort* dst[10];
  int K[10], N[10];
  int start[11];
};
__global__ __launch_bounds__(256) void kern_tr(TRS p){
  __shared__ float lds[32][33];
  int bid = blockIdx.x;
  int e = 0;
  while (bid >= p.start[e+1]) ++e;
  int tloc = bid - p.start[e];
  int tilesN = p.N[e] >> 5;
  int tn = tloc % tilesN, tk = tloc / tilesN;
  int k0 = tk << 5, n0 = tn << 5;
  const float* src = p.src[e];
  ushort* dst = p.dst[e];
  int K = p.K[e], N = p.N[e];
  int r = threadIdx.x >> 5, c = threadIdx.x & 31;
  #pragma unroll
  for (int i = 0; i < 4; ++i)
    lds[r + 8*i][c] = src[(size_t)(k0 + r + 8*i)*N + n0 + c];
  __syncthreads();
  #pragma unroll
  for (int i = 0; i < 4; ++i)
    dst[(size_t)(n0 + r + 8*i)*K + k0 + c] = f2bf(lds[c][r + 8*i]);
}

// ---------------- mgemm2: BM=64 BN=128 BK=64, bf16 A + bf16 B^T (qkv gather) -----
struct GP2 {
  const ushort* A0[6];
  const ushort* Bt[6];
  float* Cm[6];
  const int* idxp[6];
  int N, K;
};

__global__ __launch_bounds__(256) void kern_mgemm2(GP2 p){
  __shared__ __align__(16) ushort Asb[64*64];
  __shared__ __align__(16) ushort Bsb[128*64];
  __shared__ int idx_s[64];
  int z = blockIdx.z;
  const ushort* A0 = p.A0[z];
  const ushort* Bt = p.Bt[z];
  float* Cm = p.Cm[z];
  int tid = threadIdx.x;
  int m0 = blockIdx.x * 64;
  int n0 = blockIdx.y * 128;
  int lane = tid & 63, w = tid >> 6;
  int wr = w & 1, wc = w >> 1;
  int lr = lane & 15, ql = lane >> 4;

  if (tid < 64){
    int m = m0 + tid;
    idx_s[tid] = p.idxp[z][(m >> 10)*1024 + (m & 1023)];
  }
  __syncthreads();
  int gb = m0 >> 10;

  f32x4 acc[2][4];
  #pragma unroll
  for (int i = 0; i < 2; ++i)
    #pragma unroll
    for (int j = 0; j < 4; ++j) acc[i][j] = (f32x4){0.f,0.f,0.f,0.f};

  int kh = tid & 7;
  int rA = tid >> 3;
  for (int k0 = 0; k0 < p.K; k0 += 64){
    #pragma unroll
    for (int s = 0; s < 2; ++s){
      int m = rA + 32*s;
      const ushort* ap = A0 + ((size_t)(gb << 12) + idx_s[m])*(size_t)p.K + k0 + kh*8;
      short8 v = *(const short8*)ap;
      int byte = m*128 + ((kh*16) ^ ((m & 7)*16));
      *(short8*)((char*)Asb + byte) = v;
    }
    #pragma unroll
    for (int s = 0; s < 4; ++s){
      int n = rA + 32*s;
      short8 v = *(const short8*)(Bt + (size_t)(n0+n)*p.K + k0 + kh*8);
      int byte = n*128 + ((kh*16) ^ ((n & 7)*16));
      *(short8*)((char*)Bsb + byte) = v;
    }
    __syncthreads();
    short8 af[2][2], bf[4][2];
    #pragma unroll
    for (int fm = 0; fm < 2; ++fm){
      int row = wr*32 + fm*16 + lr;
      #pragma unroll
      for (int kq = 0; kq < 2; ++kq){
        int byte = row*128 + ((kq*64 + ql*16) ^ ((row & 7)*16));
        af[fm][kq] = *(const short8*)((const char*)Asb + byte);
      }
    }
    #pragma unroll
    for (int fn = 0; fn < 4; ++fn){
      int row = wc*64 + fn*16 + lr;
      #pragma unroll
      for (int kq = 0; kq < 2; ++kq){
        int byte = row*128 + ((kq*64 + ql*16) ^ ((row & 7)*16));
        bf[fn][kq] = *(const short8*)((const char*)Bsb + byte);
      }
    }
    #pragma unroll
    for (int kq = 0; kq < 2; ++kq)
      #pragma unroll
      for (int fm = 0; fm < 2; ++fm)
        #pragma unroll
        for (int fn = 0; fn < 4; ++fn)
          acc[fm][fn] = __builtin_amdgcn_mfma_f32_16x16x32_bf16(af[fm][kq], bf[fn][kq],
                                                                acc[fm][fn], 0, 0, 0);
    __syncthreads();
  }

  #pragma unroll
  for (int fm = 0; fm < 2; ++fm){
    #pragma unroll
    for (int fn = 0; fn < 4; ++fn){
      int n = n0 + wc*64 + fn*16 + lr;
      #pragma unroll
      for (int reg = 0; reg < 4; ++reg){
        int m = m0 + wr*32 + fm*16 + ql*4 + reg;
        Cm[(size_t)m*p.N + n] = acc[fm][fn][reg];
      }
    }
  }
}

// ---------------- hscore: h-GEMM (N=128) + fused gelu@Wout score reduction --------
struct HSP {
  const ushort* A0[2];
  const ushort* A1[2];
  const ushort* Bt[2];
  float* score;
  const float* ep0[2];
  const float* ep1[2];
  const float* ep2[2];
  const float* wout;
  const float* bout;
  int Mper;
};

__global__ __launch_bounds__(256) void kern_hscore(HSP p){
  __shared__ __align__(16) ushort Asb[128*64];
  __shared__ __align__(16) ushort Bsb[128*64];
  __shared__ float part[2][128];
  int z = blockIdx.z;
  const ushort* Bt = p.Bt[z];
  int tid = threadIdx.x;
  int m0 = blockIdx.x * 128;
  int lane = tid & 63, w = tid >> 6;
  int wr = w & 1, wc = w >> 1;
  int lr = lane & 15, ql = lane >> 4;

  f32x4 acc[4][4];
  #pragma unroll
  for (int i = 0; i < 4; ++i)
    #pragma unroll
    for (int j = 0; j < 4; ++j) acc[i][j] = (f32x4){0.f,0.f,0.f,0.f};

  int kh = tid & 7;
  int rA = tid >> 3;
  for (int k0 = 0; k0 < 2048; k0 += 64){
    const ushort* Asrc = (k0 < 1024) ? p.A0[z] : p.A1[z];
    int kk = (k0 & 1023) + kh*8;
    #pragma unroll
    for (int s = 0; s < 4; ++s){
      int m = rA + 32*s;
      short8 v = *(const short8*)(Asrc + (size_t)(m0+m)*1024 + kk);
      int byte = m*128 + ((kh*16) ^ ((m & 7)*16));
      *(short8*)((char*)Asb + byte) = v;
    }
    #pragma unroll
    for (int s = 0; s < 4; ++s){
      int n = rA + 32*s;
      short8 v = *(const short8*)(Bt + (size_t)n*2048 + k0 + kh*8);
      int byte = n*128 + ((kh*16) ^ ((n & 7)*16));
      *(short8*)((char*)Bsb + byte) = v;
    }
    __syncthreads();
    short8 af[4][2], bf[4][2];
    #pragma unroll
    for (int fm = 0; fm < 4; ++fm){
      int row = wr*64 + fm*16 + lr;
      #pragma unroll
      for (int kq = 0; kq < 2; ++kq){
        int byte = row*128 + ((kq*64 + ql*16) ^ ((row & 7)*16));
        af[fm][kq] = *(const short8*)((const char*)Asb + byte);
      }
    }
    #pragma unroll
    for (int fn = 0; fn < 4; ++fn){
      int row = wc*64 + fn*16 + lr;
      #pragma unroll
      for (int kq = 0; kq < 2; ++kq){
        int byte = row*128 + ((kq*64 + ql*16) ^ ((row & 7)*16));
        bf[fn][kq] = *(const short8*)((const char*)Bsb + byte);
      }
    }
    #pragma unroll
    for (int kq = 0; kq < 2; ++kq)
      #pragma unroll
      for (int fm = 0; fm < 4; ++fm)
        #pragma unroll
        for (int fn = 0; fn < 4; ++fn)
          acc[fm][fn] = __builtin_amdgcn_mfma_f32_16x16x32_bf16(af[fm][kq], bf[fn][kq],
                                                                acc[fm][fn], 0, 0, 0);
    __syncthreads();
  }

  float wv[4];
  #pragma unroll
  for (int fn = 0; fn < 4; ++fn) wv[fn] = p.wout[z*128 + wc*64 + fn*16 + lr];
  #pragma unroll
  for (int fm = 0; fm < 4; ++fm){
    #pragma unroll
    for (int reg = 0; reg < 4; ++reg){
      int m = m0 + wr*64 + fm*16 + ql*4 + reg;
      int bl = m >> 12, g = m & 4095;
      int gy = g >> 6, gx = g & 63;
      float cy = ((float)gy + 0.5f)*(1.f/64.f);
      float cx = ((float)gx + 0.5f)*(1.f/64.f);
      float ps = 0.f;
      #pragma unroll
      for (int fn = 0; fn < 4; ++fn){
        int n = wc*64 + fn*16 + lr;
        float o = acc[fm][fn][reg] + p.ep0[z][bl*128 + n] + cy*p.ep1[z][n]
                + cx*p.ep1[z][128 + n] + p.ep2[z][n];
        ps += geluf(o)*wv[fn];
      }
      #pragma unroll
      for (int off = 8; off > 0; off >>= 1) ps += __shfl_xor(ps, off);
      if (lr == 0) part[wc][wr*64 + fm*16 + ql*4 + reg] = ps;
    }
  }
  __syncthreads();
  if (tid < 128)
    p.score[(size_t)z*p.Mper + m0 + tid] = part[0][tid] + part[1][tid] + p.bout[z];
}

// ---------------- byp: gather bypass blend over 3072 non-selected rows -----------
struct BYP {
  const ushort* A0[2];
  const ushort* A1[2];
  const ushort* Bt[2];
  float* Cm[2];
  const int* nsel[2];
  const float* bias[2];
  const ushort* vt[2];
  const ushort* it[2];
};

__global__ __launch_bounds__(256) void kern_byp(BYP p){
  __shared__ __align__(16) ushort Asb[128*64];
  __shared__ __align__(16) ushort Bsb[128*64];
  __shared__ int idx_s[128];
  int z = blockIdx.z;
  const ushort* Bt = p.Bt[z];
  int tid = threadIdx.x;
  int gb  = blockIdx.x / 24;
  int m0l = (blockIdx.x % 24) * 128;
  int n0 = blockIdx.y * 128;
  int lane = tid & 63, w = tid >> 6;
  int wr = w & 1, wc = w >> 1;
  int lr = lane & 15, ql = lane >> 4;

  if (tid < 128)
    idx_s[tid] = p.nsel[z][(size_t)gb*3072 + m0l + tid];
  __syncthreads();

  f32x4 acc[4][4];
  #pragma unroll
  for (int i = 0; i < 4; ++i)
    #pragma unroll
    for (int j = 0; j < 4; ++j) acc[i][j] = (f32x4){0.f,0.f,0.f,0.f};

  int kh = tid & 7;
  int rA = tid >> 3;
  for (int k0 = 0; k0 < 2048; k0 += 64){
    const ushort* Asrc = (k0 < 1024) ? p.A0[z] : p.A1[z];
    int kk = (k0 & 1023) + kh*8;
    #pragma unroll
    for (int s = 0; s < 4; ++s){
      int m = rA + 32*s;
      size_t grow = (size_t)(gb << 12) + idx_s[m];
      short8 v = *(const short8*)(Asrc + grow*1024 + kk);
      int byte = m*128 + ((kh*16) ^ ((m & 7)*16));
      *(short8*)((char*)Asb + byte) = v;
    }
    #pragma unroll
    for (int s = 0; s < 4; ++s){
      int n = rA + 32*s;
      short8 v = *(const short8*)(Bt + (size_t)(n0+n)*2048 + k0 + kh*8);
      int byte = n*128 + ((kh*16) ^ ((n & 7)*16));
      *(short8*)((char*)Bsb + byte) = v;
    }
    __syncthreads();
    short8 af[4][2], bf[4][2];
    #pragma unroll
    for (int fm = 0; fm < 4; ++fm){
      int row = wr*64 + fm*16 + lr;
      #pragma unroll
      for (int kq = 0; kq < 2; ++kq){
        int byte = row*128 + ((kq*64 + ql*16) ^ ((row & 7)*16));
        af[fm][kq] = *(const short8*)((const char*)Asb + byte);
      }
    }
    #pragma unroll
    for (int fn = 0; fn < 4; ++fn){
      int row = wc*64 + fn*16 + lr;
      #pragma unroll
      for (int kq = 0; kq < 2; ++kq){
        int byte = row*128 + ((kq*64 + ql*16) ^ ((row & 7)*16));
        bf[fn][kq] = *(const short8*)((const char*)Bsb + byte);
      }
    }
    #pragma unroll
    for (int kq = 0; kq < 2; ++kq)
      #pragma unroll
      for (int fm = 0; fm < 4; ++fm)
        #pragma unroll
        for (int fn = 0; fn < 4; ++fn)
          acc[fm][fn] = __builtin_amdgcn_mfma_f32_16x16x32_bf16(af[fm][kq], bf[fn][kq],
                                                                acc[fm][fn], 0, 0, 0);
    __syncthreads();
  }

  float* Cm = p.Cm[z];
  const ushort* vtp = p.vt[z];
  const ushort* itp = p.it[z];
  #pragma unroll
  for (int fm = 0; fm < 4; ++fm){
    #pragma unroll
    for (int fn = 0; fn < 4; ++fn){
      int n = n0 + wc*64 + fn*16 + lr;
      float bia = p.bias[z][n];
      #pragma unroll
      for (int reg = 0; reg < 4; ++reg){
        int mloc = wr*64 + fm*16 + ql*4 + reg;
        size_t off = ((size_t)(gb << 12) + idx_s[mloc])*1024 + n;
        float vt = bf2f(vtp[off]);
        float it = bf2f(itp[off]);
        float gg = 1.f/(1.f + expf(-(acc[fm][fn][reg] + bia)));
        Cm[off] = gg*vt + (1.f-gg)*it;
      }
    }
  }
}

// ---------------- scatter GEMM: fused_sel = vs(bf16) + o@Wo, K=128 ----------------
struct SCP {
  const float* A0[2];
  const float* Bm[2];
  float* Cm[2];
  const int* idxp[2];
  const ushort* vtb[2];
};

__global__ __launch_bounds__(256) void kern_scat(SCP p){
  __shared__ __align__(16) ushort Asb[64*40];
  __shared__ __align__(16) ushort Bsb[128*40];
  __shared__ int idx_s[64];
  int z = blockIdx.z;
  const float* A0 = p.A0[z];
  const float* Bm = p.Bm[z];
  float* Cm = p.Cm[z];
  int tid = threadIdx.x;
  int m0 = blockIdx.y * 64;
  int n0 = blockIdx.x * 128;
  int lane = tid & 63, w = tid >> 6;
  int wr = w & 1, wc = w >> 1;
  int lr = lane & 15, ql = lane >> 4;
  if (tid < 64){
    int m = m0 + tid;
    idx_s[tid] = p.idxp[z][(m >> 10)*1024 + (m & 1023)];
  }
  __syncthreads();
  int gb = m0 >> 10;

  f32x4 acc[2][4];
  #pragma unroll
  for (int i = 0; i < 2; ++i)
    #pragma unroll
    for (int j = 0; j < 4; ++j) acc[i][j] = (f32x4){0.f,0.f,0.f,0.f};

  for (int k0 = 0; k0 < 128; k0 += 32){
    {
      int m = tid & 63;
      int khh = (tid >> 6) * 8;
      const float* ap = A0 + (size_t)(m0+m)*128 + k0 + khh;
      float4 f0 = *(const float4*)ap;
      float4 f1 = *(const float4*)(ap + 4);
      short8 v;
      v[0]=(short)f2bf(f0.x); v[1]=(short)f2bf(f0.y);
      v[2]=(short)f2bf(f0.z); v[3]=(short)f2bf(f0.w);
      v[4]=(short)f2bf(f1.x); v[5]=(short)f2bf(f1.y);
      v[6]=(short)f2bf(f1.z); v[7]=(short)f2bf(f1.w);
      *(short8*)&Asb[m*40 + khh] = v;
    }
    #pragma unroll
    for (int e0 = 0; e0 < 512; e0 += 256){
      int e = e0 + tid;
      int n = e & 127;
      int khh = (e >> 7) * 8;
      const float* bp = Bm + (size_t)(k0+khh)*1024 + n0 + n;
      short8 v;
      #pragma unroll
      for (int j = 0; j < 8; ++j) v[j] = (short)f2bf(bp[(size_t)j*1024]);
      *(short8*)&Bsb[n*40 + khh] = v;
    }
    __syncthreads();
    short8 af[2], bf[4];
    #pragma unroll
    for (int fr = 0; fr < 2; ++fr)
      af[fr] = *(const short8*)&Asb[(wr*32 + fr*16 + lr)*40 + ql*8];
    #pragma unroll
    for (int fc = 0; fc < 4; ++fc)
      bf[fc] = *(const short8*)&Bsb[(wc*64 + fc*16 + lr)*40 + ql*8];
    #pragma unroll
    for (int fr = 0; fr < 2; ++fr)
      #pragma unroll
      for (int fc = 0; fc < 4; ++fc)
        acc[fr][fc] = __builtin_amdgcn_mfma_f32_16x16x32_bf16(af[fr], bf[fc],
                                                              acc[fr][fc], 0, 0, 0);
    __syncthreads();
  }

  #pragma unroll
  for (int fr = 0; fr < 2; ++fr){
    #pragma unroll
    for (int fc = 0; fc < 4; ++fc){
      int n = n0 + wc*64 + fc*16 + lr;
      #pragma unroll
      for (int reg = 0; reg < 4; ++reg){
        int mloc = wr*32 + fr*16 + ql*4 + reg;
        int gt = idx_s[mloc];
        size_t off = ((size_t)(gb << 12) + gt)*1024 + n;
        Cm[off] = acc[fr][fc][reg] + bf2f(p.vtb[z][off]);
      }
    }
  }
}

// ---------------- top-1024 of 4096 + complement (bitonic, jax tie-break) ----------
__global__ __launch_bounds__(1024) void kern_topk(const float* __restrict__ score,
    int* __restrict__ idx_out, int* __restrict__ nsel_out){
  __shared__ u64 keys[4096];
  int b = blockIdx.x, t = threadIdx.x;
  for (int i = t; i < 4096; i += 1024){
    float s = score[b*4096 + i];
    uint u = __float_as_uint(s);
    uint msk = (u & 0x80000000u) ? ~u : (u | 0x80000000u);
    keys[i] = ((u64)msk << 32) | (uint)(4095 - i);
  }
  __syncthreads();
  for (int k = 2; k <= 4096; k <<= 1){
    for (int j = k >> 1; j > 0; j >>= 1){
      for (int i = t; i < 4096; i += 1024){
        int l = i ^ j;
        if (l > i){
          u64 a = keys[i], c = keys[l];
          bool descB = ((i & k) == 0);
          bool sw = descB ? (a < c) : (a > c);
          if (sw){ keys[i] = c; keys[l] = a; }
        }
      }
      __syncthreads();
    }
  }
  idx_out[b*1024 + t] = 4095 - (int)(keys[t] & 0xFFFFFFFFu);
  for (int i = t; i < 3072; i += 1024)
    nsel_out[(size_t)b*3072 + i] = 4095 - (int)(keys[1024 + i] & 0xFFFFFFFFu);
}

// ---------------- attention partials (k-split flash, 128-thr q-split) ----------
__global__ __launch_bounds__(128) void kern_attn_part(const float* __restrict__ qb,
    const float* __restrict__ kb, const float* __restrict__ vb,
    float* __restrict__ paoa, float* __restrict__ pml){
  __shared__ float Ks[64][32];
  __shared__ float Vs[64][32];
  int t = threadIdx.x;
  int hh = blockIdx.y;
  int zc = blockIdx.z;
  int zf = zc >> 2, c = zc & 3;
  size_t boff = (size_t)zf*131072;
  int jq = blockIdx.x*128 + t;
  float qv[32];
  {
    const float4* qp = (const float4*)(qb + boff + (size_t)jq*128 + hh*32);
    #pragma unroll
    for (int d = 0; d < 8; ++d) ((float4*)qv)[d] = qp[d];
  }
  float mrun = -3.0e38f, lrun = 0.f;
  float oa[32];
  #pragma unroll
  for (int d = 0; d < 32; ++d) oa[d] = 0.f;
  for (int kt = 0; kt < 4; ++kt){
    int k0 = c*256 + kt*64;
    #pragma unroll
    for (int rep = 0; rep < 4; ++rep){
      int f = t + rep*128;
      int r = f >> 3, q4 = f & 7;
      size_t base = boff + (size_t)(k0 + r)*128 + hh*32 + 4*q4;
      *(float4*)&Ks[r][4*q4] = *(const float4*)(kb + base);
      *(float4*)&Vs[r][4*q4] = *(const float4*)(vb + base);
    }
    __syncthreads();
    #pragma unroll
    for (int st = 0; st < 4; ++st){
      float s[16];
      #pragma unroll
      for (int j = 0; j < 16; ++j){
        float v = 0.f;
        #pragma unroll
        for (int d = 0; d < 32; ++d) v += qv[d]*Ks[st*16+j][d];
        s[j] = v * 0.17677669529663687f;
      }
      float mt = s[0];
      #pragma unroll
      for (int j = 1; j < 16; ++j) mt = fmaxf(mt, s[j]);
      float mnew = fmaxf(mrun, mt);
      float alpha = expf(mrun - mnew);
      lrun *= alpha;
      #pragma unroll
      for (int d = 0; d < 32; ++d) oa[d] *= alpha;
      #pragma unroll
      for (int j = 0; j < 16; ++j){
        float pe = expf(s[j] - mnew);
        lrun += pe;
        #pragma unroll
        for (int d = 0; d < 32; ++d) oa[d] += pe*Vs[st*16+j][d];
      }
      mrun = mnew;
    }
    __syncthreads();
  }
  size_t rec = (((size_t)zf*4 + hh)*4 + c)*1024 + jq;
  float* pp = paoa + rec*32;
  #pragma unroll
  for (int d = 0; d < 8; ++d) ((float4*)pp)[d] = ((float4*)oa)[d];
  pml[rec*2]   = mrun;
  pml[rec*2+1] = lrun;
}

// ---------------- attention combine ----------------
__global__ __launch_bounds__(256) void kern_attn_comb(const float* __restrict__ paoa,
    const float* __restrict__ pml, float* __restrict__ ob,
    const float* __restrict__ ipint, int PB, int b0){
  int t = threadIdx.x;
  int hh = blockIdx.y, zf = blockIdx.z;
  int jq = blockIdx.x*256 + t;
  size_t rbase = (((size_t)zf*4 + hh)*4)*1024 + jq;
  float mc[4], lc[4];
  #pragma unroll
  for (int c = 0; c < 4; ++c){
    mc[c] = pml[(rbase + c*1024)*2];
    lc[c] = pml[(rbase + c*1024)*2 + 1];
  }
  float M = fmaxf(fmaxf(mc[0], mc[1]), fmaxf(mc[2], mc[3]));
  float wgt[4], L = 0.f;
  #pragma unroll
  for (int c = 0; c < 4; ++c){ wgt[c] = expf(mc[c] - M); L += lc[c]*wgt[c]; }
  float inv = 1.f/L;
  int br = (zf >= PB) ? 1 : 0;
  int bb = zf - br*PB;
  const float* ip = ipint + br*512 + (b0+bb)*128 + hh*32;
  float* op = ob + (size_t)zf*131072 + (size_t)jq*128 + hh*32;
  #pragma unroll
  for (int d = 0; d < 32; ++d){
    float o = 0.f;
    #pragma unroll
    for (int c = 0; c < 4; ++c) o += paoa[(rbase + c*1024)*32 + d]*wgt[c];
    op[d] = o*inv + ip[d];
  }
}

// ---------------- conv weight transform ----------------
__global__ __launch_bounds__(256) void kern_wt(const float* __restrict__ w1,
    const float* __restrict__ w2, ushort* __restrict__ wt){
  int blk = blockIdx.x;
  const float* src = (blk < 9) ? w1 : w2;
  int tap = blk - (blk < 9 ? 0 : 9);
  ushort* dst = wt + (blk < 9 ? 0 : 36864) + tap*4096;
  for (int e = threadIdx.x; e < 4096; e += 256){
    dst[e] = f2bf(src[(size_t)e*9 + tap]);
  }
}

// ---------------- implicit-GEMM 3x3 conv via MFMA ----------------
template<int MODE>
__global__ __launch_bounds__(256) void kern_cmfma(const float* __restrict__ in,
    const ushort* __restrict__ wt, const float* __restrict__ bias,
    float* __restrict__ out,
    const float* __restrict__ modg, const float* __restrict__ modb,
    const float* __restrict__ vis, const float* __restrict__ irf){
  __shared__ __align__(16) ushort ins[64][268];
  int t = threadIdx.x;
  int y = blockIdx.x, b = blockIdx.y;
  int lane = t & 63, w = t >> 6;
  int wc = w & 1, wx = w >> 1;
  int lr = lane & 15, ql = lane >> 4;

  f32x4 acc[2][8];
  #pragma unroll
  for (int f = 0; f < 2; ++f)
    #pragma unroll
    for (int xf = 0; xf < 8; ++xf) acc[f][xf] = (f32x4){0.f,0.f,0.f,0.f};

  for (int dy = 0; dy < 3; ++dy){
    int yy = y + dy - 1;
    if (yy < 0 || yy > 255) continue;
    const float* src = in + ((size_t)(b*64)*256 + yy)*256;
    #pragma unroll
    for (int s = 0; s < 16; ++s){
      int e = t + s*256;
      int ci = e >> 6, q = e & 63;
      float4 f4 = *(const float4*)(src + (size_t)ci*65536 + 4*q);
      uint lo = (uint)f2bf(f4.x) | ((uint)f2bf(f4.y) << 16);
      uint hi = (uint)f2bf(f4.z) | ((uint)f2bf(f4.w) << 16);
      *(uint2*)&ins[ci][4*q + 4] = make_uint2(lo, hi);
    }
    if (t < 128){
      int r = t & 63;
      ins[r][(t >> 6) ? 260 : 3] = 0;
    }
    __syncthreads();
    short8 wf[2][3][2];
    #pragma unroll
    for (int kk = 0; kk < 2; ++kk)
      #pragma unroll
      for (int dx = 0; dx < 3; ++dx)
        #pragma unroll
        for (int f = 0; f < 2; ++f)
          wf[kk][dx][f] = *(const short8*)(wt +
            (size_t)((dy*3 + dx)*64 + 32*wc + 16*f + lr)*64 + kk*32 + ql*8);
    #pragma unroll
    for (int kk = 0; kk < 2; ++kk){
      const ushort* bp = &ins[kk*32 + ql*8][0];
      #pragma unroll
      for (int dx = 0; dx < 3; ++dx){
        int xb = 128*wx + lr + dx + 3;
        #pragma unroll
        for (int xf = 0; xf < 8; ++xf){
          int xi = xb + 16*xf;
          short8 bf;
          #pragma unroll
          for (int e = 0; e < 8; ++e) bf[e] = (short)bp[e*268 + xi];
          acc[0][xf] = __builtin_amdgcn_mfma_f32_16x16x32_bf16(wf[kk][dx][0], bf,
                                                               acc[0][xf], 0, 0, 0);
          acc[1][xf] = __builtin_amdgcn_mfma_f32_16x16x32_bf16(wf[kk][dx][1], bf,
                                                               acc[1][xf], 0, 0, 0);
        }
      }
    }
    __syncthreads();
  }

  #pragma unroll
  for (int f = 0; f < 2; ++f){
    #pragma unroll
    for (int xf = 0; xf < 8; ++xf){
      int x = 128*wx + 16*xf + lr;
      #pragma unroll
      for (int reg = 0; reg < 4; ++reg){
        int co = 32*wc + 16*f + ql*4 + reg;
        float v = acc[f][xf][reg] + bias[co];
        size_t oi = ((size_t)(b*64 + co)*256 + y)*256 + x;
        if (MODE == 1){
          out[oi] = fmaxf(v, 0.f);
        } else {
          out[oi] = v*modg[b*64+co] + modb[b*64+co] + 0.5f*(vis[oi] + irf[oi]);
        }
      }
    }
  }
}

// ---------------- launch ----------------
extern "C" void kernel_launch(void* const* d_in, const int* in_sizes, int n_in,
                              void* d_out, int out_size, void* d_ws, size_t ws_size,
                              hipStream_t stream){
  (void)in_sizes; (void)n_in; (void)out_size;
  const float* vis  = (const float*)d_in[0];
  const float* irf  = (const float*)d_in[1];
  const float* bank = (const float*)d_in[2];
  const float* Wr   = (const float*)d_in[3];
  const float* br   = (const float*)d_in[4];
  const float* Wtok = (const float*)d_in[5];
  const float* Wpri = (const float*)d_in[6];
  const float* Wco  = (const float*)d_in[7];
  const float* bs   = (const float*)d_in[8];
  const float* Wout = (const float*)d_in[9];
  const float* bout = (const float*)d_in[10];
  const float* Wq   = (const float*)d_in[11];
  const float* Wk   = (const float*)d_in[12];
  const float* Wv   = (const float*)d_in[13];
  const float* Wo   = (const float*)d_in[14];
  const float* Wint = (const float*)d_in[15];
  const float* Wbyp = (const float*)d_in[16];
  const float* bbyp = (const float*)d_in[17];
  const float* c1w  = (const float*)d_in[18];
  const float* c1b  = (const float*)d_in[19];
  const float* c2w  = (const float*)d_in[20];
  const float* c2b  = (const float*)d_in[21];
  const float* Wa1  = (const float*)d_in[22];
  const float* ba1  = (const float*)d_in[23];
  const float* Wa2  = (const float*)d_in[24];
  const float* ba2  = (const float*)d_in[25];

  auto needB = [](int PB)->size_t{
    return ((size_t)PB*14755840 + 2792448) * 4;
  };
  const int PB = (ws_size >= needB(4)) ? 4 : (ws_size >= needB(2)) ? 2 : 1;

  float* ws = (float*)d_ws;
  const size_t PLF = (size_t)PB*4194304;
  float* PH4 = ws;                                 // fwd im transient + FULL_ph (fp32)
  ushort* ABV = (ushort*)(ws + PLF);               // 4 bf16 planes = 2*PLF floats
  ushort* PBV = ABV + PLF;
  ushort* ABI = PBV + PLF;
  ushort* PBI = ABI + PLF;
  float* S0 = ws + PLF;                            // iFFT fp32 transients alias bf16 region
  float* S1 = S0 + PLF;
  float* sm = ws + 3*PLF;
  float* hbuf  = sm; sm += (size_t)2*PB*524288;    // nsel + paoa alias here
  float* qbuf  = sm; sm += (size_t)2*PB*131072;
  float* kbuf  = sm; sm += (size_t)2*PB*131072;
  float* vbuf  = sm; sm += (size_t)2*PB*131072;
  float* obuf  = sm; sm += (size_t)2*PB*131072;
  float* score = sm; sm += (size_t)2*PB*4096;
  int*   idxb  = (int*)sm; sm += (size_t)2*PB*1024;
  float* pml   = sm; sm += (size_t)PB*65536;
  ushort* BTtok = (ushort*)sm;                     // [2][128][2048]
  ushort* BTbyp = BTtok + 524288;                  // [2][1024][2048]
  ushort* BTq   = BTbyp + 4194304;                 // [2][128][1024]
  ushort* BTk   = BTq + 262144;
  ushort* BTv   = BTk + 262144;
  sm += 2752512;
  float* pooled= sm; sm += 512;
  float* IP    = sm; sm += 1024;
  float* IPint = sm; sm += 1024;
  float* modg  = sm; sm += 256;
  float* modb  = sm; sm += 256;
  ushort* wtb = (ushort*)sm; sm += 36864;
  int*   nselb = (int*)hbuf;                       // [2PB][3072] (dead before paoa)
  float* paoa  = hbuf;

  kern_pool <<<512, 256, 0, stream>>>(vis, irf, pooled);
  kern_small<<<1, 256, 0, stream>>>(pooled, Wr, br, bank, Wpri, Wint,
                                    Wa1, ba1, Wa2, ba2, IP, IPint, modg, modb);
  kern_wt   <<<18, 256, 0, stream>>>(c1w, c2w, wtb);
  {
    TRS tr{};
    const float* srcs[10] = {Wtok, Wtok+262144, Wbyp, Wbyp+2097152,
                             Wq, Wq+131072, Wk, Wk+131072, Wv, Wv+131072};
    ushort* dsts[10] = {BTtok, BTtok+262144, BTbyp, BTbyp+2097152,
                        BTq, BTq+131072, BTk, BTk+131072, BTv, BTv+131072};
    int Ks[10] = {2048,2048,2048,2048,1024,1024,1024,1024,1024,1024};
    int Ns[10] = {128,128,1024,1024,128,128,128,128,128,128};
    int tiles[10] = {256,256,2048,2048,128,128,128,128,128,128};
    int acc0 = 0;
    for (int i = 0; i < 10; ++i){
      tr.src[i] = srcs[i]; tr.dst[i] = dsts[i];
      tr.K[i] = Ks[i]; tr.N[i] = Ns[i];
      tr.start[i] = acc0; acc0 += tiles[i];
    }
    tr.start[10] = acc0;
    kern_tr<<<acc0, 256, 0, stream>>>(tr);
  }

  for (int b0 = 0; b0 < 4; b0 += PB){
    const float* vis_b = vis + (size_t)b0*4194304;
    const float* ir_b  = irf + (size_t)b0*4194304;
    float* OUT = (float*)d_out + (size_t)b0*4194304;

    // packed forward FFT2: Z = FFT2(vis + i*ir), unpack -> 4 bf16 amp/ph planes
    kern_fft_rows_pack<<<PB*8192, 256, 0, stream>>>(vis_b, ir_b, OUT, PH4);
    kern_fft_cols_pack<<<PB*1024, 256, 0, stream>>>(OUT, PH4, ABV, PBV, ABI, PBI);

    {  // h-GEMM with fused score (h never stored)
      HSP p{};
      p.A0[0]=ABV; p.A1[0]=ABI; p.A0[1]=PBV; p.A1[1]=PBI;
      for (int z = 0; z < 2; ++z){
        p.Bt[z] = BTtok + (size_t)z*262144;
        p.ep0[z] = IP + z*512 + b0*128;
        p.ep1[z] = Wco + z*256;
        p.ep2[z] = bs + z*128;
      }
      p.score = score; p.wout = Wout; p.bout = bout;
      p.Mper = PB*4096;
      kern_hscore<<<dim3(PB*32, 1, 2), 256, 0, stream>>>(p);
    }
    kern_topk<<<2*PB, 1024, 0, stream>>>(score, idxb, nselb);
    {  // bypass blend over 3072 non-selected rows per (branch,batch)
      BYP p{};
      p.A0[0]=ABV; p.A1[0]=ABI; p.A0[1]=PBV; p.A1[1]=PBI;
      p.vt[0]=ABV; p.it[0]=ABI; p.vt[1]=PBV; p.it[1]=PBI;
      p.Cm[0]=OUT; p.Cm[1]=PH4;
      for (int z = 0; z < 2; ++z){
        p.Bt[z] = BTbyp + (size_t)z*2097152;
        p.bias[z] = bbyp + z*1024;
        p.nsel[z] = nselb + (size_t)z*PB*3072;
      }
      kern_byp<<<dim3(PB*24, 8, 2), 256, 0, stream>>>(p);
    }
    {  // q,k,v gathered rows
      GP2 p{};
      const ushort* Aplanes[6] = {ABV, ABI, ABI, PBV, PBI, PBI};
      const ushort* Bmats[6] = {BTq, BTk, BTv, BTq+131072, BTk+131072, BTv+131072};
      float* Cms[6] = {qbuf, kbuf, vbuf,
                       qbuf+(size_t)PB*131072, kbuf+(size_t)PB*131072,
                       vbuf+(size_t)PB*131072};
      for (int z = 0; z < 6; ++z){
        p.A0[z] = Aplanes[z]; p.Bt[z] = Bmats[z]; p.Cm[z] = Cms[z];
        p.idxp[z] = idxb + (z < 3 ? 0 : PB*1024);
      }
      p.N = 128; p.K = 1024;
      kern_mgemm2<<<dim3(PB*16, 1, 6), 256, 0, stream>>>(p);
    }
    // k-split flash attention (nsel dead -> paoa aliases hbuf)
    kern_attn_part<<<dim3(8, 4, 2*PB*4), 128, 0, stream>>>(qbuf, kbuf, vbuf,
                                                           paoa, pml);
    kern_attn_comb<<<dim3(4, 4, 2*PB), 256, 0, stream>>>(paoa, pml, obuf,
                                                         IPint, PB, b0);
    {  // fused_sel = vs(bf16) + o@Wo, scatter into FULL (selected rows)
      SCP p{};
      p.A0[0]=obuf; p.A0[1]=obuf+(size_t)PB*131072;
      p.Bm[0]=Wo; p.Bm[1]=Wo+131072;
      p.Cm[0]=OUT; p.Cm[1]=PH4;
      p.vtb[0]=ABV; p.vtb[1]=PBV;
      p.idxp[0]=idxb; p.idxp[1]=idxb+PB*1024;
      kern_scat<<<dim3(8, PB*16, 2), 256, 0, stream>>>(p);
    }

    // spec = famp*e^{i fph}; inverse FFT2 -> spatial into OUT
    kern_ifft_rows_spec<<<PB*4096, 256, 0, stream>>>(OUT, PH4, S0, S1);
    kern_fft_cols_inv  <<<PB*1024, 256, 0, stream>>>(S0, S1, OUT);
  }

  // convs (MFMA): d_out(spatial) -> ws[0..16.78M floats) (conv1+relu) -> d_out
  kern_cmfma<1><<<dim3(256, 4), 256, 0, stream>>>((float*)d_out, wtb, c1b, ws,
                                                  nullptr, nullptr, nullptr, nullptr);
  kern_cmfma<2><<<dim3(256, 4), 256, 0, stream>>>(ws, wtb + 36864, c2b, (float*)d_out,
                                                  modg, modb, vis, irf);
}

// Round 14
// 1230.885 us; speedup vs baseline: 1.1975x; 1.0492x over previous
//
#include <hip/hip_runtime.h>

typedef unsigned int uint;
typedef unsigned short ushort;
typedef unsigned long long u64;
typedef __attribute__((ext_vector_type(8))) short short8;
typedef __attribute__((ext_vector_type(4))) float f32x4;

__device__ __forceinline__ uint brev8(uint x){ return __brev(x) >> 24; }
__device__ __forceinline__ float geluf(float x){
  return 0.5f*x*(1.f + tanhf(0.7978845608028654f*(x + 0.044715f*x*x*x)));
}
__device__ __forceinline__ ushort f2bf(float f){
  unsigned u = __float_as_uint(f);
  unsigned r = u + 0x7FFFu + ((u >> 16) & 1u);
  return (ushort)(r >> 16);
}
__device__ __forceinline__ float bf2f(ushort u){
  return __uint_as_float((uint)u << 16);
}

// ---------------- pooled mean ----------------
__global__ __launch_bounds__(256) void kern_pool(const float* __restrict__ vis,
                                                 const float* __restrict__ irf,
                                                 float* __restrict__ pooled){
  __shared__ float red[256];
  int bc = blockIdx.x;
  int b = bc >> 7, cc = bc & 127;
  const float* src = (cc < 64) ? (vis + (size_t)(b*64+cc)*65536)
                               : (irf + (size_t)(b*64+(cc-64))*65536);
  float s = 0.f;
  for (int i = threadIdx.x; i < 65536; i += 256) s += src[i];
  red[threadIdx.x] = s;
  __syncthreads();
  for (int off = 128; off > 0; off >>= 1){
    if (threadIdx.x < off) red[threadIdx.x] += red[threadIdx.x + off];
    __syncthreads();
  }
  if (threadIdx.x == 0) pooled[bc] = red[0] * (1.f/65536.f);
}

// ---------------- prompt/intent/affine small ops ----------------
__global__ __launch_bounds__(256) void kern_small(const float* __restrict__ pooled,
    const float* __restrict__ Wr, const float* __restrict__ br,
    const float* __restrict__ bank, const float* __restrict__ Wpri,
    const float* __restrict__ Wint, const float* __restrict__ Wa1,
    const float* __restrict__ ba1, const float* __restrict__ Wa2,
    const float* __restrict__ ba2,
    float* __restrict__ IP, float* __restrict__ IPint,
    float* __restrict__ modg, float* __restrict__ modb){
  __shared__ float logit_s[16];
  __shared__ float pw_s[16];
  __shared__ float intent_s[4][64];
  __shared__ float t1_s[4][128];
  int t = threadIdx.x;
  if (t < 16){
    int b = t >> 2, j = t & 3;
    float s = br[j];
    for (int k = 0; k < 128; ++k) s += pooled[b*128+k]*Wr[k*4+j];
    logit_s[t] = s;
  }
  __syncthreads();
  if (t < 4){
    int b = t;
    float m = logit_s[b*4];
    for (int j = 1; j < 4; ++j) m = fmaxf(m, logit_s[b*4+j]);
    float e[4], sum = 0.f;
    for (int j = 0; j < 4; ++j){ e[j] = expf(logit_s[b*4+j]-m); sum += e[j]; }
    for (int j = 0; j < 4; ++j) pw_s[b*4+j] = e[j]/sum;
  }
  __syncthreads();
  {
    int b = t >> 6, p = t & 63;
    float s = 0.f;
    for (int j = 0; j < 4; ++j) s += pw_s[b*4+j]*bank[j*64+p];
    intent_s[b][p] = s;
  }
  __syncthreads();
  for (int o = t; o < 1024; o += 256){
    int i = o >> 9, rem = o & 511, b = rem >> 7, n = rem & 127;
    float s1 = 0.f, s2 = 0.f;
    for (int p = 0; p < 64; ++p){
      float iv = intent_s[b][p];
      s1 += iv * Wpri[(i*64+p)*128 + n];
      s2 += iv * Wint[(i*64+p)*128 + n];
    }
    IP[o] = s1; IPint[o] = s2;
  }
  for (int o = t; o < 512; o += 256){
    int b = o >> 7, n = o & 127;
    float s = ba1[n];
    for (int p = 0; p < 64; ++p) s += intent_s[b][p]*Wa1[p*128+n];
    t1_s[b][n] = geluf(s);
  }
  __syncthreads();
  for (int o = t; o < 512; o += 256){
    int b = o >> 7, n = o & 127;
    float s = ba2[n];
    for (int p = 0; p < 128; ++p) s += t1_s[b][p]*Wa2[p*128+n];
    if (n < 64) modg[b*64+n] = 1.f + 0.1f*tanhf(s);
    else        modb[b*64+(n-64)] = 0.1f*s;
  }
}

// ---------------- packed forward row FFT: Z = FFT(vis + i*ir) per row ----------
__global__ __launch_bounds__(256) void kern_fft_rows_pack(const float* __restrict__ xv,
    const float* __restrict__ xi, float* __restrict__ sre, float* __restrict__ sim){
  __shared__ float re[2][256], im[2][256];
  __shared__ float twr[128], twi[128];
  int t = threadIdx.x;
  if (t < 128){
    float a = -6.2831853071795864f * (float)t * (1.f/256.f);
    sincosf(a, &twi[t], &twr[t]);
  }
  int r = t >> 7, jj = t & 127;
  size_t row = (size_t)blockIdx.x*2 + r;
  {
    const float* vp = xv + row*256;
    const float* ip = xi + row*256;
    re[r][jj] = vp[jj]; re[r][jj+128] = vp[jj+128];
    im[r][jj] = ip[jj]; im[r][jj+128] = ip[jj+128];
  }
  __syncthreads();
  for (int s = 0; s < 8; ++s){
    int half = 128 >> s;
    int j = jj & (half-1);
    int g = jj >> (7-s);
    int k = (g << (8-s)) + j;
    int m = j << s;
    float wc = twr[m], ws = twi[m];
    float are = re[r][k],      aim = im[r][k];
    float bre = re[r][k+half], bim = im[r][k+half];
    re[r][k] = are + bre; im[r][k] = aim + bim;
    float tr = are - bre, ti = aim - bim;
    re[r][k+half] = tr*wc - ti*ws;
    im[r][k+half] = tr*ws + ti*wc;
    __syncthreads();
  }
  {
    float* orp = sre + row*256; float* oip = sim + row*256;
    int w1 = jj, w2 = jj + 128;
    orp[w1] = re[r][brev8(w1)]; oip[w1] = im[r][brev8(w1)];
    orp[w2] = re[r][brev8(w2)]; oip[w2] = im[r][brev8(w2)];
  }
}

// ---------------- packed column FFT + unpack (quad-aligned, swizzled LDS) ----------
// 18 LDS columns: 0..7 = v 8j..8j+7; 8..15 = v 248-8j..255-8j; 16 = (256-8j)&255;
// 17 = 8j+8.  Mirror col: c=0->16, c=8->17, else 16-c.  Row swizzle p(r)=r^(r>>4).
__global__ __launch_bounds__(256) void kern_fft_cols_pack(const float* __restrict__ sre,
    const float* __restrict__ sim, ushort* __restrict__ AV, ushort* __restrict__ PV,
    ushort* __restrict__ AI, ushort* __restrict__ PI){
  __shared__ float reL[256*19];
  __shared__ float imL[256*19];
  __shared__ float twr[128], twi[128];
  int t = threadIdx.x;
  if (t < 128){
    float a = -6.2831853071795864f * (float)t * (1.f/256.f);
    sincosf(a, &twi[t], &twr[t]);
  }
  int img = blockIdx.x >> 4;
  int j = blockIdx.x & 15;
  int vA = 8*j;
  int vB = 248 - 8*j;
  int v16 = (256 - 8*j) & 255;
  int v17 = 8*j + 8;
  {
    const float* pr = sre + ((size_t)img*256 + t)*256;
    const float* pi = sim + ((size_t)img*256 + t)*256;
    int base = (t ^ (t >> 4))*19;
    float4 a0 = *(const float4*)(pr + vA);
    float4 a1 = *(const float4*)(pr + vA + 4);
    float4 c0 = *(const float4*)(pi + vA);
    float4 c1 = *(const float4*)(pi + vA + 4);
    reL[base+0]=a0.x; reL[base+1]=a0.y; reL[base+2]=a0.z; reL[base+3]=a0.w;
    reL[base+4]=a1.x; reL[base+5]=a1.y; reL[base+6]=a1.z; reL[base+7]=a1.w;
    imL[base+0]=c0.x; imL[base+1]=c0.y; imL[base+2]=c0.z; imL[base+3]=c0.w;
    imL[base+4]=c1.x; imL[base+5]=c1.y; imL[base+6]=c1.z; imL[base+7]=c1.w;
    float4 b0 = *(const float4*)(pr + vB);
    float4 b1 = *(const float4*)(pr + vB + 4);
    float4 d0 = *(const float4*)(pi + vB);
    float4 d1 = *(const float4*)(pi + vB + 4);
    reL[base+8]=b0.x;  reL[base+9]=b0.y;  reL[base+10]=b0.z; reL[base+11]=b0.w;
    reL[base+12]=b1.x; reL[base+13]=b1.y; reL[base+14]=b1.z; reL[base+15]=b1.w;
    imL[base+8]=d0.x;  imL[base+9]=d0.y;  imL[base+10]=d0.z; imL[base+11]=d0.w;
    imL[base+12]=d1.x; imL[base+13]=d1.y; imL[base+14]=d1.z; imL[base+15]=d1.w;
    reL[base+16] = pr[v16]; imL[base+16] = pi[v16];
    reL[base+17] = pr[v17]; imL[base+17] = pi[v17];
  }
  __syncthreads();
  for (int s = 0; s < 8; ++s){
    int half = 128 >> s;
    #pragma unroll
    for (int it = 0; it < 9; ++it){
      int idx = t + it*256;          // 0..2303 = 18 cols x 128 butterflies
      int col = idx % 18;
      int tj  = idx / 18;
      int jl = tj & (half-1);
      int g  = tj >> (7-s);
      int k  = (g << (8-s)) + jl;
      int m  = jl << s;
      float wc = twr[m], ws = twi[m];
      int r1 = k + half;
      int p0 = (k  ^ (k  >> 4))*19 + col;
      int p1 = (r1 ^ (r1 >> 4))*19 + col;
      float are = reL[p0], aim = imL[p0];
      float bre = reL[p1], bim = imL[p1];
      reL[p0] = are + bre; imL[p0] = aim + bim;
      float tr = are - bre, ti = aim - bim;
      reL[p1] = tr*wc - ti*ws;
      imL[p1] = tr*ws + ti*wc;
    }
    __syncthreads();
  }
  int b = img >> 6, cimg = img & 63;
  int u = t;
  int bu  = (int)brev8((uint)u);
  int bmu = (int)brev8((uint)((256 - u) & 255));
  int su  = (bu  ^ (bu  >> 4))*19;
  int smu = (bmu ^ (bmu >> 4))*19;
  #pragma unroll
  for (int qi = 0; qi < 4; ++qi){
    int cbase = qi*4;
    int vbase = (qi < 2) ? (vA + qi*4) : (vB + (qi-2)*4);
    ushort av4[4], pv4[4], ai4[4], pi4[4];
    #pragma unroll
    for (int e = 0; e < 4; ++e){
      int c = cbase + e;
      int mc = (c == 0) ? 16 : ((c == 8) ? 17 : (16 - c));
      float re1 = reL[su + c],   im1 = imL[su + c];
      float re2 = reL[smu + mc], im2 = imL[smu + mc];
      float vr = 0.5f*(re1 + re2), vi = 0.5f*(im1 - im2);
      float jr = 0.5f*(im1 + im2), ji = 0.5f*(re2 - re1);
      av4[e] = f2bf(sqrtf(vr*vr + vi*vi));
      pv4[e] = f2bf(atan2f(vi, vr));
      ai4[e] = f2bf(sqrtf(jr*jr + ji*ji));
      pi4[e] = f2bf(atan2f(ji, jr));
    }
    size_t addr = ((size_t)(b*4096 + (u>>2)*64 + (vbase>>2)))*1024
                + cimg*16 + (u&3)*4;
    uint2 w;
    w.x = (uint)av4[0] | ((uint)av4[1]<<16);
    w.y = (uint)av4[2] | ((uint)av4[3]<<16);
    *(uint2*)(AV + addr) = w;
    w.x = (uint)pv4[0] | ((uint)pv4[1]<<16);
    w.y = (uint)pv4[2] | ((uint)pv4[3]<<16);
    *(uint2*)(PV + addr) = w;
    w.x = (uint)ai4[0] | ((uint)ai4[1]<<16);
    w.y = (uint)ai4[2] | ((uint)ai4[3]<<16);
    *(uint2*)(AI + addr) = w;
    w.x = (uint)pi4[0] | ((uint)pi4[1]<<16);
    w.y = (uint)pi4[2] | ((uint)pi4[3]<<16);
    *(uint2*)(PI + addr) = w;
  }
}

// ---------------- inverse row FFT with spec construction (fp32) ----------------
__global__ __launch_bounds__(256) void kern_ifft_rows_spec(const float* __restrict__ famp,
    const float* __restrict__ fph, float* __restrict__ sre, float* __restrict__ sim){
  __shared__ float re[4][256], im[4][256];
  __shared__ float twr[128], twi[128];
  int t = threadIdx.x;
  if (t < 128){
    float a = -6.2831853071795864f * (float)t * (1.f/256.f);
    sincosf(a, &twi[t], &twr[t]);
  }
  int R = blockIdx.x * 4;
  {
    int r = t >> 6, q = t & 63;
    int row = R + r;
    int bc = row >> 8, h = row & 255;
    int b = bc >> 6, c = bc & 63;
    size_t addr = ((size_t)(b*4096 + (h>>2)*64 + q))*1024 + c*16 + (h&3)*4;
    float4 a4 = *(const float4*)(famp + addr);
    float4 p4 = *(const float4*)(fph + addr);
    float sn, cs;
    sincosf(p4.x, &sn, &cs); re[r][4*q+0] = a4.x*cs; im[r][4*q+0] = a4.x*sn;
    sincosf(p4.y, &sn, &cs); re[r][4*q+1] = a4.y*cs; im[r][4*q+1] = a4.y*sn;
    sincosf(p4.z, &sn, &cs); re[r][4*q+2] = a4.z*cs; im[r][4*q+2] = a4.z*sn;
    sincosf(p4.w, &sn, &cs); re[r][4*q+3] = a4.w*cs; im[r][4*q+3] = a4.w*sn;
  }
  __syncthreads();
  for (int s = 0; s < 8; ++s){
    int half = 128 >> s;
    #pragma unroll
    for (int bi0 = 0; bi0 < 2; ++bi0){
      int bi = t + bi0*256;
      int r = bi >> 7, tj = bi & 127;
      int j = tj & (half-1);
      int g = tj >> (7-s);
      int k = (g << (8-s)) + j;
      int m = j << s;
      float wc = twr[m], ws = -twi[m];
      float are = re[r][k],      aim = im[r][k];
      float bre = re[r][k+half], bim = im[r][k+half];
      re[r][k] = are + bre; im[r][k] = aim + bim;
      float tr = are - bre, ti = aim - bim;
      re[r][k+half] = tr*wc - ti*ws;
      im[r][k+half] = tr*ws + ti*wc;
    }
    __syncthreads();
  }
  {
    int r = t >> 6, q = t & 63;
    size_t row = (size_t)R + r;
    float4 vr, vi;
    vr.x = re[r][brev8(4*q+0)]; vi.x = im[r][brev8(4*q+0)];
    vr.y = re[r][brev8(4*q+1)]; vi.y = im[r][brev8(4*q+1)];
    vr.z = re[r][brev8(4*q+2)]; vi.z = im[r][brev8(4*q+2)];
    vr.w = re[r][brev8(4*q+3)]; vi.w = im[r][brev8(4*q+3)];
    *(float4*)(sre + row*256 + 4*q) = vr;
    *(float4*)(sim + row*256 + 4*q) = vi;
  }
}

// ---------------- inverse column FFT (fp32 in -> fp32 spatial out) --------------
__global__ __launch_bounds__(256) void kern_fft_cols_inv(const float* __restrict__ sre,
    const float* __restrict__ sim, float* __restrict__ out0){
  __shared__ float reL[256*17];
  __shared__ float imL[256*17];
  __shared__ float twr[128], twi[128];
  int t = threadIdx.x;
  if (t < 128){
    float a = -6.2831853071795864f * (float)t * (1.f/256.f);
    sincosf(a, &twi[t], &twr[t]);
  }
  int img = blockIdx.x >> 4;
  int c0 = (blockIdx.x & 15) * 16;
  {
    const float* pr = sre + ((size_t)img*256 + t)*256 + c0;
    const float* pi = sim + ((size_t)img*256 + t)*256 + c0;
    #pragma unroll
    for (int p = 0; p < 4; ++p){
      float4 vr = *(const float4*)(pr + 4*p);
      float4 vi = *(const float4*)(pi + 4*p);
      int base = t*17 + 4*p;
      reL[base+0]=vr.x; reL[base+1]=vr.y; reL[base+2]=vr.z; reL[base+3]=vr.w;
      imL[base+0]=vi.x; imL[base+1]=vi.y; imL[base+2]=vi.z; imL[base+3]=vi.w;
    }
  }
  __syncthreads();
  int col = t & 15, tb = t >> 4;
  for (int s = 0; s < 8; ++s){
    int half = 128 >> s;
    #pragma unroll
    for (int it = 0; it < 8; ++it){
      int tj = tb + it*16;
      int j = tj & (half-1);
      int g = tj >> (7-s);
      int k = (g << (8-s)) + j;
      int m = j << s;
      float wc = twr[m];
      float ws = -twi[m];
      int i0 = k*17 + col, i1 = (k+half)*17 + col;
      float are = reL[i0], aim = imL[i0];
      float bre = reL[i1], bim = imL[i1];
      reL[i0] = are + bre; imL[i0] = aim + bim;
      float tr = are - bre, ti = aim - bim;
      reL[i1] = tr*wc - ti*ws;
      imL[i1] = tr*ws + ti*wc;
    }
    __syncthreads();
  }
  int h = t; int src = (int)brev8((uint)h);
  float* op = out0 + ((size_t)img*256 + h)*256 + c0;
  #pragma unroll
  for (int p = 0; p < 4; ++p){
    int base = src*17 + 4*p;
    float4 v;
    v.x = reL[base+0]*(1.f/65536.f);
    v.y = reL[base+1]*(1.f/65536.f);
    v.z = reL[base+2]*(1.f/65536.f);
    v.w = reL[base+3]*(1.f/65536.f);
    *(float4*)(op + 4*p) = v;
  }
}

// ---------------- transpose-convert: fp32 [K][N] -> bf16 [N][K], 10 mats ----------
struct TRS {
  const float* src[10];
  ushort* dst[10];
  int K[10], N[10];
  int start[11];
};
__global__ __launch_bounds__(256) void kern_tr(TRS p){
  __shared__ float lds[32][33];
  int bid = blockIdx.x;
  int e = 0;
  while (bid >= p.start[e+1]) ++e;
  int tloc = bid - p.start[e];
  int tilesN = p.N[e] >> 5;
  int tn = tloc % tilesN, tk = tloc / tilesN;
  int k0 = tk << 5, n0 = tn << 5;
  const float* src = p.src[e];
  ushort* dst = p.dst[e];
  int K = p.K[e], N = p.N[e];
  int r = threadIdx.x >> 5, c = threadIdx.x & 31;
  #pragma unroll
  for (int i = 0; i < 4; ++i)
    lds[r + 8*i][c] = src[(size_t)(k0 + r + 8*i)*N + n0 + c];
  __syncthreads();
  #pragma unroll
  for (int i = 0; i < 4; ++i)
    dst[(size_t)(n0 + r + 8*i)*K + k0 + c] = f2bf(lds[c][r + 8*i]);
}

// ---------------- mgemm2: BM=64 BN=128 BK=64, bf16 A + bf16 B^T (qkv gather) -----
struct GP2 {
  const ushort* A0[6];
  const ushort* Bt[6];
  float* Cm[6];
  const int* idxp[6];
  int N, K;
};

__global__ __launch_bounds__(256) void kern_mgemm2(GP2 p){
  __shared__ __align__(16) ushort Asb[64*64];
  __shared__ __align__(16) ushort Bsb[128*64];
  __shared__ int idx_s[64];
  int z = blockIdx.z;
  const ushort* A0 = p.A0[z];
  const ushort* Bt = p.Bt[z];
  float* Cm = p.Cm[z];
  int tid = threadIdx.x;
  int m0 = blockIdx.x * 64;
  int n0 = blockIdx.y * 128;
  int lane = tid & 63, w = tid >> 6;
  int wr = w & 1, wc = w >> 1;
  int lr = lane & 15, ql = lane >> 4;

  if (tid < 64){
    int m = m0 + tid;
    idx_s[tid] = p.idxp[z][(m >> 10)*1024 + (m & 1023)];
  }
  __syncthreads();
  int gb = m0 >> 10;

  f32x4 acc[2][4];
  #pragma unroll
  for (int i = 0; i < 2; ++i)
    #pragma unroll
    for (int j = 0; j < 4; ++j) acc[i][j] = (f32x4){0.f,0.f,0.f,0.f};

  int kh = tid & 7;
  int rA = tid >> 3;
  for (int k0 = 0; k0 < p.K; k0 += 64){
    #pragma unroll
    for (int s = 0; s < 2; ++s){
      int m = rA + 32*s;
      const ushort* ap = A0 + ((size_t)(gb << 12) + idx_s[m])*(size_t)p.K + k0 + kh*8;
      short8 v = *(const short8*)ap;
      int byte = m*128 + ((kh*16) ^ ((m & 7)*16));
      *(short8*)((char*)Asb + byte) = v;
    }
    #pragma unroll
    for (int s = 0; s < 4; ++s){
      int n = rA + 32*s;
      short8 v = *(const short8*)(Bt + (size_t)(n0+n)*p.K + k0 + kh*8);
      int byte = n*128 + ((kh*16) ^ ((n & 7)*16));
      *(short8*)((char*)Bsb + byte) = v;
    }
    __syncthreads();
    short8 af[2][2], bf[4][2];
    #pragma unroll
    for (int fm = 0; fm < 2; ++fm){
      int row = wr*32 + fm*16 + lr;
      #pragma unroll
      for (int kq = 0; kq < 2; ++kq){
        int byte = row*128 + ((kq*64 + ql*16) ^ ((row & 7)*16));
        af[fm][kq] = *(const short8*)((const char*)Asb + byte);
      }
    }
    #pragma unroll
    for (int fn = 0; fn < 4; ++fn){
      int row = wc*64 + fn*16 + lr;
      #pragma unroll
      for (int kq = 0; kq < 2; ++kq){
        int byte = row*128 + ((kq*64 + ql*16) ^ ((row & 7)*16));
        bf[fn][kq] = *(const short8*)((const char*)Bsb + byte);
      }
    }
    #pragma unroll
    for (int kq = 0; kq < 2; ++kq)
      #pragma unroll
      for (int fm = 0; fm < 2; ++fm)
        #pragma unroll
        for (int fn = 0; fn < 4; ++fn)
          acc[fm][fn] = __builtin_amdgcn_mfma_f32_16x16x32_bf16(af[fm][kq], bf[fn][kq],
                                                                acc[fm][fn], 0, 0, 0);
    __syncthreads();
  }

  #pragma unroll
  for (int fm = 0; fm < 2; ++fm){
    #pragma unroll
    for (int fn = 0; fn < 4; ++fn){
      int n = n0 + wc*64 + fn*16 + lr;
      #pragma unroll
      for (int reg = 0; reg < 4; ++reg){
        int m = m0 + wr*32 + fm*16 + ql*4 + reg;
        Cm[(size_t)m*p.N + n] = acc[fm][fn][reg];
      }
    }
  }
}

// ---------------- hscore: h-GEMM (N=128) + fused gelu@Wout score reduction --------
struct HSP {
  const ushort* A0[2];
  const ushort* A1[2];
  const ushort* Bt[2];
  float* score;
  const float* ep0[2];
  const float* ep1[2];
  const float* ep2[2];
  const float* wout;
  const float* bout;
  int Mper;
};

__global__ __launch_bounds__(256) void kern_hscore(HSP p){
  __shared__ __align__(16) ushort Asb[128*64];
  __shared__ __align__(16) ushort Bsb[128*64];
  __shared__ float part[2][128];
  int z = blockIdx.z;
  const ushort* Bt = p.Bt[z];
  int tid = threadIdx.x;
  int m0 = blockIdx.x * 128;
  int lane = tid & 63, w = tid >> 6;
  int wr = w & 1, wc = w >> 1;
  int lr = lane & 15, ql = lane >> 4;

  f32x4 acc[4][4];
  #pragma unroll
  for (int i = 0; i < 4; ++i)
    #pragma unroll
    for (int j = 0; j < 4; ++j) acc[i][j] = (f32x4){0.f,0.f,0.f,0.f};

  int kh = tid & 7;
  int rA = tid >> 3;
  for (int k0 = 0; k0 < 2048; k0 += 64){
    const ushort* Asrc = (k0 < 1024) ? p.A0[z] : p.A1[z];
    int kk = (k0 & 1023) + kh*8;
    #pragma unroll
    for (int s = 0; s < 4; ++s){
      int m = rA + 32*s;
      short8 v = *(const short8*)(Asrc + (size_t)(m0+m)*1024 + kk);
      int byte = m*128 + ((kh*16) ^ ((m & 7)*16));
      *(short8*)((char*)Asb + byte) = v;
    }
    #pragma unroll
    for (int s = 0; s < 4; ++s){
      int n = rA + 32*s;
      short8 v = *(const short8*)(Bt + (size_t)n*2048 + k0 + kh*8);
      int byte = n*128 + ((kh*16) ^ ((n & 7)*16));
      *(short8*)((char*)Bsb + byte) = v;
    }
    __syncthreads();
    short8 af[4][2], bf[4][2];
    #pragma unroll
    for (int fm = 0; fm < 4; ++fm){
      int row = wr*64 + fm*16 + lr;
      #pragma unroll
      for (int kq = 0; kq < 2; ++kq){
        int byte = row*128 + ((kq*64 + ql*16) ^ ((row & 7)*16));
        af[fm][kq] = *(const short8*)((const char*)Asb + byte);
      }
    }
    #pragma unroll
    for (int fn = 0; fn < 4; ++fn){
      int row = wc*64 + fn*16 + lr;
      #pragma unroll
      for (int kq = 0; kq < 2; ++kq){
        int byte = row*128 + ((kq*64 + ql*16) ^ ((row & 7)*16));
        bf[fn][kq] = *(const short8*)((const char*)Bsb + byte);
      }
    }
    #pragma unroll
    for (int kq = 0; kq < 2; ++kq)
      #pragma unroll
      for (int fm = 0; fm < 4; ++fm)
        #pragma unroll
        for (int fn = 0; fn < 4; ++fn)
          acc[fm][fn] = __builtin_amdgcn_mfma_f32_16x16x32_bf16(af[fm][kq], bf[fn][kq],
                                                                acc[fm][fn], 0, 0, 0);
    __syncthreads();
  }

  float wv[4];
  #pragma unroll
  for (int fn = 0; fn < 4; ++fn) wv[fn] = p.wout[z*128 + wc*64 + fn*16 + lr];
  #pragma unroll
  for (int fm = 0; fm < 4; ++fm){
    #pragma unroll
    for (int reg = 0; reg < 4; ++reg){
      int m = m0 + wr*64 + fm*16 + ql*4 + reg;
      int bl = m >> 12, g = m & 4095;
      int gy = g >> 6, gx = g & 63;
      float cy = ((float)gy + 0.5f)*(1.f/64.f);
      float cx = ((float)gx + 0.5f)*(1.f/64.f);
      float ps = 0.f;
      #pragma unroll
      for (int fn = 0; fn < 4; ++fn){
        int n = wc*64 + fn*16 + lr;
        float o = acc[fm][fn][reg] + p.ep0[z][bl*128 + n] + cy*p.ep1[z][n]
                + cx*p.ep1[z][128 + n] + p.ep2[z][n];
        ps += geluf(o)*wv[fn];
      }
      #pragma unroll
      for (int off = 8; off > 0; off >>= 1) ps += __shfl_xor(ps, off);
      if (lr == 0) part[wc][wr*64 + fm*16 + ql*4 + reg] = ps;
    }
  }
  __syncthreads();
  if (tid < 128)
    p.score[(size_t)z*p.Mper + m0 + tid] = part[0][tid] + part[1][tid] + p.bout[z];
}

// ---------------- byp: gather bypass blend over 3072 non-selected rows -----------
struct BYP {
  const ushort* A0[2];
  const ushort* A1[2];
  const ushort* Bt[2];
  float* Cm[2];
  const int* nsel[2];
  const float* bias[2];
  const ushort* vt[2];
  const ushort* it[2];
};

__global__ __launch_bounds__(256) void kern_byp(BYP p){
  __shared__ __align__(16) ushort Asb[128*64];
  __shared__ __align__(16) ushort Bsb[128*64];
  __shared__ int idx_s[128];
  int z = blockIdx.z;
  const ushort* Bt = p.Bt[z];
  int tid = threadIdx.x;
  int gb  = blockIdx.x / 24;
  int m0l = (blockIdx.x % 24) * 128;
  int n0 = blockIdx.y * 128;
  int lane = tid & 63, w = tid >> 6;
  int wr = w & 1, wc = w >> 1;
  int lr = lane & 15, ql = lane >> 4;

  if (tid < 128)
    idx_s[tid] = p.nsel[z][(size_t)gb*3072 + m0l + tid];
  __syncthreads();

  f32x4 acc[4][4];
  #pragma unroll
  for (int i = 0; i < 4; ++i)
    #pragma unroll
    for (int j = 0; j < 4; ++j) acc[i][j] = (f32x4){0.f,0.f,0.f,0.f};

  int kh = tid & 7;
  int rA = tid >> 3;
  for (int k0 = 0; k0 < 2048; k0 += 64){
    const ushort* Asrc = (k0 < 1024) ? p.A0[z] : p.A1[z];
    int kk = (k0 & 1023) + kh*8;
    #pragma unroll
    for (int s = 0; s < 4; ++s){
      int m = rA + 32*s;
      size_t grow = (size_t)(gb << 12) + idx_s[m];
      short8 v = *(const short8*)(Asrc + grow*1024 + kk);
      int byte = m*128 + ((kh*16) ^ ((m & 7)*16));
      *(short8*)((char*)Asb + byte) = v;
    }
    #pragma unroll
    for (int s = 0; s < 4; ++s){
      int n = rA + 32*s;
      short8 v = *(const short8*)(Bt + (size_t)(n0+n)*2048 + k0 + kh*8);
      int byte = n*128 + ((kh*16) ^ ((n & 7)*16));
      *(short8*)((char*)Bsb + byte) = v;
    }
    __syncthreads();
    short8 af[4][2], bf[4][2];
    #pragma unroll
    for (int fm = 0; fm < 4; ++fm){
      int row = wr*64 + fm*16 + lr;
      #pragma unroll
      for (int kq = 0; kq < 2; ++kq){
        int byte = row*128 + ((kq*64 + ql*16) ^ ((row & 7)*16));
        af[fm][kq] = *(const short8*)((const char*)Asb + byte);
      }
    }
    #pragma unroll
    for (int fn = 0; fn < 4; ++fn){
      int row = wc*64 + fn*16 + lr;
      #pragma unroll
      for (int kq = 0; kq < 2; ++kq){
        int byte = row*128 + ((kq*64 + ql*16) ^ ((row & 7)*16));
        bf[fn][kq] = *(const short8*)((const char*)Bsb + byte);
      }
    }
    #pragma unroll
    for (int kq = 0; kq < 2; ++kq)
      #pragma unroll
      for (int fm = 0; fm < 4; ++fm)
        #pragma unroll
        for (int fn = 0; fn < 4; ++fn)
          acc[fm][fn] = __builtin_amdgcn_mfma_f32_16x16x32_bf16(af[fm][kq], bf[fn][kq],
                                                                acc[fm][fn], 0, 0, 0);
    __syncthreads();
  }

  float* Cm = p.Cm[z];
  const ushort* vtp = p.vt[z];
  const ushort* itp = p.it[z];
  #pragma unroll
  for (int fm = 0; fm < 4; ++fm){
    #pragma unroll
    for (int fn = 0; fn < 4; ++fn){
      int n = n0 + wc*64 + fn*16 + lr;
      float bia = p.bias[z][n];
      #pragma unroll
      for (int reg = 0; reg < 4; ++reg){
        int mloc = wr*64 + fm*16 + ql*4 + reg;
        size_t off = ((size_t)(gb << 12) + idx_s[mloc])*1024 + n;
        float vt = bf2f(vtp[off]);
        float it = bf2f(itp[off]);
        float gg = 1.f/(1.f + expf(-(acc[fm][fn][reg] + bia)));
        Cm[off] = gg*vt + (1.f-gg)*it;
      }
    }
  }
}

// ---------------- scatter GEMM: fused_sel = vs(bf16) + o@Wo, K=128 ----------------
struct SCP {
  const float* A0[2];
  const float* Bm[2];
  float* Cm[2];
  const int* idxp[2];
  const ushort* vtb[2];
};

__global__ __launch_bounds__(256) void kern_scat(SCP p){
  __shared__ __align__(16) ushort Asb[64*40];
  __shared__ __align__(16) ushort Bsb[128*40];
  __shared__ int idx_s[64];
  int z = blockIdx.z;
  const float* A0 = p.A0[z];
  const float* Bm = p.Bm[z];
  float* Cm = p.Cm[z];
  int tid = threadIdx.x;
  int m0 = blockIdx.y * 64;
  int n0 = blockIdx.x * 128;
  int lane = tid & 63, w = tid >> 6;
  int wr = w & 1, wc = w >> 1;
  int lr = lane & 15, ql = lane >> 4;
  if (tid < 64){
    int m = m0 + tid;
    idx_s[tid] = p.idxp[z][(m >> 10)*1024 + (m & 1023)];
  }
  __syncthreads();
  int gb = m0 >> 10;

  f32x4 acc[2][4];
  #pragma unroll
  for (int i = 0; i < 2; ++i)
    #pragma unroll
    for (int j = 0; j < 4; ++j) acc[i][j] = (f32x4){0.f,0.f,0.f,0.f};

  for (int k0 = 0; k0 < 128; k0 += 32){
    {
      int m = tid & 63;
      int khh = (tid >> 6) * 8;
      const float* ap = A0 + (size_t)(m0+m)*128 + k0 + khh;
      float4 f0 = *(const float4*)ap;
      float4 f1 = *(const float4*)(ap + 4);
      short8 v;
      v[0]=(short)f2bf(f0.x); v[1]=(short)f2bf(f0.y);
      v[2]=(short)f2bf(f0.z); v[3]=(short)f2bf(f0.w);
      v[4]=(short)f2bf(f1.x); v[5]=(short)f2bf(f1.y);
      v[6]=(short)f2bf(f1.z); v[7]=(short)f2bf(f1.w);
      *(short8*)&Asb[m*40 + khh] = v;
    }
    #pragma unroll
    for (int e0 = 0; e0 < 512; e0 += 256){
      int e = e0 + tid;
      int n = e & 127;
      int khh = (e >> 7) * 8;
      const float* bp = Bm + (size_t)(k0+khh)*1024 + n0 + n;
      short8 v;
      #pragma unroll
      for (int j = 0; j < 8; ++j) v[j] = (short)f2bf(bp[(size_t)j*1024]);
      *(short8*)&Bsb[n*40 + khh] = v;
    }
    __syncthreads();
    short8 af[2], bf[4];
    #pragma unroll
    for (int fr = 0; fr < 2; ++fr)
      af[fr] = *(const short8*)&Asb[(wr*32 + fr*16 + lr)*40 + ql*8];
    #pragma unroll
    for (int fc = 0; fc < 4; ++fc)
      bf[fc] = *(const short8*)&Bsb[(wc*64 + fc*16 + lr)*40 + ql*8];
    #pragma unroll
    for (int fr = 0; fr < 2; ++fr)
      #pragma unroll
      for (int fc = 0; fc < 4; ++fc)
        acc[fr][fc] = __builtin_amdgcn_mfma_f32_16x16x32_bf16(af[fr], bf[fc],
                                                              acc[fr][fc], 0, 0, 0);
    __syncthreads();
  }

  #pragma unroll
  for (int fr = 0; fr < 2; ++fr){
    #pragma unroll
    for (int fc = 0; fc < 4; ++fc){
      int n = n0 + wc*64 + fc*16 + lr;
      #pragma unroll
      for (int reg = 0; reg < 4; ++reg){
        int mloc = wr*32 + fr*16 + ql*4 + reg;
        int gt = idx_s[mloc];
        size_t off = ((size_t)(gb << 12) + gt)*1024 + n;
        Cm[off] = acc[fr][fc][reg] + bf2f(p.vtb[z][off]);
      }
    }
  }
}

// ---------------- top-1024 of 4096 + complement (bitonic, jax tie-break) ----------
__global__ __launch_bounds__(1024) void kern_topk(const float* __restrict__ score,
    int* __restrict__ idx_out, int* __restrict__ nsel_out){
  __shared__ u64 keys[4096];
  int b = blockIdx.x, t = threadIdx.x;
  for (int i = t; i < 4096; i += 1024){
    float s = score[b*4096 + i];
    uint u = __float_as_uint(s);
    uint msk = (u & 0x80000000u) ? ~u : (u | 0x80000000u);
    keys[i] = ((u64)msk << 32) | (uint)(4095 - i);
  }
  __syncthreads();
  for (int k = 2; k <= 4096; k <<= 1){
    for (int j = k >> 1; j > 0; j >>= 1){
      for (int i = t; i < 4096; i += 1024){
        int l = i ^ j;
        if (l > i){
          u64 a = keys[i], c = keys[l];
          bool descB = ((i & k) == 0);
          bool sw = descB ? (a < c) : (a > c);
          if (sw){ keys[i] = c; keys[l] = a; }
        }
      }
      __syncthreads();
    }
  }
  idx_out[b*1024 + t] = 4095 - (int)(keys[t] & 0xFFFFFFFFu);
  for (int i = t; i < 3072; i += 1024)
    nsel_out[(size_t)b*3072 + i] = 4095 - (int)(keys[1024 + i] & 0xFFFFFFFFu);
}

// ---------------- attention partials (k-split flash, 128-thr q-split) ----------
__global__ __launch_bounds__(128) void kern_attn_part(const float* __restrict__ qb,
    const float* __restrict__ kb, const float* __restrict__ vb,
    float* __restrict__ paoa, float* __restrict__ pml){
  __shared__ float Ks[64][32];
  __shared__ float Vs[64][32];
  int t = threadIdx.x;
  int hh = blockIdx.y;
  int zc = blockIdx.z;
  int zf = zc >> 2, c = zc & 3;
  size_t boff = (size_t)zf*131072;
  int jq = blockIdx.x*128 + t;
  float qv[32];
  {
    const float4* qp = (const float4*)(qb + boff + (size_t)jq*128 + hh*32);
    #pragma unroll
    for (int d = 0; d < 8; ++d) ((float4*)qv)[d] = qp[d];
  }
  float mrun = -3.0e38f, lrun = 0.f;
  float oa[32];
  #pragma unroll
  for (int d = 0; d < 32; ++d) oa[d] = 0.f;
  for (int kt = 0; kt < 4; ++kt){
    int k0 = c*256 + kt*64;
    #pragma unroll
    for (int rep = 0; rep < 4; ++rep){
      int f = t + rep*128;
      int r = f >> 3, q4 = f & 7;
      size_t base = boff + (size_t)(k0 + r)*128 + hh*32 + 4*q4;
      *(float4*)&Ks[r][4*q4] = *(const float4*)(kb + base);
      *(float4*)&Vs[r][4*q4] = *(const float4*)(vb + base);
    }
    __syncthreads();
    #pragma unroll
    for (int st = 0; st < 4; ++st){
      float s[16];
      #pragma unroll
      for (int j = 0; j < 16; ++j){
        float v = 0.f;
        #pragma unroll
        for (int d = 0; d < 32; ++d) v += qv[d]*Ks[st*16+j][d];
        s[j] = v * 0.17677669529663687f;
      }
      float mt = s[0];
      #pragma unroll
      for (int j = 1; j < 16; ++j) mt = fmaxf(mt, s[j]);
      float mnew = fmaxf(mrun, mt);
      float alpha = expf(mrun - mnew);
      lrun *= alpha;
      #pragma unroll
      for (int d = 0; d < 32; ++d) oa[d] *= alpha;
      #pragma unroll
      for (int j = 0; j < 16; ++j){
        float pe = expf(s[j] - mnew);
        lrun += pe;
        #pragma unroll
        for (int d = 0; d < 32; ++d) oa[d] += pe*Vs[st*16+j][d];
      }
      mrun = mnew;
    }
    __syncthreads();
  }
  size_t rec = (((size_t)zf*4 + hh)*4 + c)*1024 + jq;
  float* pp = paoa + rec*32;
  #pragma unroll
  for (int d = 0; d < 8; ++d) ((float4*)pp)[d] = ((float4*)oa)[d];
  pml[rec*2]   = mrun;
  pml[rec*2+1] = lrun;
}

// ---------------- attention combine ----------------
__global__ __launch_bounds__(256) void kern_attn_comb(const float* __restrict__ paoa,
    const float* __restrict__ pml, float* __restrict__ ob,
    const float* __restrict__ ipint, int PB, int b0){
  int t = threadIdx.x;
  int hh = blockIdx.y, zf = blockIdx.z;
  int jq = blockIdx.x*256 + t;
  size_t rbase = (((size_t)zf*4 + hh)*4)*1024 + jq;
  float mc[4], lc[4];
  #pragma unroll
  for (int c = 0; c < 4; ++c){
    mc[c] = pml[(rbase + c*1024)*2];
    lc[c] = pml[(rbase + c*1024)*2 + 1];
  }
  float M = fmaxf(fmaxf(mc[0], mc[1]), fmaxf(mc[2], mc[3]));
  float wgt[4], L = 0.f;
  #pragma unroll
  for (int c = 0; c < 4; ++c){ wgt[c] = expf(mc[c] - M); L += lc[c]*wgt[c]; }
  float inv = 1.f/L;
  int br = (zf >= PB) ? 1 : 0;
  int bb = zf - br*PB;
  const float* ip = ipint + br*512 + (b0+bb)*128 + hh*32;
  float* op = ob + (size_t)zf*131072 + (size_t)jq*128 + hh*32;
  #pragma unroll
  for (int d = 0; d < 32; ++d){
    float o = 0.f;
    #pragma unroll
    for (int c = 0; c < 4; ++c) o += paoa[(rbase + c*1024)*32 + d]*wgt[c];
    op[d] = o*inv + ip[d];
  }
}

// ---------------- conv weight transform ----------------
__global__ __launch_bounds__(256) void kern_wt(const float* __restrict__ w1,
    const float* __restrict__ w2, ushort* __restrict__ wt){
  int blk = blockIdx.x;
  const float* src = (blk < 9) ? w1 : w2;
  int tap = blk - (blk < 9 ? 0 : 9);
  ushort* dst = wt + (blk < 9 ? 0 : 36864) + tap*4096;
  for (int e = threadIdx.x; e < 4096; e += 256){
    dst[e] = f2bf(src[(size_t)e*9 + tap]);
  }
}

// ---------------- implicit-GEMM 3x3 conv via MFMA ----------------
template<int MODE>
__global__ __launch_bounds__(256) void kern_cmfma(const float* __restrict__ in,
    const ushort* __restrict__ wt, const float* __restrict__ bias,
    float* __restrict__ out,
    const float* __restrict__ modg, const float* __restrict__ modb,
    const float* __restrict__ vis, const float* __restrict__ irf){
  __shared__ __align__(16) ushort ins[64][268];
  int t = threadIdx.x;
  int y = blockIdx.x, b = blockIdx.y;
  int lane = t & 63, w = t >> 6;
  int wc = w & 1, wx = w >> 1;
  int lr = lane & 15, ql = lane >> 4;

  f32x4 acc[2][8];
  #pragma unroll
  for (int f = 0; f < 2; ++f)
    #pragma unroll
    for (int xf = 0; xf < 8; ++xf) acc[f][xf] = (f32x4){0.f,0.f,0.f,0.f};

  for (int dy = 0; dy < 3; ++dy){
    int yy = y + dy - 1;
    if (yy < 0 || yy > 255) continue;
    const float* src = in + ((size_t)(b*64)*256 + yy)*256;
    #pragma unroll
    for (int s = 0; s < 16; ++s){
      int e = t + s*256;
      int ci = e >> 6, q = e & 63;
      float4 f4 = *(const float4*)(src + (size_t)ci*65536 + 4*q);
      uint lo = (uint)f2bf(f4.x) | ((uint)f2bf(f4.y) << 16);
      uint hi = (uint)f2bf(f4.z) | ((uint)f2bf(f4.w) << 16);
      *(uint2*)&ins[ci][4*q + 4] = make_uint2(lo, hi);
    }
    if (t < 128){
      int r = t & 63;
      ins[r][(t >> 6) ? 260 : 3] = 0;
    }
    __syncthreads();
    short8 wf[2][3][2];
    #pragma unroll
    for (int kk = 0; kk < 2; ++kk)
      #pragma unroll
      for (int dx = 0; dx < 3; ++dx)
        #pragma unroll
        for (int f = 0; f < 2; ++f)
          wf[kk][dx][f] = *(const short8*)(wt +
            (size_t)((dy*3 + dx)*64 + 32*wc + 16*f + lr)*64 + kk*32 + ql*8);
    #pragma unroll
    for (int kk = 0; kk < 2; ++kk){
      const ushort* bp = &ins[kk*32 + ql*8][0];
      #pragma unroll
      for (int dx = 0; dx < 3; ++dx){
        int xb = 128*wx + lr + dx + 3;
        #pragma unroll
        for (int xf = 0; xf < 8; ++xf){
          int xi = xb + 16*xf;
          short8 bf;
          #pragma unroll
          for (int e = 0; e < 8; ++e) bf[e] = (short)bp[e*268 + xi];
          acc[0][xf] = __builtin_amdgcn_mfma_f32_16x16x32_bf16(wf[kk][dx][0], bf,
                                                               acc[0][xf], 0, 0, 0);
          acc[1][xf] = __builtin_amdgcn_mfma_f32_16x16x32_bf16(wf[kk][dx][1], bf,
                                                               acc[1][xf], 0, 0, 0);
        }
      }
    }
    __syncthreads();
  }

  #pragma unroll
  for (int f = 0; f < 2; ++f){
    #pragma unroll
    for (int xf = 0; xf < 8; ++xf){
      int x = 128*wx + 16*xf + lr;
      #pragma unroll
      for (int reg = 0; reg < 4; ++reg){
        int co = 32*wc + 16*f + ql*4 + reg;
        float v = acc[f][xf][reg] + bias[co];
        size_t oi = ((size_t)(b*64 + co)*256 + y)*256 + x;
        if (MODE == 1){
          out[oi] = fmaxf(v, 0.f);
        } else {
          out[oi] = v*modg[b*64+co] + modb[b*64+co] + 0.5f*(vis[oi] + irf[oi]);
        }
      }
    }
  }
}

// ---------------- launch ----------------
extern "C" void kernel_launch(void* const* d_in, const int* in_sizes, int n_in,
                              void* d_out, int out_size, void* d_ws, size_t ws_size,
                              hipStream_t stream){
  (void)in_sizes; (void)n_in; (void)out_size;
  const float* vis  = (const float*)d_in[0];
  const float* irf  = (const float*)d_in[1];
  const float* bank = (const float*)d_in[2];
  const float* Wr   = (const float*)d_in[3];
  const float* br   = (const float*)d_in[4];
  const float* Wtok = (const float*)d_in[5];
  const float* Wpri = (const float*)d_in[6];
  const float* Wco  = (const float*)d_in[7];
  const float* bs   = (const float*)d_in[8];
  const float* Wout = (const float*)d_in[9];
  const float* bout = (const float*)d_in[10];
  const float* Wq   = (const float*)d_in[11];
  const float* Wk   = (const float*)d_in[12];
  const float* Wv   = (const float*)d_in[13];
  const float* Wo   = (const float*)d_in[14];
  const float* Wint = (const float*)d_in[15];
  const float* Wbyp = (const float*)d_in[16];
  const float* bbyp = (const float*)d_in[17];
  const float* c1w  = (const float*)d_in[18];
  const float* c1b  = (const float*)d_in[19];
  const float* c2w  = (const float*)d_in[20];
  const float* c2b  = (const float*)d_in[21];
  const float* Wa1  = (const float*)d_in[22];
  const float* ba1  = (const float*)d_in[23];
  const float* Wa2  = (const float*)d_in[24];
  const float* ba2  = (const float*)d_in[25];

  auto needB = [](int PB)->size_t{
    return ((size_t)PB*14755840 + 2792448) * 4;
  };
  const int PB = (ws_size >= needB(4)) ? 4 : (ws_size >= needB(2)) ? 2 : 1;

  float* ws = (float*)d_ws;
  const size_t PLF = (size_t)PB*4194304;
  float* PH4 = ws;                                 // fwd im transient + FULL_ph (fp32)
  ushort* ABV = (ushort*)(ws + PLF);               // 4 bf16 planes = 2*PLF floats
  ushort* PBV = ABV + PLF;
  ushort* ABI = PBV + PLF;
  ushort* PBI = ABI + PLF;
  float* S0 = ws + PLF;                            // iFFT fp32 transients alias bf16 region
  float* S1 = S0 + PLF;
  float* sm = ws + 3*PLF;
  float* hbuf  = sm; sm += (size_t)2*PB*524288;    // nsel + paoa alias here
  float* qbuf  = sm; sm += (size_t)2*PB*131072;
  float* kbuf  = sm; sm += (size_t)2*PB*131072;
  float* vbuf  = sm; sm += (size_t)2*PB*131072;
  float* obuf  = sm; sm += (size_t)2*PB*131072;
  float* score = sm; sm += (size_t)2*PB*4096;
  int*   idxb  = (int*)sm; sm += (size_t)2*PB*1024;
  float* pml   = sm; sm += (size_t)PB*65536;
  ushort* BTtok = (ushort*)sm;                     // [2][128][2048]
  ushort* BTbyp = BTtok + 524288;                  // [2][1024][2048]
  ushort* BTq   = BTbyp + 4194304;                 // [2][128][1024]
  ushort* BTk   = BTq + 262144;
  ushort* BTv   = BTk + 262144;
  sm += 2752512;
  float* pooled= sm; sm += 512;
  float* IP    = sm; sm += 1024;
  float* IPint = sm; sm += 1024;
  float* modg  = sm; sm += 256;
  float* modb  = sm; sm += 256;
  ushort* wtb = (ushort*)sm; sm += 36864;
  int*   nselb = (int*)hbuf;                       // [2PB][3072] (dead before paoa)
  float* paoa  = hbuf;

  kern_pool <<<512, 256, 0, stream>>>(vis, irf, pooled);
  kern_small<<<1, 256, 0, stream>>>(pooled, Wr, br, bank, Wpri, Wint,
                                    Wa1, ba1, Wa2, ba2, IP, IPint, modg, modb);
  kern_wt   <<<18, 256, 0, stream>>>(c1w, c2w, wtb);
  {
    TRS tr{};
    const float* srcs[10] = {Wtok, Wtok+262144, Wbyp, Wbyp+2097152,
                             Wq, Wq+131072, Wk, Wk+131072, Wv, Wv+131072};
    ushort* dsts[10] = {BTtok, BTtok+262144, BTbyp, BTbyp+2097152,
                        BTq, BTq+131072, BTk, BTk+131072, BTv, BTv+131072};
    int Ks[10] = {2048,2048,2048,2048,1024,1024,1024,1024,1024,1024};
    int Ns[10] = {128,128,1024,1024,128,128,128,128,128,128};
    int tiles[10] = {256,256,2048,2048,128,128,128,128,128,128};
    int acc0 = 0;
    for (int i = 0; i < 10; ++i){
      tr.src[i] = srcs[i]; tr.dst[i] = dsts[i];
      tr.K[i] = Ks[i]; tr.N[i] = Ns[i];
      tr.start[i] = acc0; acc0 += tiles[i];
    }
    tr.start[10] = acc0;
    kern_tr<<<acc0, 256, 0, stream>>>(tr);
  }

  for (int b0 = 0; b0 < 4; b0 += PB){
    const float* vis_b = vis + (size_t)b0*4194304;
    const float* ir_b  = irf + (size_t)b0*4194304;
    float* OUT = (float*)d_out + (size_t)b0*4194304;

    // packed forward FFT2: Z = FFT2(vis + i*ir), unpack -> 4 bf16 amp/ph planes
    kern_fft_rows_pack<<<PB*8192, 256, 0, stream>>>(vis_b, ir_b, OUT, PH4);
    kern_fft_cols_pack<<<PB*1024, 256, 0, stream>>>(OUT, PH4, ABV, PBV, ABI, PBI);

    {  // h-GEMM with fused score (h never stored)
      HSP p{};
      p.A0[0]=ABV; p.A1[0]=ABI; p.A0[1]=PBV; p.A1[1]=PBI;
      for (int z = 0; z < 2; ++z){
        p.Bt[z] = BTtok + (size_t)z*262144;
        p.ep0[z] = IP + z*512 + b0*128;
        p.ep1[z] = Wco + z*256;
        p.ep2[z] = bs + z*128;
      }
      p.score = score; p.wout = Wout; p.bout = bout;
      p.Mper = PB*4096;
      kern_hscore<<<dim3(PB*32, 1, 2), 256, 0, stream>>>(p);
    }
    kern_topk<<<2*PB, 1024, 0, stream>>>(score, idxb, nselb);
    {  // bypass blend over 3072 non-selected rows per (branch,batch)
      BYP p{};
      p.A0[0]=ABV; p.A1[0]=ABI; p.A0[1]=PBV; p.A1[1]=PBI;
      p.vt[0]=ABV; p.it[0]=ABI; p.vt[1]=PBV; p.it[1]=PBI;
      p.Cm[0]=OUT; p.Cm[1]=PH4;
      for (int z = 0; z < 2; ++z){
        p.Bt[z] = BTbyp + (size_t)z*2097152;
        p.bias[z] = bbyp + z*1024;
        p.nsel[z] = nselb + (size_t)z*PB*3072;
      }
      kern_byp<<<dim3(PB*24, 8, 2), 256, 0, stream>>>(p);
    }
    {  // q,k,v gathered rows
      GP2 p{};
      const ushort* Aplanes[6] = {ABV, ABI, ABI, PBV, PBI, PBI};
      const ushort* Bmats[6] = {BTq, BTk, BTv, BTq+131072, BTk+131072, BTv+131072};
      float* Cms[6] = {qbuf, kbuf, vbuf,
                       qbuf+(size_t)PB*131072, kbuf+(size_t)PB*131072,
                       vbuf+(size_t)PB*131072};
      for (int z = 0; z < 6; ++z){
        p.A0[z] = Aplanes[z]; p.Bt[z] = Bmats[z]; p.Cm[z] = Cms[z];
        p.idxp[z] = idxb + (z < 3 ? 0 : PB*1024);
      }
      p.N = 128; p.K = 1024;
      kern_mgemm2<<<dim3(PB*16, 1, 6), 256, 0, stream>>>(p);
    }
    // k-split flash attention (nsel dead -> paoa aliases hbuf)
    kern_attn_part<<<dim3(8, 4, 2*PB*4), 128, 0, stream>>>(qbuf, kbuf, vbuf,
                                                           paoa, pml);
    kern_attn_comb<<<dim3(4, 4, 2*PB), 256, 0, stream>>>(paoa, pml, obuf,
                                                         IPint, PB, b0);
    {  // fused_sel = vs(bf16) + o@Wo, scatter into FULL (selected rows)
      SCP p{};
      p.A0[0]=obuf; p.A0[1]=obuf+(size_t)PB*131072;
      p.Bm[0]=Wo; p.Bm[1]=Wo+131072;
      p.Cm[0]=OUT; p.Cm[1]=PH4;
      p.vtb[0]=ABV; p.vtb[1]=PBV;
      p.idxp[0]=idxb; p.idxp[1]=idxb+PB*1024;
      kern_scat<<<dim3(8, PB*16, 2), 256, 0, stream>>>(p);
    }

    // spec = famp*e^{i fph}; inverse FFT2 -> spatial into OUT
    kern_ifft_rows_spec<<<PB*4096, 256, 0, stream>>>(OUT, PH4, S0, S1);
    kern_fft_cols_inv  <<<PB*1024, 256, 0, stream>>>(S0, S1, OUT);
  }

  // convs (MFMA): d_out(spatial) -> ws[0..16.78M floats) (conv1+relu) -> d_out
  kern_cmfma<1><<<dim3(256, 4), 256, 0, stream>>>((float*)d_out, wtb, c1b, ws,
                                                  nullptr, nullptr, nullptr, nullptr);
  kern_cmfma<2><<<dim3(256, 4), 256, 0, stream>>>(ws, wtb + 36864, c2b, (float*)d_out,
                                                  modg, modb, vis, irf);
}